// Round 2
// baseline (6890.207 us; speedup 1.0000x reference)
//
#include <hip/hip_runtime.h>

#define DEV __device__ __forceinline__

typedef unsigned short u16;
typedef unsigned int   u32;
typedef u16   u16x8 __attribute__((ext_vector_type(8)));
typedef __bf16 bf16x8 __attribute__((ext_vector_type(8)));
typedef float f32x4 __attribute__((ext_vector_type(4)));

DEV float b2f(u16 u){ return __uint_as_float(((u32)u) << 16); }
DEV u16 f2b(float f){ u32 u = __float_as_uint(f); u32 r = (u + 0x7fffu + ((u >> 16) & 1u)) >> 16; return (u16)r; }

DEV f32x4 mfma16(u16x8 a, u16x8 b, f32x4 c){
  return __builtin_amdgcn_mfma_f32_16x16x32_bf16(
      __builtin_bit_cast(bf16x8, a), __builtin_bit_cast(bf16x8, b), c, 0, 0, 0);
}

// ---------------- LayerNorm: x(f32) -> xn(bf16) + per-row stats ----------------
__global__ __launch_bounds__(256) void ln_kernel(const float* __restrict__ x,
                                                 const float* __restrict__ w,
                                                 const float* __restrict__ bb,
                                                 u16* __restrict__ xn,
                                                 float2* __restrict__ stats){
  int row = blockIdx.x;
  const float* xr = x + (size_t)row * 512;
  int t = threadIdx.x;
  float2 v = *(const float2*)(xr + t * 2);
  float s = v.x + v.y;
  float sq = v.x * v.x + v.y * v.y;
  #pragma unroll
  for(int off = 32; off; off >>= 1){ s += __shfl_xor(s, off, 64); sq += __shfl_xor(sq, off, 64); }
  __shared__ float rs[4], rq[4];
  int wv = t >> 6, ln = t & 63;
  if(ln == 0){ rs[wv] = s; rq[wv] = sq; }
  __syncthreads();
  s = rs[0] + rs[1] + rs[2] + rs[3];
  sq = rq[0] + rq[1] + rq[2] + rq[3];
  float mu = s * (1.f / 512.f);
  float var = sq * (1.f / 512.f) - mu * mu;
  float rstd = rsqrtf(var + 1e-5f);
  if(t == 0) stats[row] = make_float2(mu, rstd);
  float w0 = w[t * 2], w1 = w[t * 2 + 1], b0 = bb[t * 2], b1 = bb[t * 2 + 1];
  u16 u0 = f2b((v.x - mu) * rstd * w0 + b0);
  u16 u1 = f2b((v.y - mu) * rstd * w1 + b1);
  ((u32*)(xn + (size_t)row * 512))[t] = (u32)u0 | ((u32)u1 << 16);
}

// ------------- landmark means of LN(x) in fp32: xl[b*256+j][512] -------------
__global__ __launch_bounds__(256) void xl_kernel(const float* __restrict__ x,
                                                 const float2* __restrict__ stats,
                                                 const float* __restrict__ w,
                                                 const float* __restrict__ bb,
                                                 float* __restrict__ xl){
  int blk = blockIdx.x;          // b*256 + j
  int b = blk >> 8, j = blk & 255;
  int t = threadIdx.x;
  int d0 = t * 2;
  float acc0 = 0.f, acc1 = 0.f;
  size_t row0 = (size_t)b * 8192 + (size_t)j * 32;
  for(int tt = 0; tt < 32; tt++){
    size_t row = row0 + tt;
    float2 st = stats[row];
    const float* xr = x + row * 512;
    float2 v = *(const float2*)(xr + d0);
    acc0 += (v.x - st.x) * st.y;
    acc1 += (v.y - st.x) * st.y;
  }
  float* dst = xl + (size_t)blk * 512;
  dst[d0]     = acc0 * (1.f / 32.f) * w[d0]     + bb[d0];
  dst[d0 + 1] = acc1 * (1.f / 32.f) * w[d0 + 1] + bb[d0 + 1];
}

// ------------- transpose fp32 [K][N] -> bf16 [N][K] -------------
__global__ __launch_bounds__(256) void trans_kernel(const float* __restrict__ src,
                                                    u16* __restrict__ dst, int K, int N){
  int idx = blockIdx.x * 256 + threadIdx.x;
  if(idx >= K * N) return;
  int k = idx / N, n = idx - k * N;
  dst[(size_t)n * K + k] = f2b(src[idx]);
}

// ------------- transpose fp32: first 1024 cols of w_qkv -> wqkT[1024][512] -------------
__global__ __launch_bounds__(256) void transf32_kernel(const float* __restrict__ src,
                                                       float* __restrict__ dst){
  int idx = blockIdx.x * 256 + threadIdx.x;   // idx over 1024*512 dst elems
  int n = idx >> 9, k = idx & 511;
  dst[idx] = src[(size_t)k * 1536 + n];
}

// ------------- big bf16 GEMM: A[M x 512] @ BT[N x 512]^T, 128x128 tile -------------
template<int EPI>
__global__ __launch_bounds__(256) void gemm128(const u16* __restrict__ A,
                                               const u16* __restrict__ BT,
                                               u16* __restrict__ qo, u16* __restrict__ ko, u16* __restrict__ vo,
                                               const float* __restrict__ bout,
                                               const float* __restrict__ xres,
                                               float* __restrict__ dout){
  __shared__ u16 As[128][40];
  __shared__ u16 Bs[128][40];
  const int K = 512;
  int tb_m = blockIdx.x * 128, tb_n = blockIdx.y * 128;
  int tid = threadIdx.x, lane = tid & 63, w = tid >> 6;
  int wm = (w >> 1) * 64, wn = (w & 1) * 64;
  f32x4 acc[4][4] = {};
  int srow = tid >> 1, sseg = (tid & 1) * 16;
  const u16* Ag = A + (size_t)(tb_m + srow) * K + sseg;
  const u16* Bg = BT + (size_t)(tb_n + srow) * K + sseg;
  for(int kk = 0; kk < K; kk += 32){
    __syncthreads();
    u16x8 a0 = *(const u16x8*)(Ag + kk);
    u16x8 a1 = *(const u16x8*)(Ag + kk + 8);
    u16x8 b0 = *(const u16x8*)(Bg + kk);
    u16x8 b1 = *(const u16x8*)(Bg + kk + 8);
    *(u16x8*)&As[srow][sseg]     = a0;
    *(u16x8*)&As[srow][sseg + 8] = a1;
    *(u16x8*)&Bs[srow][sseg]     = b0;
    *(u16x8*)&Bs[srow][sseg + 8] = b1;
    __syncthreads();
    int r = lane & 15, ko2 = (lane >> 4) * 8;
    u16x8 af[4], bf[4];
    #pragma unroll
    for(int mi = 0; mi < 4; mi++) af[mi] = *(const u16x8*)&As[wm + mi * 16 + r][ko2];
    #pragma unroll
    for(int ni = 0; ni < 4; ni++) bf[ni] = *(const u16x8*)&Bs[wn + ni * 16 + r][ko2];
    #pragma unroll
    for(int mi = 0; mi < 4; mi++)
      #pragma unroll
      for(int ni = 0; ni < 4; ni++)
        acc[mi][ni] = mfma16(af[mi], bf[ni], acc[mi][ni]);
  }
  int r = lane & 15, rr = (lane >> 4) * 4;
  #pragma unroll
  for(int mi = 0; mi < 4; mi++)
    #pragma unroll
    for(int ni = 0; ni < 4; ni++){
      int col = tb_n + wn + ni * 16 + r;
      #pragma unroll
      for(int e = 0; e < 4; e++){
        int row = tb_m + wm + mi * 16 + rr + e;
        float val = acc[mi][ni][e];
        if(EPI == 0){
          int t3 = col >> 9, h = (col >> 6) & 7, dh = col & 63;
          int b = row >> 13, n = row & 8191;
          if(t3 == 0) val *= 0.125f;
          u16* dst = (t3 == 0 ? qo : (t3 == 1 ? ko : vo));
          dst[(((size_t)(b * 8 + h) * 8192) + n) * 64 + dh] = f2b(val);
        } else {
          val += bout[col] + xres[(size_t)row * 512 + col];
          dout[(size_t)row * 512 + col] = val;
        }
      }
    }
}

// ------------- fp32 GEMM: ql/kl = xl[1024][512] @ wqkT[1024][512]^T, scatter epi -------------
__global__ __launch_bounds__(256) void gemm_qlkl(const float* __restrict__ A,
                                                 const float* __restrict__ BT,
                                                 float* __restrict__ qlf,
                                                 float* __restrict__ klf){
  __shared__ float As[64][17];
  __shared__ float Bs[64][17];
  int tb_m = blockIdx.x * 64, tb_n = blockIdx.y * 64;
  int tid = threadIdx.x;
  int ty = tid >> 4, tx = tid & 15;
  float acc[4][4] = {};
  int srow = tid >> 2, sseg = (tid & 3) * 4;
  const float* Ag = A + (size_t)(tb_m + srow) * 512 + sseg;
  const float* Bg = BT + (size_t)(tb_n + srow) * 512 + sseg;
  for(int kk = 0; kk < 512; kk += 16){
    __syncthreads();
    f32x4 a4 = *(const f32x4*)(Ag + kk);
    f32x4 b4 = *(const f32x4*)(Bg + kk);
    #pragma unroll
    for(int e = 0; e < 4; e++){ As[srow][sseg + e] = a4[e]; Bs[srow][sseg + e] = b4[e]; }
    __syncthreads();
    #pragma unroll
    for(int k2 = 0; k2 < 16; k2++){
      float a[4], b[4];
      #pragma unroll
      for(int i = 0; i < 4; i++) a[i] = As[ty * 4 + i][k2];
      #pragma unroll
      for(int jv = 0; jv < 4; jv++) b[jv] = Bs[tx * 4 + jv][k2];
      #pragma unroll
      for(int i = 0; i < 4; i++)
        #pragma unroll
        for(int jv = 0; jv < 4; jv++) acc[i][jv] += a[i] * b[jv];
    }
  }
  #pragma unroll
  for(int i = 0; i < 4; i++)
    #pragma unroll
    for(int jv = 0; jv < 4; jv++){
      int r = tb_m + ty * 4 + i;
      int c = tb_n + tx * 4 + jv;
      int b = r >> 8, jl = r & 255;
      float val = acc[i][jv];
      if(c < 512){
        qlf[(((size_t)(b * 8 + (c >> 6)) * 256) + jl) * 64 + (c & 63)] = val * 0.125f;
      } else {
        int c2 = c - 512;
        klf[(((size_t)(b * 8 + (c2 >> 6)) * 256) + jl) * 64 + (c2 & 63)] = val;
      }
    }
}

// ------------- batched fp32 pinv GEMM: per-bh 256x256, C = osc*(A @ (dB*I + sB*B)) -------------
__global__ __launch_bounds__(256) void gemm_pinv_f32(const float* __restrict__ A,
                                                     const float* __restrict__ BT,
                                                     float* __restrict__ Cp, float* __restrict__ CTp,
                                                     float dB, float sB, float osc){
  __shared__ float As[64][17];
  __shared__ float Bs[64][17];
  int bh = blockIdx.y;
  size_t base = (size_t)bh * 65536;
  int tb_m = (blockIdx.x >> 2) * 64, tb_n = (blockIdx.x & 3) * 64;
  int tid = threadIdx.x;
  int ty = tid >> 4, tx = tid & 15;
  float acc[4][4] = {};
  int srow = tid >> 2, sseg = (tid & 3) * 4;
  const float* Ag = A + base + (size_t)(tb_m + srow) * 256 + sseg;
  const float* Bg = BT + base + (size_t)(tb_n + srow) * 256 + sseg;
  int bn = tb_n + srow;
  for(int kk = 0; kk < 256; kk += 16){
    __syncthreads();
    f32x4 a4 = *(const f32x4*)(Ag + kk);
    f32x4 b4 = *(const f32x4*)(Bg + kk);
    #pragma unroll
    for(int e = 0; e < 4; e++){
      As[srow][sseg + e] = a4[e];
      float vv = sB * b4[e];
      if(kk + sseg + e == bn) vv += dB;
      Bs[srow][sseg + e] = vv;
    }
    __syncthreads();
    #pragma unroll
    for(int k2 = 0; k2 < 16; k2++){
      float a[4], b[4];
      #pragma unroll
      for(int i = 0; i < 4; i++) a[i] = As[ty * 4 + i][k2];
      #pragma unroll
      for(int jv = 0; jv < 4; jv++) b[jv] = Bs[tx * 4 + jv][k2];
      #pragma unroll
      for(int i = 0; i < 4; i++)
        #pragma unroll
        for(int jv = 0; jv < 4; jv++) acc[i][jv] += a[i] * b[jv];
    }
  }
  #pragma unroll
  for(int i = 0; i < 4; i++)
    #pragma unroll
    for(int jv = 0; jv < 4; jv++){
      int r = tb_m + ty * 4 + i;
      int c = tb_n + tx * 4 + jv;
      float val = osc * acc[i][jv];
      if(Cp)  Cp[base + (size_t)r * 256 + c] = val;
      if(CTp) CTp[base + (size_t)c * 256 + r] = val;
    }
}

// ------------- a2 = softmax(q_l @ k_l^T) per row, fp32 -------------
__global__ __launch_bounds__(256) void a2_kernel(const float* __restrict__ qlf,
                                                 const float* __restrict__ klf,
                                                 float* __restrict__ a2){
  int i = blockIdx.x, bh = blockIdx.y, j = threadIdx.x;
  const float* qp = qlf + ((size_t)bh * 256 + i) * 64;
  const float* kp = klf + ((size_t)bh * 256 + j) * 64;
  float s = 0.f;
  #pragma unroll
  for(int d0 = 0; d0 < 16; d0++){
    f32x4 uq = *(const f32x4*)(qp + d0 * 4);
    f32x4 uk = *(const f32x4*)(kp + d0 * 4);
    #pragma unroll
    for(int e = 0; e < 4; e++) s += uq[e] * uk[e];
  }
  __shared__ float red[256];
  red[j] = s; __syncthreads();
  for(int off = 128; off; off >>= 1){ if(j < off) red[j] = fmaxf(red[j], red[j + off]); __syncthreads(); }
  float m = red[0]; __syncthreads();
  float p = expf(s - m);
  red[j] = p; __syncthreads();
  for(int off = 128; off; off >>= 1){ if(j < off) red[j] += red[j + off]; __syncthreads(); }
  float denom = red[0];
  a2[((size_t)bh * 256 + i) * 256 + j] = p / denom;
}

// ------------- scale maxes -------------
__global__ __launch_bounds__(256) void scale_kernel(const float* __restrict__ a2, u32* __restrict__ maxes){
  int bh = blockIdx.x, t = threadIdx.x;
  const float* p = a2 + (size_t)bh * 65536;
  float cs = 0.f, rs = 0.f;
  for(int i = 0; i < 256; i++) cs += p[i * 256 + t];
  for(int j = 0; j < 256; j++) rs += p[t * 256 + j];
  __shared__ float rc[256], rr[256];
  rc[t] = cs; rr[t] = rs; __syncthreads();
  for(int off = 128; off; off >>= 1){
    if(t < off){ rc[t] = fmaxf(rc[t], rc[t + off]); rr[t] = fmaxf(rr[t], rr[t + off]); }
    __syncthreads();
  }
  if(t == 0){
    atomicMax(&maxes[0], __float_as_uint(rc[0]));
    atomicMax(&maxes[1], __float_as_uint(rr[0]));
  }
}

// ------------- z0 = a2^T / scale and z0T = a2 / scale -------------
__global__ __launch_bounds__(256) void z0_kernel(const float* __restrict__ a2,
                                                 float* __restrict__ z, float* __restrict__ zT,
                                                 const u32* __restrict__ maxes){
  float scale = __uint_as_float(maxes[0]) * __uint_as_float(maxes[1]);
  int bh = blockIdx.y;
  int idx = blockIdx.x * 256 + threadIdx.x;
  int i = idx >> 8, j = idx & 255;
  float v = a2[(size_t)bh * 65536 + idx] / scale;
  zT[(size_t)bh * 65536 + idx] = v;
  z[(size_t)bh * 65536 + (size_t)j * 256 + i] = v;
}

// ------------- av = softmax(q_l @ k^T) @ v  (flash, wave per landmark row) -------------
__global__ __launch_bounds__(256) void a3v_kernel(const float* __restrict__ qlf,
                                                  const u16* __restrict__ k,
                                                  const u16* __restrict__ v,
                                                  float* __restrict__ av){
  int w = threadIdx.x >> 6, lane = threadIdx.x & 63;
  int rowid = blockIdx.x * 4 + w;
  int bh = rowid >> 8, i = rowid & 255;
  const float* qp = qlf + ((size_t)bh * 256 + i) * 64;
  float q[64];
  #pragma unroll
  for(int d0 = 0; d0 < 16; d0++){
    f32x4 u = *(const f32x4*)(qp + d0 * 4);
    #pragma unroll
    for(int e = 0; e < 4; e++) q[d0 * 4 + e] = u[e];
  }
  const u16* kb = k + (size_t)bh * 8192 * 64;
  const u16* vb = v + (size_t)bh * 8192 * 64;
  float m = -1e30f, l = 0.f;
  float acc[64];
  #pragma unroll
  for(int d = 0; d < 64; d++) acc[d] = 0.f;
  for(int c = 0; c < 128; c++){
    int key = c * 64 + lane;
    const u16* kr = kb + (size_t)key * 64;
    float s = 0.f;
    #pragma unroll
    for(int d0 = 0; d0 < 8; d0++){
      u16x8 u = *(const u16x8*)(kr + d0 * 8);
      #pragma unroll
      for(int e = 0; e < 8; e++) s += q[d0 * 8 + e] * b2f(u[e]);
    }
    float mc = s;
    #pragma unroll
    for(int off = 32; off; off >>= 1) mc = fmaxf(mc, __shfl_xor(mc, off, 64));
    if(mc > m){
      float f = __expf(m - mc);
      l *= f;
      #pragma unroll
      for(int d = 0; d < 64; d++) acc[d] *= f;
      m = mc;
    }
    float p = __expf(s - m);
    float ps = p;
    #pragma unroll
    for(int off = 32; off; off >>= 1) ps += __shfl_xor(ps, off, 64);
    l += ps;
    const u16* vr = vb + (size_t)key * 64;
    #pragma unroll
    for(int d0 = 0; d0 < 8; d0++){
      u16x8 u = *(const u16x8*)(vr + d0 * 8);
      #pragma unroll
      for(int e = 0; e < 8; e++) acc[d0 * 8 + e] += p * b2f(u[e]);
    }
  }
  #pragma unroll
  for(int off = 32; off; off >>= 1)
    #pragma unroll
    for(int d = 0; d < 64; d++) acc[d] += __shfl_xor(acc[d], off, 64);
  float outv = 0.f;
  #pragma unroll
  for(int d = 0; d < 64; d++) if(lane == d) outv = acc[d];
  av[((size_t)bh * 256 + i) * 64 + lane] = outv / l;
}

// ------------- W = Z @ av -------------
__global__ __launch_bounds__(64) void zw_kernel(const float* __restrict__ z,
                                                const float* __restrict__ av,
                                                float* __restrict__ W){
  int i = blockIdx.x & 255, bh = blockIdx.x >> 8, d = threadIdx.x;
  const float* zr = z + ((size_t)bh * 256 + i) * 256;
  const float* ab = av + (size_t)bh * 256 * 64;
  float s = 0.f;
  for(int j = 0; j < 256; j++) s += zr[j] * ab[j * 64 + d];
  W[((size_t)bh * 256 + i) * 64 + d] = s;
}

// ------------- depthwise conv residual -> o (bf16 token layout) -------------
__global__ __launch_bounds__(256) void conv_kernel(const u16* __restrict__ v,
                                                   const float* __restrict__ cw,
                                                   u16* __restrict__ o){
  __shared__ float wl[33];
  __shared__ u16 vl[96][64];
  int bh = blockIdx.y, b = bh >> 3, h = bh & 7;
  int r0 = blockIdx.x * 64;
  if(threadIdx.x < 33) wl[threadIdx.x] = cw[h * 33 + threadIdx.x];
  const u16* vb = v + (size_t)bh * 8192 * 64;
  for(int idx = threadIdx.x; idx < 768; idx += 256){
    int row = idx >> 3, col = (idx & 7) * 8;
    int gr = r0 - 16 + row;
    u16x8 u = {};
    if(gr >= 0 && gr < 8192) u = *(const u16x8*)(vb + (size_t)gr * 64 + col);
    *(u16x8*)&vl[row][col] = u;
  }
  __syncthreads();
  int d = threadIdx.x & 63, rbase = (threadIdx.x >> 6) * 16;
  for(int r = 0; r < 16; r++){
    int lr = rbase + r;
    float s = 0.f;
    #pragma unroll
    for(int t = 0; t < 33; t++) s += wl[t] * b2f(vl[lr + t][d]);
    size_t oi = ((size_t)b * 8192 + (r0 + rbase + r)) * 512 + h * 64 + d;
    o[oi] = f2b(s);
  }
}

// ------------- out_attn = softmax(q @ k_l^T) @ W, += conv residual -------------
__global__ __launch_bounds__(256) void a1_kernel(const u16* __restrict__ q,
                                                 const float* __restrict__ klf,
                                                 const float* __restrict__ W,
                                                 u16* __restrict__ o){
  int w = threadIdx.x >> 6, lane = threadIdx.x & 63;
  int rowid = blockIdx.x * 4 + w;
  int bh = rowid >> 13, n = rowid & 8191;
  int b = bh >> 3, h = bh & 7;
  const u16* qp = q + ((size_t)bh * 8192 + n) * 64;
  float qv[64];
  #pragma unroll
  for(int d0 = 0; d0 < 8; d0++){
    u16x8 u = *(const u16x8*)(qp + d0 * 8);
    #pragma unroll
    for(int e = 0; e < 8; e++) qv[d0 * 8 + e] = b2f(u[e]);
  }
  const float* klb = klf + (size_t)bh * 256 * 64;
  const float* Wb = W + (size_t)bh * 256 * 64;
  float m = -1e30f, l = 0.f;
  float acc[64];
  #pragma unroll
  for(int d = 0; d < 64; d++) acc[d] = 0.f;
  for(int c = 0; c < 4; c++){
    int j = c * 64 + lane;
    const float* kr = klb + (size_t)j * 64;
    float s = 0.f;
    #pragma unroll
    for(int d0 = 0; d0 < 16; d0++){
      f32x4 u = *(const f32x4*)(kr + d0 * 4);
      #pragma unroll
      for(int e = 0; e < 4; e++) s += qv[d0 * 4 + e] * u[e];
    }
    float mc = s;
    #pragma unroll
    for(int off = 32; off; off >>= 1) mc = fmaxf(mc, __shfl_xor(mc, off, 64));
    if(mc > m){
      float f = __expf(m - mc);
      l *= f;
      #pragma unroll
      for(int d = 0; d < 64; d++) acc[d] *= f;
      m = mc;
    }
    float p = __expf(s - m);
    float ps = p;
    #pragma unroll
    for(int off = 32; off; off >>= 1) ps += __shfl_xor(ps, off, 64);
    l += ps;
    const float* Wr = Wb + (size_t)j * 64;
    #pragma unroll
    for(int d0 = 0; d0 < 16; d0++){
      f32x4 wv = *(const f32x4*)(Wr + d0 * 4);
      #pragma unroll
      for(int e = 0; e < 4; e++) acc[d0 * 4 + e] += p * wv[e];
    }
  }
  #pragma unroll
  for(int off = 32; off; off >>= 1)
    #pragma unroll
    for(int d = 0; d < 64; d++) acc[d] += __shfl_xor(acc[d], off, 64);
  float outv = 0.f;
  #pragma unroll
  for(int d = 0; d < 64; d++) if(lane == d) outv = acc[d];
  size_t oi = ((size_t)b * 8192 + n) * 512 + h * 64 + lane;
  o[oi] = f2b(outv / l + b2f(o[oi]));
}

extern "C" void kernel_launch(void* const* d_in, const int* in_sizes, int n_in,
                              void* d_out, int out_size, void* d_ws, size_t ws_size,
                              hipStream_t stream){
  (void)in_sizes; (void)n_in; (void)out_size; (void)ws_size;
  const float* x     = (const float*)d_in[0];
  const float* ln_w  = (const float*)d_in[1];
  const float* ln_b  = (const float*)d_in[2];
  const float* w_qkv = (const float*)d_in[3];
  const float* w_out = (const float*)d_in[4];
  const float* b_out = (const float*)d_in[5];
  const float* cw    = (const float*)d_in[6];
  float* out = (float*)d_out;

  char* base = (char*)d_ws;
  size_t off = 0;
  auto alloc = [&](size_t bytes)->void*{
    void* r = base + off; off += (bytes + 255) & ~(size_t)255; return r;
  };
  u16* xn      = (u16*)alloc(32768ull * 512 * 2);    // reused as o after QKV GEMM
  float2* stat = (float2*)alloc(32768ull * 8);
  u16* qb      = (u16*)alloc(32ull * 8192 * 64 * 2);
  u16* kb      = (u16*)alloc(32ull * 8192 * 64 * 2);
  u16* vb      = (u16*)alloc(32ull * 8192 * 64 * 2);
  u16* wqkvT   = (u16*)alloc(1536ull * 512 * 2);
  u16* woutT   = (u16*)alloc(512ull * 512 * 2);
  float* wqkT  = (float*)alloc(1024ull * 512 * 4);
  float* xl    = (float*)alloc(1024ull * 512 * 4);
  float* qlf   = (float*)alloc(32ull * 256 * 64 * 4);
  float* klf   = (float*)alloc(32ull * 256 * 64 * 4);
  float* a2b   = (float*)alloc(32ull * 65536 * 4);
  float* zA    = (float*)alloc(32ull * 65536 * 4);
  float* zAT   = (float*)alloc(32ull * 65536 * 4);
  float* zB    = (float*)alloc(32ull * 65536 * 4);
  float* zBT   = (float*)alloc(32ull * 65536 * 4);
  float* az    = (float*)alloc(32ull * 65536 * 4);
  float* azT   = (float*)alloc(32ull * 65536 * 4);
  float* x2t   = (float*)alloc(32ull * 65536 * 4);
  float* x3t   = (float*)alloc(32ull * 65536 * 4);
  float* av    = (float*)alloc(32ull * 256 * 64 * 4);
  float* Wz    = (float*)alloc(32ull * 256 * 64 * 4);
  u32* scal    = (u32*)alloc(256);
  u16* ob = xn;

  hipMemsetAsync(scal, 0, 8, stream);
  ln_kernel<<<32768, 256, 0, stream>>>(x, ln_w, ln_b, xn, stat);
  trans_kernel<<<3072, 256, 0, stream>>>(w_qkv, wqkvT, 512, 1536);
  trans_kernel<<<1024, 256, 0, stream>>>(w_out, woutT, 512, 512);
  transf32_kernel<<<2048, 256, 0, stream>>>(w_qkv, wqkT);
  gemm128<0><<<dim3(256, 12), 256, 0, stream>>>(xn, wqkvT, qb, kb, vb, nullptr, nullptr, nullptr);
  xl_kernel<<<1024, 256, 0, stream>>>(x, stat, ln_w, ln_b, xl);
  gemm_qlkl<<<dim3(16, 16), 256, 0, stream>>>(xl, wqkT, qlf, klf);
  a2_kernel<<<dim3(256, 32), 256, 0, stream>>>(qlf, klf, a2b);
  scale_kernel<<<32, 256, 0, stream>>>(a2b, scal);
  z0_kernel<<<dim3(256, 32), 256, 0, stream>>>(a2b, zA, zAT, scal);

  float* zPing = zA; float* zPingT = zAT; float* zPong = zB; float* zPongT = zBT;
  for(int it = 0; it < 6; it++){
    gemm_pinv_f32<<<dim3(16, 32), 256, 0, stream>>>(a2b, zPingT, az, azT, 0.f, 1.f, 1.f);
    gemm_pinv_f32<<<dim3(16, 32), 256, 0, stream>>>(az, azT, nullptr, x2t, 7.f, -1.f, 1.f);
    gemm_pinv_f32<<<dim3(16, 32), 256, 0, stream>>>(az, x2t, nullptr, x3t, 11.f, -1.f, 1.f);
    gemm_pinv_f32<<<dim3(16, 32), 256, 0, stream>>>(zPing, x3t, zPong, zPongT, 13.f, -1.f, 0.25f);
    float* t1 = zPing; zPing = zPong; zPong = t1;
    float* t2 = zPingT; zPingT = zPongT; zPongT = t2;
  }

  a3v_kernel<<<2048, 256, 0, stream>>>(qlf, kb, vb, av);
  zw_kernel<<<8192, 64, 0, stream>>>(zPing, av, Wz);
  conv_kernel<<<dim3(128, 32), 256, 0, stream>>>(vb, cw, ob);
  a1_kernel<<<65536, 256, 0, stream>>>(qb, klf, Wz, ob);
  gemm128<1><<<dim3(256, 4), 256, 0, stream>>>(ob, woutT, nullptr, nullptr, nullptr, b_out, x, out);
}

// Round 3
// 1443.663 us; speedup vs baseline: 4.7727x; 4.7727x over previous
//
#include <hip/hip_runtime.h>

#define DEV __device__ __forceinline__

typedef unsigned short u16;
typedef unsigned int   u32;
typedef u16   u16x8 __attribute__((ext_vector_type(8)));
typedef __bf16 bf16x8 __attribute__((ext_vector_type(8)));
typedef float f32x4 __attribute__((ext_vector_type(4)));

DEV float b2f(u16 u){ return __uint_as_float(((u32)u) << 16); }
DEV u16 f2b(float f){ u32 u = __float_as_uint(f); u32 r = (u + 0x7fffu + ((u >> 16) & 1u)) >> 16; return (u16)r; }

DEV f32x4 mfma16(u16x8 a, u16x8 b, f32x4 c){
  return __builtin_amdgcn_mfma_f32_16x16x32_bf16(
      __builtin_bit_cast(bf16x8, a), __builtin_bit_cast(bf16x8, b), c, 0, 0, 0);
}

// ---------------- LayerNorm: x(f32) -> xn(bf16) + per-row stats ----------------
__global__ __launch_bounds__(256) void ln_kernel(const float* __restrict__ x,
                                                 const float* __restrict__ w,
                                                 const float* __restrict__ bb,
                                                 u16* __restrict__ xn,
                                                 float2* __restrict__ stats){
  int row = blockIdx.x;
  const float* xr = x + (size_t)row * 512;
  int t = threadIdx.x;
  float2 v = *(const float2*)(xr + t * 2);
  float s = v.x + v.y;
  float sq = v.x * v.x + v.y * v.y;
  #pragma unroll
  for(int off = 32; off; off >>= 1){ s += __shfl_xor(s, off, 64); sq += __shfl_xor(sq, off, 64); }
  __shared__ float rs[4], rq[4];
  int wv = t >> 6, ln = t & 63;
  if(ln == 0){ rs[wv] = s; rq[wv] = sq; }
  __syncthreads();
  s = rs[0] + rs[1] + rs[2] + rs[3];
  sq = rq[0] + rq[1] + rq[2] + rq[3];
  float mu = s * (1.f / 512.f);
  float var = sq * (1.f / 512.f) - mu * mu;
  float rstd = rsqrtf(var + 1e-5f);
  if(t == 0) stats[row] = make_float2(mu, rstd);
  float w0 = w[t * 2], w1 = w[t * 2 + 1], b0 = bb[t * 2], b1 = bb[t * 2 + 1];
  u16 u0 = f2b((v.x - mu) * rstd * w0 + b0);
  u16 u1 = f2b((v.y - mu) * rstd * w1 + b1);
  ((u32*)(xn + (size_t)row * 512))[t] = (u32)u0 | ((u32)u1 << 16);
}

// ------------- landmark means of LN(x) in fp32: xl[b*256+j][512] -------------
__global__ __launch_bounds__(256) void xl_kernel(const float* __restrict__ x,
                                                 const float2* __restrict__ stats,
                                                 const float* __restrict__ w,
                                                 const float* __restrict__ bb,
                                                 float* __restrict__ xl){
  int blk = blockIdx.x;          // b*256 + j
  int b = blk >> 8, j = blk & 255;
  int t = threadIdx.x;
  int d0 = t * 2;
  float acc0 = 0.f, acc1 = 0.f;
  size_t row0 = (size_t)b * 8192 + (size_t)j * 32;
  for(int tt = 0; tt < 32; tt++){
    size_t row = row0 + tt;
    float2 st = stats[row];
    const float* xr = x + row * 512;
    float2 v = *(const float2*)(xr + d0);
    acc0 += (v.x - st.x) * st.y;
    acc1 += (v.y - st.x) * st.y;
  }
  float* dst = xl + (size_t)blk * 512;
  dst[d0]     = acc0 * (1.f / 32.f) * w[d0]     + bb[d0];
  dst[d0 + 1] = acc1 * (1.f / 32.f) * w[d0 + 1] + bb[d0 + 1];
}

// ------------- transpose fp32 [K][N] -> bf16 [N][K] -------------
__global__ __launch_bounds__(256) void trans_kernel(const float* __restrict__ src,
                                                    u16* __restrict__ dst, int K, int N){
  int idx = blockIdx.x * 256 + threadIdx.x;
  if(idx >= K * N) return;
  int k = idx / N, n = idx - k * N;
  dst[(size_t)n * K + k] = f2b(src[idx]);
}

// ------------- transpose fp32: first 1024 cols of w_qkv -> wqkT[1024][512] -------------
__global__ __launch_bounds__(256) void transf32_kernel(const float* __restrict__ src,
                                                       float* __restrict__ dst){
  int idx = blockIdx.x * 256 + threadIdx.x;
  int n = idx >> 9, k = idx & 511;
  dst[idx] = src[(size_t)k * 1536 + n];
}

// ------------- v [key][d] -> vt [d][key] (bf16, per bh) -------------
__global__ __launch_bounds__(256) void vtrans_kernel(const u16* __restrict__ v,
                                                     u16* __restrict__ vt){
  __shared__ u16 tile[64][72];
  int bh = blockIdx.y, n0 = blockIdx.x * 64;
  int t = threadIdx.x;
  for(int s = t; s < 512; s += 256){
    int row = s >> 3, col = (s & 7) * 8;
    *(u16x8*)&tile[row][col] = *(const u16x8*)(v + ((size_t)bh * 8192 + n0 + row) * 64 + col);
  }
  __syncthreads();
  for(int s = t; s < 512; s += 256){
    int d = s >> 3, nc = (s & 7) * 8;
    u16x8 u;
    #pragma unroll
    for(int e = 0; e < 8; e++) u[e] = tile[nc + e][d];
    *(u16x8*)(vt + ((size_t)bh * 64 + d) * 8192 + n0 + nc) = u;
  }
}

// ------------- big bf16 GEMM: A[M x 512] @ BT[N x 512]^T, 128x128 tile -------------
template<int EPI>
__global__ __launch_bounds__(256) void gemm128(const u16* __restrict__ A,
                                               const u16* __restrict__ BT,
                                               u16* __restrict__ qo, u16* __restrict__ ko, u16* __restrict__ vo,
                                               const float* __restrict__ bout,
                                               const float* __restrict__ xres,
                                               float* __restrict__ dout){
  __shared__ u16 As[128][40];
  __shared__ u16 Bs[128][40];
  const int K = 512;
  int tb_m = blockIdx.x * 128, tb_n = blockIdx.y * 128;
  int tid = threadIdx.x, lane = tid & 63, w = tid >> 6;
  int wm = (w >> 1) * 64, wn = (w & 1) * 64;
  f32x4 acc[4][4] = {};
  int srow = tid >> 1, sseg = (tid & 1) * 16;
  const u16* Ag = A + (size_t)(tb_m + srow) * K + sseg;
  const u16* Bg = BT + (size_t)(tb_n + srow) * K + sseg;
  for(int kk = 0; kk < K; kk += 32){
    __syncthreads();
    u16x8 a0 = *(const u16x8*)(Ag + kk);
    u16x8 a1 = *(const u16x8*)(Ag + kk + 8);
    u16x8 b0 = *(const u16x8*)(Bg + kk);
    u16x8 b1 = *(const u16x8*)(Bg + kk + 8);
    *(u16x8*)&As[srow][sseg]     = a0;
    *(u16x8*)&As[srow][sseg + 8] = a1;
    *(u16x8*)&Bs[srow][sseg]     = b0;
    *(u16x8*)&Bs[srow][sseg + 8] = b1;
    __syncthreads();
    int r = lane & 15, ko2 = (lane >> 4) * 8;
    u16x8 af[4], bf[4];
    #pragma unroll
    for(int mi = 0; mi < 4; mi++) af[mi] = *(const u16x8*)&As[wm + mi * 16 + r][ko2];
    #pragma unroll
    for(int ni = 0; ni < 4; ni++) bf[ni] = *(const u16x8*)&Bs[wn + ni * 16 + r][ko2];
    #pragma unroll
    for(int mi = 0; mi < 4; mi++)
      #pragma unroll
      for(int ni = 0; ni < 4; ni++)
        acc[mi][ni] = mfma16(af[mi], bf[ni], acc[mi][ni]);
  }
  int r = lane & 15, rr = (lane >> 4) * 4;
  #pragma unroll
  for(int mi = 0; mi < 4; mi++)
    #pragma unroll
    for(int ni = 0; ni < 4; ni++){
      int col = tb_n + wn + ni * 16 + r;
      #pragma unroll
      for(int e = 0; e < 4; e++){
        int row = tb_m + wm + mi * 16 + rr + e;
        float val = acc[mi][ni][e];
        if(EPI == 0){
          int t3 = col >> 9, h = (col >> 6) & 7, dh = col & 63;
          int b = row >> 13, n = row & 8191;
          if(t3 == 0) val *= 0.125f;
          u16* dst = (t3 == 0 ? qo : (t3 == 1 ? ko : vo));
          dst[(((size_t)(b * 8 + h) * 8192) + n) * 64 + dh] = f2b(val);
        } else {
          val += bout[col] + xres[(size_t)row * 512 + col];
          dout[(size_t)row * 512 + col] = val;
        }
      }
    }
}

// ------------- fp32 GEMM: ql/kl = xl @ wqkT^T, scatter epi + hi/lo split -------------
__global__ __launch_bounds__(256) void gemm_qlkl(const float* __restrict__ A,
                                                 const float* __restrict__ BT,
                                                 float* __restrict__ qlf,
                                                 float* __restrict__ klf,
                                                 u16* __restrict__ qlh, u16* __restrict__ qll,
                                                 u16* __restrict__ klh, u16* __restrict__ kll){
  __shared__ float As[64][17];
  __shared__ float Bs[64][17];
  int tb_m = blockIdx.x * 64, tb_n = blockIdx.y * 64;
  int tid = threadIdx.x;
  int ty = tid >> 4, tx = tid & 15;
  float acc[4][4] = {};
  int srow = tid >> 2, sseg = (tid & 3) * 4;
  const float* Ag = A + (size_t)(tb_m + srow) * 512 + sseg;
  const float* Bg = BT + (size_t)(tb_n + srow) * 512 + sseg;
  for(int kk = 0; kk < 512; kk += 16){
    __syncthreads();
    f32x4 a4 = *(const f32x4*)(Ag + kk);
    f32x4 b4 = *(const f32x4*)(Bg + kk);
    #pragma unroll
    for(int e = 0; e < 4; e++){ As[srow][sseg + e] = a4[e]; Bs[srow][sseg + e] = b4[e]; }
    __syncthreads();
    #pragma unroll
    for(int k2 = 0; k2 < 16; k2++){
      float a[4], b[4];
      #pragma unroll
      for(int i = 0; i < 4; i++) a[i] = As[ty * 4 + i][k2];
      #pragma unroll
      for(int jv = 0; jv < 4; jv++) b[jv] = Bs[tx * 4 + jv][k2];
      #pragma unroll
      for(int i = 0; i < 4; i++)
        #pragma unroll
        for(int jv = 0; jv < 4; jv++) acc[i][jv] += a[i] * b[jv];
    }
  }
  #pragma unroll
  for(int i = 0; i < 4; i++)
    #pragma unroll
    for(int jv = 0; jv < 4; jv++){
      int r = tb_m + ty * 4 + i;
      int c = tb_n + tx * 4 + jv;
      int b = r >> 8, jl = r & 255;
      float val = acc[i][jv];
      if(c < 512){
        float q = val * 0.125f;
        size_t qi = (((size_t)(b * 8 + (c >> 6)) * 256) + jl) * 64 + (c & 63);
        qlf[qi] = q;
        u16 hi = f2b(q);
        qlh[qi] = hi; qll[qi] = f2b(q - b2f(hi));
      } else {
        int c2 = c - 512;
        size_t ki = (((size_t)(b * 8 + (c2 >> 6)) * 256) + jl) * 64 + (c2 & 63);
        klf[ki] = val;
        u16 hi = f2b(val);
        klh[ki] = hi; kll[ki] = f2b(val - b2f(hi));
      }
    }
}

// ------------- batched fp32 pinv GEMM -------------
__global__ __launch_bounds__(256) void gemm_pinv_f32(const float* __restrict__ A,
                                                     const float* __restrict__ BT,
                                                     float* __restrict__ Cp, float* __restrict__ CTp,
                                                     float dB, float sB, float osc){
  __shared__ float As[64][17];
  __shared__ float Bs[64][17];
  int bh = blockIdx.y;
  size_t base = (size_t)bh * 65536;
  int tb_m = (blockIdx.x >> 2) * 64, tb_n = (blockIdx.x & 3) * 64;
  int tid = threadIdx.x;
  int ty = tid >> 4, tx = tid & 15;
  float acc[4][4] = {};
  int srow = tid >> 2, sseg = (tid & 3) * 4;
  const float* Ag = A + base + (size_t)(tb_m + srow) * 256 + sseg;
  const float* Bg = BT + base + (size_t)(tb_n + srow) * 256 + sseg;
  int bn = tb_n + srow;
  for(int kk = 0; kk < 256; kk += 16){
    __syncthreads();
    f32x4 a4 = *(const f32x4*)(Ag + kk);
    f32x4 b4 = *(const f32x4*)(Bg + kk);
    #pragma unroll
    for(int e = 0; e < 4; e++){
      As[srow][sseg + e] = a4[e];
      float vv = sB * b4[e];
      if(kk + sseg + e == bn) vv += dB;
      Bs[srow][sseg + e] = vv;
    }
    __syncthreads();
    #pragma unroll
    for(int k2 = 0; k2 < 16; k2++){
      float a[4], b[4];
      #pragma unroll
      for(int i = 0; i < 4; i++) a[i] = As[ty * 4 + i][k2];
      #pragma unroll
      for(int jv = 0; jv < 4; jv++) b[jv] = Bs[tx * 4 + jv][k2];
      #pragma unroll
      for(int i = 0; i < 4; i++)
        #pragma unroll
        for(int jv = 0; jv < 4; jv++) acc[i][jv] += a[i] * b[jv];
    }
  }
  #pragma unroll
  for(int i = 0; i < 4; i++)
    #pragma unroll
    for(int jv = 0; jv < 4; jv++){
      int r = tb_m + ty * 4 + i;
      int c = tb_n + tx * 4 + jv;
      float val = osc * acc[i][jv];
      if(Cp)  Cp[base + (size_t)r * 256 + c] = val;
      if(CTp) CTp[base + (size_t)c * 256 + r] = val;
    }
}

// ------------- a2 = softmax(q_l @ k_l^T) per row, fp32 -------------
__global__ __launch_bounds__(256) void a2_kernel(const float* __restrict__ qlf,
                                                 const float* __restrict__ klf,
                                                 float* __restrict__ a2){
  int i = blockIdx.x, bh = blockIdx.y, j = threadIdx.x;
  const float* qp = qlf + ((size_t)bh * 256 + i) * 64;
  const float* kp = klf + ((size_t)bh * 256 + j) * 64;
  float s = 0.f;
  #pragma unroll
  for(int d0 = 0; d0 < 16; d0++){
    f32x4 uq = *(const f32x4*)(qp + d0 * 4);
    f32x4 uk = *(const f32x4*)(kp + d0 * 4);
    #pragma unroll
    for(int e = 0; e < 4; e++) s += uq[e] * uk[e];
  }
  __shared__ float red[256];
  red[j] = s; __syncthreads();
  for(int off = 128; off; off >>= 1){ if(j < off) red[j] = fmaxf(red[j], red[j + off]); __syncthreads(); }
  float m = red[0]; __syncthreads();
  float p = expf(s - m);
  red[j] = p; __syncthreads();
  for(int off = 128; off; off >>= 1){ if(j < off) red[j] += red[j + off]; __syncthreads(); }
  float denom = red[0];
  a2[((size_t)bh * 256 + i) * 256 + j] = p / denom;
}

// ------------- scale maxes -------------
__global__ __launch_bounds__(256) void scale_kernel(const float* __restrict__ a2, u32* __restrict__ maxes){
  int bh = blockIdx.x, t = threadIdx.x;
  const float* p = a2 + (size_t)bh * 65536;
  float cs = 0.f, rs = 0.f;
  for(int i = 0; i < 256; i++) cs += p[i * 256 + t];
  for(int j = 0; j < 256; j++) rs += p[t * 256 + j];
  __shared__ float rc[256], rr[256];
  rc[t] = cs; rr[t] = rs; __syncthreads();
  for(int off = 128; off; off >>= 1){
    if(t < off){ rc[t] = fmaxf(rc[t], rc[t + off]); rr[t] = fmaxf(rr[t], rr[t + off]); }
    __syncthreads();
  }
  if(t == 0){
    atomicMax(&maxes[0], __float_as_uint(rc[0]));
    atomicMax(&maxes[1], __float_as_uint(rr[0]));
  }
}

// ------------- z0 = a2^T / scale and z0T = a2 / scale -------------
__global__ __launch_bounds__(256) void z0_kernel(const float* __restrict__ a2,
                                                 float* __restrict__ z, float* __restrict__ zT,
                                                 const u32* __restrict__ maxes){
  float scale = __uint_as_float(maxes[0]) * __uint_as_float(maxes[1]);
  int bh = blockIdx.y;
  int idx = blockIdx.x * 256 + threadIdx.x;
  int i = idx >> 8, j = idx & 255;
  float v = a2[(size_t)bh * 65536 + idx] / scale;
  zT[(size_t)bh * 65536 + idx] = v;
  z[(size_t)bh * 65536 + (size_t)j * 256 + i] = v;
}

// ------------- unified MFMA flash attention -------------
template<int MODE>
__global__ __launch_bounds__(256) void flash_kernel(
    const u16* __restrict__ Aex,
    const u16* __restrict__ Ah_, const u16* __restrict__ Al_,
    const u16* __restrict__ Bh_, const u16* __restrict__ Bl_,
    const u16* __restrict__ Vh_, const u16* __restrict__ Vl_,
    u16* __restrict__ o,
    float* __restrict__ pacc, float2* __restrict__ pml){
  __shared__ u32 pbuf[4][32][66];
  int w = threadIdx.x >> 6, lane = threadIdx.x & 63;
  int lr = lane & 15, lg = lane >> 4;
  int bh = blockIdx.y;
  int rowbase = blockIdx.x * 128 + w * 32;
  constexpr int NT = (MODE == 0) ? 4 : 32;
  int kbase = (MODE == 0) ? 0 : blockIdx.z * 2048;

  u16x8 afh[2][2], afl[2][2];
  #pragma unroll
  for(int mi = 0; mi < 2; mi++)
    #pragma unroll
    for(int ks = 0; ks < 2; ks++){
      int r = rowbase + mi * 16 + lr;
      if(MODE == 0){
        afh[mi][ks] = *(const u16x8*)(Aex + ((size_t)bh * 8192 + r) * 64 + ks * 32 + lg * 8);
      } else {
        size_t idx = ((size_t)bh * 256 + r) * 64 + ks * 32 + lg * 8;
        afh[mi][ks] = *(const u16x8*)(Ah_ + idx);
        afl[mi][ks] = *(const u16x8*)(Al_ + idx);
      }
    }

  f32x4 pv[2][4] = {};
  float m[2][4], l[2][4];
  #pragma unroll
  for(int mi = 0; mi < 2; mi++)
    #pragma unroll
    for(int e = 0; e < 4; e++){ m[mi][e] = -1e30f; l[mi][e] = 0.f; }

  for(int t = 0; t < NT; t++){
    u16x8 bfh[4][2], bfl[4][2];
    #pragma unroll
    for(int ni = 0; ni < 4; ni++)
      #pragma unroll
      for(int ks = 0; ks < 2; ks++){
        if(MODE == 0){
          int j = t * 64 + ni * 16 + lr;
          size_t bi = ((size_t)bh * 256 + j) * 64 + ks * 32 + lg * 8;
          bfh[ni][ks] = *(const u16x8*)(Bh_ + bi);
          bfl[ni][ks] = *(const u16x8*)(Bl_ + bi);
        } else {
          int key = kbase + t * 64 + ni * 16 + lr;
          bfh[ni][ks] = *(const u16x8*)(Bh_ + ((size_t)bh * 8192 + key) * 64 + ks * 32 + lg * 8);
        }
      }
    f32x4 sv[2][4];
    #pragma unroll
    for(int mi = 0; mi < 2; mi++)
      #pragma unroll
      for(int ni = 0; ni < 4; ni++) sv[mi][ni] = (f32x4){0.f, 0.f, 0.f, 0.f};
    #pragma unroll
    for(int ks = 0; ks < 2; ks++)
      #pragma unroll
      for(int mi = 0; mi < 2; mi++)
        #pragma unroll
        for(int ni = 0; ni < 4; ni++){
          sv[mi][ni] = mfma16(afh[mi][ks], bfh[ni][ks], sv[mi][ni]);
          if(MODE == 0) sv[mi][ni] = mfma16(afh[mi][ks], bfl[ni][ks], sv[mi][ni]);
          else          sv[mi][ni] = mfma16(afl[mi][ks], bfh[ni][ks], sv[mi][ni]);
        }
    #pragma unroll
    for(int mi = 0; mi < 2; mi++)
      #pragma unroll
      for(int e = 0; e < 4; e++){
        float mx = fmaxf(fmaxf(sv[mi][0][e], sv[mi][1][e]), fmaxf(sv[mi][2][e], sv[mi][3][e]));
        #pragma unroll
        for(int off = 1; off < 16; off <<= 1) mx = fmaxf(mx, __shfl_xor(mx, off, 64));
        float mo = m[mi][e];
        float mn = fmaxf(mo, mx);
        float fs = __expf(mo - mn);
        m[mi][e] = mn;
        float rs = 0.f;
        #pragma unroll
        for(int ni = 0; ni < 4; ni++){
          float p = __expf(sv[mi][ni][e] - mn);
          sv[mi][ni][e] = p;
          rs += p;
        }
        #pragma unroll
        for(int off = 1; off < 16; off <<= 1) rs += __shfl_xor(rs, off, 64);
        l[mi][e] = l[mi][e] * fs + rs;
        #pragma unroll
        for(int ni2 = 0; ni2 < 4; ni2++) pv[mi][ni2][e] *= fs;
      }
    #pragma unroll
    for(int mi = 0; mi < 2; mi++)
      #pragma unroll
      for(int ni = 0; ni < 4; ni++)
        #pragma unroll
        for(int e = 0; e < 4; e++){
          float p = sv[mi][ni][e];
          u16 ph = f2b(p);
          u16 plo = f2b(p - b2f(ph));
          pbuf[w][mi * 16 + lg * 4 + e][ni * 16 + lr] = (u32)ph | ((u32)plo << 16);
        }
    #pragma unroll
    for(int ks2 = 0; ks2 < 2; ks2++){
      u16x8 pah[2], pal[2];
      #pragma unroll
      for(int mi = 0; mi < 2; mi++)
        #pragma unroll
        for(int e2 = 0; e2 < 8; e2++){
          u32 tv = pbuf[w][mi * 16 + lr][ks2 * 32 + lg * 8 + e2];
          pah[mi][e2] = (u16)(tv & 0xffffu);
          pal[mi][e2] = (u16)(tv >> 16);
        }
      #pragma unroll
      for(int ni2 = 0; ni2 < 4; ni2++){
        int d = ni2 * 16 + lr;
        u16x8 vh, vl;
        if(MODE == 0){
          size_t vi = ((size_t)bh * 64 + d) * 256 + t * 64 + ks2 * 32 + lg * 8;
          vh = *(const u16x8*)(Vh_ + vi);
          vl = *(const u16x8*)(Vl_ + vi);
        } else {
          size_t vi = ((size_t)bh * 64 + d) * 8192 + kbase + t * 64 + ks2 * 32 + lg * 8;
          vh = *(const u16x8*)(Vh_ + vi);
        }
        #pragma unroll
        for(int mi = 0; mi < 2; mi++){
          pv[mi][ni2] = mfma16(pah[mi], vh, pv[mi][ni2]);
          if(MODE == 0){
            pv[mi][ni2] = mfma16(pah[mi], vl, pv[mi][ni2]);
            pv[mi][ni2] = mfma16(pal[mi], vh, pv[mi][ni2]);
          } else {
            pv[mi][ni2] = mfma16(pal[mi], vh, pv[mi][ni2]);
          }
        }
      }
    }
  }
  #pragma unroll
  for(int mi = 0; mi < 2; mi++)
    #pragma unroll
    for(int ni2 = 0; ni2 < 4; ni2++)
      #pragma unroll
      for(int e = 0; e < 4; e++){
        int row = rowbase + mi * 16 + lg * 4 + e;
        int col = ni2 * 16 + lr;
        if(MODE == 0){
          float val = pv[mi][ni2][e] / l[mi][e];
          int b = bh >> 3, h = bh & 7;
          size_t oi = ((size_t)b * 8192 + row) * 512 + h * 64 + col;
          o[oi] = f2b(val + b2f(o[oi]));
        } else {
          pacc[(((size_t)blockIdx.z * 8192) + (size_t)bh * 256 + row) * 64 + col] = pv[mi][ni2][e];
        }
      }
  if(MODE == 1 && lr == 0){
    #pragma unroll
    for(int mi = 0; mi < 2; mi++)
      #pragma unroll
      for(int e = 0; e < 4; e++){
        int row = rowbase + mi * 16 + lg * 4 + e;
        pml[(size_t)blockIdx.z * 8192 + (size_t)bh * 256 + row] = make_float2(m[mi][e], l[mi][e]);
      }
  }
}

// ------------- merge a3v split-K partials -> av fp32 -------------
__global__ __launch_bounds__(64) void a3v_merge(const float* __restrict__ pacc,
                                                const float2* __restrict__ pml,
                                                float* __restrict__ av){
  int row = blockIdx.x, d = threadIdx.x;
  float2 s[4];
  float M = -1e30f;
  #pragma unroll
  for(int p = 0; p < 4; p++){ s[p] = pml[(size_t)p * 8192 + row]; M = fmaxf(M, s[p].x); }
  float L = 0.f, acc = 0.f;
  #pragma unroll
  for(int p = 0; p < 4; p++){
    float f = __expf(s[p].x - M);
    L += s[p].y * f;
    acc += f * pacc[((size_t)p * 8192 + row) * 64 + d];
  }
  av[(size_t)row * 64 + d] = acc / L;
}

// ------------- W^T = (Z @ av)^T as bf16 hi/lo -------------
__global__ __launch_bounds__(64) void zw_kernel(const float* __restrict__ z,
                                                const float* __restrict__ av,
                                                u16* __restrict__ wth, u16* __restrict__ wtl){
  int i = blockIdx.x & 255, bh = blockIdx.x >> 8, d = threadIdx.x;
  const float* zr = z + ((size_t)bh * 256 + i) * 256;
  const float* ab = av + (size_t)bh * 256 * 64;
  float s = 0.f;
  for(int j = 0; j < 256; j++) s += zr[j] * ab[j * 64 + d];
  size_t oi = ((size_t)bh * 64 + d) * 256 + i;
  u16 hi = f2b(s);
  wth[oi] = hi;
  wtl[oi] = f2b(s - b2f(hi));
}

// ------------- depthwise conv residual -> o (bf16 token layout) -------------
__global__ __launch_bounds__(256) void conv_kernel(const u16* __restrict__ v,
                                                   const float* __restrict__ cw,
                                                   u16* __restrict__ o){
  __shared__ float wl[33];
  __shared__ u16 vl[96][64];
  int bh = blockIdx.y, b = bh >> 3, h = bh & 7;
  int r0 = blockIdx.x * 64;
  if(threadIdx.x < 33) wl[threadIdx.x] = cw[h * 33 + threadIdx.x];
  const u16* vb = v + (size_t)bh * 8192 * 64;
  for(int idx = threadIdx.x; idx < 768; idx += 256){
    int row = idx >> 3, col = (idx & 7) * 8;
    int gr = r0 - 16 + row;
    u16x8 u = {};
    if(gr >= 0 && gr < 8192) u = *(const u16x8*)(vb + (size_t)gr * 64 + col);
    *(u16x8*)&vl[row][col] = u;
  }
  __syncthreads();
  int d = threadIdx.x & 63, rbase = (threadIdx.x >> 6) * 16;
  for(int r = 0; r < 16; r++){
    int lr = rbase + r;
    float s = 0.f;
    #pragma unroll
    for(int t = 0; t < 33; t++) s += wl[t] * b2f(vl[lr + t][d]);
    size_t oi = ((size_t)b * 8192 + (r0 + rbase + r)) * 512 + h * 64 + d;
    o[oi] = f2b(s);
  }
}

extern "C" void kernel_launch(void* const* d_in, const int* in_sizes, int n_in,
                              void* d_out, int out_size, void* d_ws, size_t ws_size,
                              hipStream_t stream){
  (void)in_sizes; (void)n_in; (void)out_size; (void)ws_size;
  const float* x     = (const float*)d_in[0];
  const float* ln_w  = (const float*)d_in[1];
  const float* ln_b  = (const float*)d_in[2];
  const float* w_qkv = (const float*)d_in[3];
  const float* w_out = (const float*)d_in[4];
  const float* b_out = (const float*)d_in[5];
  const float* cw    = (const float*)d_in[6];
  float* out = (float*)d_out;

  char* base = (char*)d_ws;
  size_t off = 0;
  auto alloc = [&](size_t bytes)->void*{
    void* r = base + off; off += (bytes + 255) & ~(size_t)255; return r;
  };
  u16* xn      = (u16*)alloc(32768ull * 512 * 2);    // reused as o after QKV GEMM
  float2* stat = (float2*)alloc(32768ull * 8);
  u16* qb      = (u16*)alloc(32ull * 8192 * 64 * 2);
  u16* kb      = (u16*)alloc(32ull * 8192 * 64 * 2);
  u16* vb      = (u16*)alloc(32ull * 8192 * 64 * 2);
  u16* vtb     = (u16*)alloc(32ull * 8192 * 64 * 2);
  u16* wqkvT   = (u16*)alloc(1536ull * 512 * 2);
  u16* woutT   = (u16*)alloc(512ull * 512 * 2);
  float* wqkT  = (float*)alloc(1024ull * 512 * 4);
  float* xl    = (float*)alloc(1024ull * 512 * 4);
  float* qlf   = (float*)alloc(32ull * 256 * 64 * 4);
  float* klf   = (float*)alloc(32ull * 256 * 64 * 4);
  u16* qlh     = (u16*)alloc(32ull * 256 * 64 * 2);
  u16* qll     = (u16*)alloc(32ull * 256 * 64 * 2);
  u16* klh     = (u16*)alloc(32ull * 256 * 64 * 2);
  u16* kll     = (u16*)alloc(32ull * 256 * 64 * 2);
  float* a2b   = (float*)alloc(32ull * 65536 * 4);
  float* zA    = (float*)alloc(32ull * 65536 * 4);
  float* zAT   = (float*)alloc(32ull * 65536 * 4);
  float* zB    = (float*)alloc(32ull * 65536 * 4);
  float* zBT   = (float*)alloc(32ull * 65536 * 4);
  float* az    = (float*)alloc(32ull * 65536 * 4);
  float* azT   = (float*)alloc(32ull * 65536 * 4);   // reused as x3t
  float* x2t   = (float*)alloc(32ull * 65536 * 4);
  float* av    = (float*)alloc(32ull * 256 * 64 * 4);
  u16* wth     = (u16*)alloc(32ull * 64 * 256 * 2);
  u16* wtl     = (u16*)alloc(32ull * 64 * 256 * 2);
  u32* scal    = (u32*)alloc(256);
  u16* ob = xn;
  float* x3t = azT;
  float* pacc = az;            // dead after pinv loop
  float2* pml = (float2*)x2t;  // dead after pinv loop

  hipMemsetAsync(scal, 0, 8, stream);
  ln_kernel<<<32768, 256, 0, stream>>>(x, ln_w, ln_b, xn, stat);
  trans_kernel<<<3072, 256, 0, stream>>>(w_qkv, wqkvT, 512, 1536);
  trans_kernel<<<1024, 256, 0, stream>>>(w_out, woutT, 512, 512);
  transf32_kernel<<<2048, 256, 0, stream>>>(w_qkv, wqkT);
  gemm128<0><<<dim3(256, 12), 256, 0, stream>>>(xn, wqkvT, qb, kb, vb, nullptr, nullptr, nullptr);
  vtrans_kernel<<<dim3(128, 32), 256, 0, stream>>>(vb, vtb);
  xl_kernel<<<1024, 256, 0, stream>>>(x, stat, ln_w, ln_b, xl);
  gemm_qlkl<<<dim3(16, 16), 256, 0, stream>>>(xl, wqkT, qlf, klf, qlh, qll, klh, kll);
  a2_kernel<<<dim3(256, 32), 256, 0, stream>>>(qlf, klf, a2b);
  scale_kernel<<<32, 256, 0, stream>>>(a2b, scal);
  z0_kernel<<<dim3(256, 32), 256, 0, stream>>>(a2b, zA, zAT, scal);

  float* zP = zA; float* zPT = zAT; float* zQ = zB; float* zQT = zBT;
  for(int it = 0; it < 6; it++){
    gemm_pinv_f32<<<dim3(16, 32), 256, 0, stream>>>(a2b, zPT, az, azT, 0.f, 1.f, 1.f);
    gemm_pinv_f32<<<dim3(16, 32), 256, 0, stream>>>(az, azT, nullptr, x2t, 7.f, -1.f, 1.f);
    gemm_pinv_f32<<<dim3(16, 32), 256, 0, stream>>>(az, x2t, nullptr, x3t, 11.f, -1.f, 1.f);
    gemm_pinv_f32<<<dim3(16, 32), 256, 0, stream>>>(zP, x3t, zQ, zQT, 13.f, -1.f, 0.25f);
    float* t1 = zP; zP = zQ; zQ = t1;
    float* t2 = zPT; zPT = zQT; zQT = t2;
  }

  flash_kernel<1><<<dim3(2, 32, 4), 256, 0, stream>>>(nullptr, qlh, qll, kb, nullptr, vtb, nullptr,
                                                      nullptr, pacc, pml);
  a3v_merge<<<8192, 64, 0, stream>>>(pacc, pml, av);
  zw_kernel<<<8192, 64, 0, stream>>>(zP, av, wth, wtl);
  conv_kernel<<<dim3(128, 32), 256, 0, stream>>>(vb, cw, ob);
  flash_kernel<0><<<dim3(64, 32), 256, 0, stream>>>(qb, nullptr, nullptr, klh, kll, wth, wtl,
                                                    ob, nullptr, nullptr);
  gemm128<1><<<dim3(256, 4), 256, 0, stream>>>(ob, woutT, nullptr, nullptr, nullptr, b_out, x, out);
}

// Round 4
// 1181.286 us; speedup vs baseline: 5.8328x; 1.2221x over previous
//
#include <hip/hip_runtime.h>

#define DEV __device__ __forceinline__

typedef unsigned short u16;
typedef unsigned int   u32;
typedef u16   u16x8 __attribute__((ext_vector_type(8)));
typedef __bf16 bf16x8 __attribute__((ext_vector_type(8)));
typedef float f32x4 __attribute__((ext_vector_type(4)));

DEV float b2f(u16 u){ return __uint_as_float(((u32)u) << 16); }
DEV u16 f2b(float f){ u32 u = __float_as_uint(f); u32 r = (u + 0x7fffu + ((u >> 16) & 1u)) >> 16; return (u16)r; }

DEV f32x4 mfma16(u16x8 a, u16x8 b, f32x4 c){
  return __builtin_amdgcn_mfma_f32_16x16x32_bf16(
      __builtin_bit_cast(bf16x8, a), __builtin_bit_cast(bf16x8, b), c, 0, 0, 0);
}

// ---------------- LayerNorm: x(f32) -> xn(bf16) + per-row stats ----------------
__global__ __launch_bounds__(256) void ln_kernel(const float* __restrict__ x,
                                                 const float* __restrict__ w,
                                                 const float* __restrict__ bb,
                                                 u16* __restrict__ xn,
                                                 float2* __restrict__ stats){
  int row = blockIdx.x;
  const float* xr = x + (size_t)row * 512;
  int t = threadIdx.x;
  float2 v = *(const float2*)(xr + t * 2);
  float s = v.x + v.y;
  float sq = v.x * v.x + v.y * v.y;
  #pragma unroll
  for(int off = 32; off; off >>= 1){ s += __shfl_xor(s, off, 64); sq += __shfl_xor(sq, off, 64); }
  __shared__ float rs[4], rq[4];
  int wv = t >> 6, ln = t & 63;
  if(ln == 0){ rs[wv] = s; rq[wv] = sq; }
  __syncthreads();
  s = rs[0] + rs[1] + rs[2] + rs[3];
  sq = rq[0] + rq[1] + rq[2] + rq[3];
  float mu = s * (1.f / 512.f);
  float var = sq * (1.f / 512.f) - mu * mu;
  float rstd = rsqrtf(var + 1e-5f);
  if(t == 0) stats[row] = make_float2(mu, rstd);
  float w0 = w[t * 2], w1 = w[t * 2 + 1], b0 = bb[t * 2], b1 = bb[t * 2 + 1];
  u16 u0 = f2b((v.x - mu) * rstd * w0 + b0);
  u16 u1 = f2b((v.y - mu) * rstd * w1 + b1);
  ((u32*)(xn + (size_t)row * 512))[t] = (u32)u0 | ((u32)u1 << 16);
}

// ------------- landmark means of LN(x) in fp32: xl[b*256+j][512] -------------
__global__ __launch_bounds__(256) void xl_kernel(const float* __restrict__ x,
                                                 const float2* __restrict__ stats,
                                                 const float* __restrict__ w,
                                                 const float* __restrict__ bb,
                                                 float* __restrict__ xl){
  int blk = blockIdx.x;          // b*256 + j
  int b = blk >> 8, j = blk & 255;
  int t = threadIdx.x;
  int d0 = t * 2;
  float acc0 = 0.f, acc1 = 0.f;
  size_t row0 = (size_t)b * 8192 + (size_t)j * 32;
  for(int tt = 0; tt < 32; tt++){
    size_t row = row0 + tt;
    float2 st = stats[row];
    const float* xr = x + row * 512;
    float2 v = *(const float2*)(xr + d0);
    acc0 += (v.x - st.x) * st.y;
    acc1 += (v.y - st.x) * st.y;
  }
  float* dst = xl + (size_t)blk * 512;
  dst[d0]     = acc0 * (1.f / 32.f) * w[d0]     + bb[d0];
  dst[d0 + 1] = acc1 * (1.f / 32.f) * w[d0 + 1] + bb[d0 + 1];
}

// ------------- transpose fp32 [K][N] -> bf16 [N][K] -------------
__global__ __launch_bounds__(256) void trans_kernel(const float* __restrict__ src,
                                                    u16* __restrict__ dst, int K, int N){
  int idx = blockIdx.x * 256 + threadIdx.x;
  if(idx >= K * N) return;
  int k = idx / N, n = idx - k * N;
  dst[(size_t)n * K + k] = f2b(src[idx]);
}

// ------------- transpose fp32: first 1024 cols of w_qkv -> wqkT[1024][512] -------------
__global__ __launch_bounds__(256) void transf32_kernel(const float* __restrict__ src,
                                                       float* __restrict__ dst){
  int idx = blockIdx.x * 256 + threadIdx.x;
  int n = idx >> 9, k = idx & 511;
  dst[idx] = src[(size_t)k * 1536 + n];
}

// ------------- v [key][d] -> vt [d][key] (bf16, per bh) -------------
__global__ __launch_bounds__(256) void vtrans_kernel(const u16* __restrict__ v,
                                                     u16* __restrict__ vt){
  __shared__ u16 tile[64][72];
  int bh = blockIdx.y, n0 = blockIdx.x * 64;
  int t = threadIdx.x;
  for(int s = t; s < 512; s += 256){
    int row = s >> 3, col = (s & 7) * 8;
    *(u16x8*)&tile[row][col] = *(const u16x8*)(v + ((size_t)bh * 8192 + n0 + row) * 64 + col);
  }
  __syncthreads();
  for(int s = t; s < 512; s += 256){
    int d = s >> 3, nc = (s & 7) * 8;
    u16x8 u;
    #pragma unroll
    for(int e = 0; e < 8; e++) u[e] = tile[nc + e][d];
    *(u16x8*)(vt + ((size_t)bh * 64 + d) * 8192 + n0 + nc) = u;
  }
}

// ------------- big bf16 GEMM: A[M x 512] @ BT[N x 512]^T, 128x128 tile -------------
template<int EPI>
__global__ __launch_bounds__(256) void gemm128(const u16* __restrict__ A,
                                               const u16* __restrict__ BT,
                                               u16* __restrict__ qo, u16* __restrict__ ko, u16* __restrict__ vo,
                                               const float* __restrict__ bout,
                                               const float* __restrict__ xres,
                                               float* __restrict__ dout){
  __shared__ u16 As[128][40];
  __shared__ u16 Bs[128][40];
  const int K = 512;
  int tb_m = blockIdx.x * 128, tb_n = blockIdx.y * 128;
  int tid = threadIdx.x, lane = tid & 63, w = tid >> 6;
  int wm = (w >> 1) * 64, wn = (w & 1) * 64;
  f32x4 acc[4][4] = {};
  int srow = tid >> 1, sseg = (tid & 1) * 16;
  const u16* Ag = A + (size_t)(tb_m + srow) * K + sseg;
  const u16* Bg = BT + (size_t)(tb_n + srow) * K + sseg;
  for(int kk = 0; kk < K; kk += 32){
    __syncthreads();
    u16x8 a0 = *(const u16x8*)(Ag + kk);
    u16x8 a1 = *(const u16x8*)(Ag + kk + 8);
    u16x8 b0 = *(const u16x8*)(Bg + kk);
    u16x8 b1 = *(const u16x8*)(Bg + kk + 8);
    *(u16x8*)&As[srow][sseg]     = a0;
    *(u16x8*)&As[srow][sseg + 8] = a1;
    *(u16x8*)&Bs[srow][sseg]     = b0;
    *(u16x8*)&Bs[srow][sseg + 8] = b1;
    __syncthreads();
    int r = lane & 15, ko2 = (lane >> 4) * 8;
    u16x8 af[4], bf[4];
    #pragma unroll
    for(int mi = 0; mi < 4; mi++) af[mi] = *(const u16x8*)&As[wm + mi * 16 + r][ko2];
    #pragma unroll
    for(int ni = 0; ni < 4; ni++) bf[ni] = *(const u16x8*)&Bs[wn + ni * 16 + r][ko2];
    #pragma unroll
    for(int mi = 0; mi < 4; mi++)
      #pragma unroll
      for(int ni = 0; ni < 4; ni++)
        acc[mi][ni] = mfma16(af[mi], bf[ni], acc[mi][ni]);
  }
  int r = lane & 15, rr = (lane >> 4) * 4;
  #pragma unroll
  for(int mi = 0; mi < 4; mi++)
    #pragma unroll
    for(int ni = 0; ni < 4; ni++){
      int col = tb_n + wn + ni * 16 + r;
      #pragma unroll
      for(int e = 0; e < 4; e++){
        int row = tb_m + wm + mi * 16 + rr + e;
        float val = acc[mi][ni][e];
        if(EPI == 0){
          int t3 = col >> 9, h = (col >> 6) & 7, dh = col & 63;
          int b = row >> 13, n = row & 8191;
          if(t3 == 0) val *= 0.125f;
          u16* dst = (t3 == 0 ? qo : (t3 == 1 ? ko : vo));
          dst[(((size_t)(b * 8 + h) * 8192) + n) * 64 + dh] = f2b(val);
        } else {
          val += bout[col] + xres[(size_t)row * 512 + col];
          dout[(size_t)row * 512 + col] = val;
        }
      }
    }
}

// ------------- fp32 GEMM: ql/kl = xl @ wqkT^T, scatter epi + hi/lo split -------------
__global__ __launch_bounds__(256) void gemm_qlkl(const float* __restrict__ A,
                                                 const float* __restrict__ BT,
                                                 float* __restrict__ qlf,
                                                 float* __restrict__ klf,
                                                 u16* __restrict__ qlh, u16* __restrict__ qll,
                                                 u16* __restrict__ klh, u16* __restrict__ kll){
  __shared__ float As[64][17];
  __shared__ float Bs[64][17];
  int tb_m = blockIdx.x * 64, tb_n = blockIdx.y * 64;
  int tid = threadIdx.x;
  int ty = tid >> 4, tx = tid & 15;
  float acc[4][4] = {};
  int srow = tid >> 2, sseg = (tid & 3) * 4;
  const float* Ag = A + (size_t)(tb_m + srow) * 512 + sseg;
  const float* Bg = BT + (size_t)(tb_n + srow) * 512 + sseg;
  for(int kk = 0; kk < 512; kk += 16){
    __syncthreads();
    f32x4 a4 = *(const f32x4*)(Ag + kk);
    f32x4 b4 = *(const f32x4*)(Bg + kk);
    #pragma unroll
    for(int e = 0; e < 4; e++){ As[srow][sseg + e] = a4[e]; Bs[srow][sseg + e] = b4[e]; }
    __syncthreads();
    #pragma unroll
    for(int k2 = 0; k2 < 16; k2++){
      float a[4], b[4];
      #pragma unroll
      for(int i = 0; i < 4; i++) a[i] = As[ty * 4 + i][k2];
      #pragma unroll
      for(int jv = 0; jv < 4; jv++) b[jv] = Bs[tx * 4 + jv][k2];
      #pragma unroll
      for(int i = 0; i < 4; i++)
        #pragma unroll
        for(int jv = 0; jv < 4; jv++) acc[i][jv] += a[i] * b[jv];
    }
  }
  #pragma unroll
  for(int i = 0; i < 4; i++)
    #pragma unroll
    for(int jv = 0; jv < 4; jv++){
      int r = tb_m + ty * 4 + i;
      int c = tb_n + tx * 4 + jv;
      int b = r >> 8, jl = r & 255;
      float val = acc[i][jv];
      if(c < 512){
        float q = val * 0.125f;
        size_t qi = (((size_t)(b * 8 + (c >> 6)) * 256) + jl) * 64 + (c & 63);
        qlf[qi] = q;
        u16 hi = f2b(q);
        qlh[qi] = hi; qll[qi] = f2b(q - b2f(hi));
      } else {
        int c2 = c - 512;
        size_t ki = (((size_t)(b * 8 + (c2 >> 6)) * 256) + jl) * 64 + (c2 & 63);
        klf[ki] = val;
        u16 hi = f2b(val);
        klh[ki] = hi; kll[ki] = f2b(val - b2f(hi));
      }
    }
}

// ------------- batched fp32 pinv GEMM, k-major LDS + b128 reads -------------
__global__ __launch_bounds__(256) void gemm_pinv_f32(const float* __restrict__ A,
                                                     const float* __restrict__ BT,
                                                     float* __restrict__ Cp, float* __restrict__ CTp,
                                                     float dB, float sB, float osc){
  __shared__ float As[32][68];   // [k][row]
  __shared__ float Bs[32][68];
  int bh = blockIdx.y;
  size_t base = (size_t)bh * 65536;
  int tb_m = (blockIdx.x >> 2) * 64, tb_n = (blockIdx.x & 3) * 64;
  int tid = threadIdx.x;
  int ty = tid >> 4, tx = tid & 15;
  float acc[4][4] = {};
  int srow = tid >> 2, sseg = (tid & 3) * 8;
  const float* Ag = A + base + (size_t)(tb_m + srow) * 256 + sseg;
  const float* Bg = BT + base + (size_t)(tb_n + srow) * 256 + sseg;
  int bn = tb_n + srow;
  for(int kk = 0; kk < 256; kk += 32){
    __syncthreads();
    f32x4 a0 = *(const f32x4*)(Ag + kk);
    f32x4 a1 = *(const f32x4*)(Ag + kk + 4);
    f32x4 b0 = *(const f32x4*)(Bg + kk);
    f32x4 b1 = *(const f32x4*)(Bg + kk + 4);
    #pragma unroll
    for(int e = 0; e < 4; e++){
      As[sseg + e][srow]     = a0[e];
      As[sseg + 4 + e][srow] = a1[e];
      float v0 = sB * b0[e]; if(kk + sseg + e == bn) v0 += dB;
      float v1 = sB * b1[e]; if(kk + sseg + 4 + e == bn) v1 += dB;
      Bs[sseg + e][srow]     = v0;
      Bs[sseg + 4 + e][srow] = v1;
    }
    __syncthreads();
    #pragma unroll
    for(int k2 = 0; k2 < 32; k2++){
      f32x4 av4 = *(const f32x4*)&As[k2][ty * 4];
      f32x4 bv4 = *(const f32x4*)&Bs[k2][tx * 4];
      #pragma unroll
      for(int i = 0; i < 4; i++)
        #pragma unroll
        for(int jv = 0; jv < 4; jv++) acc[i][jv] += av4[i] * bv4[jv];
    }
  }
  #pragma unroll
  for(int i = 0; i < 4; i++)
    #pragma unroll
    for(int jv = 0; jv < 4; jv++){
      int r = tb_m + ty * 4 + i;
      int c = tb_n + tx * 4 + jv;
      float val = osc * acc[i][jv];
      if(Cp)  Cp[base + (size_t)r * 256 + c] = val;
      if(CTp) CTp[base + (size_t)c * 256 + r] = val;
    }
}

// ------------- a2 = softmax(q_l @ k_l^T) per row, fp32 -------------
__global__ __launch_bounds__(256) void a2_kernel(const float* __restrict__ qlf,
                                                 const float* __restrict__ klf,
                                                 float* __restrict__ a2){
  int i = blockIdx.x, bh = blockIdx.y, j = threadIdx.x;
  const float* qp = qlf + ((size_t)bh * 256 + i) * 64;
  const float* kp = klf + ((size_t)bh * 256 + j) * 64;
  float s = 0.f;
  #pragma unroll
  for(int d0 = 0; d0 < 16; d0++){
    f32x4 uq = *(const f32x4*)(qp + d0 * 4);
    f32x4 uk = *(const f32x4*)(kp + d0 * 4);
    #pragma unroll
    for(int e = 0; e < 4; e++) s += uq[e] * uk[e];
  }
  __shared__ float red[256];
  red[j] = s; __syncthreads();
  for(int off = 128; off; off >>= 1){ if(j < off) red[j] = fmaxf(red[j], red[j + off]); __syncthreads(); }
  float m = red[0]; __syncthreads();
  float p = expf(s - m);
  red[j] = p; __syncthreads();
  for(int off = 128; off; off >>= 1){ if(j < off) red[j] += red[j + off]; __syncthreads(); }
  float denom = red[0];
  a2[((size_t)bh * 256 + i) * 256 + j] = p / denom;
}

// ------------- scale maxes -------------
__global__ __launch_bounds__(256) void scale_kernel(const float* __restrict__ a2, u32* __restrict__ maxes){
  int bh = blockIdx.x, t = threadIdx.x;
  const float* p = a2 + (size_t)bh * 65536;
  float cs = 0.f, rs = 0.f;
  for(int i = 0; i < 256; i++) cs += p[i * 256 + t];
  for(int j = 0; j < 256; j++) rs += p[t * 256 + j];
  __shared__ float rc[256], rr[256];
  rc[t] = cs; rr[t] = rs; __syncthreads();
  for(int off = 128; off; off >>= 1){
    if(t < off){ rc[t] = fmaxf(rc[t], rc[t + off]); rr[t] = fmaxf(rr[t], rr[t + off]); }
    __syncthreads();
  }
  if(t == 0){
    atomicMax(&maxes[0], __float_as_uint(rc[0]));
    atomicMax(&maxes[1], __float_as_uint(rr[0]));
  }
}

// ------------- z0 = a2^T / scale and z0T = a2 / scale -------------
__global__ __launch_bounds__(256) void z0_kernel(const float* __restrict__ a2,
                                                 float* __restrict__ z, float* __restrict__ zT,
                                                 const u32* __restrict__ maxes){
  float scale = __uint_as_float(maxes[0]) * __uint_as_float(maxes[1]);
  int bh = blockIdx.y;
  int idx = blockIdx.x * 256 + threadIdx.x;
  int i = idx >> 8, j = idx & 255;
  float v = a2[(size_t)bh * 65536 + idx] / scale;
  zT[(size_t)bh * 65536 + idx] = v;
  z[(size_t)bh * 65536 + (size_t)j * 256 + i] = v;
}

// ------------- unified MFMA flash attention -------------
// MODE 0 (a1): A=qb exact; B=kl hi/lo; V=W^T hi/lo; 256 keys; RMW into o.
// MODE 1 (a3v): A=ql hi/lo; B=kb exact; V=v^T exact; 512-key split; partial out.
template<int MODE>
__global__ __launch_bounds__(256) void flash_kernel(
    const u16* __restrict__ Aex,
    const u16* __restrict__ Ah_, const u16* __restrict__ Al_,
    const u16* __restrict__ Bh_, const u16* __restrict__ Bl_,
    const u16* __restrict__ Vh_, const u16* __restrict__ Vl_,
    u16* __restrict__ o,
    float* __restrict__ pacc, float2* __restrict__ pml){
  __shared__ u32 pbuf[4][32][66];
  int w = threadIdx.x >> 6, lane = threadIdx.x & 63;
  int lr = lane & 15, lg = lane >> 4;
  int bh = blockIdx.y;
  int rowbase = blockIdx.x * 128 + w * 32;
  constexpr int NT = (MODE == 0) ? 4 : 8;
  int kbase = (MODE == 0) ? 0 : blockIdx.z * 512;

  u16x8 afh[2][2], afl[2][2];
  #pragma unroll
  for(int mi = 0; mi < 2; mi++)
    #pragma unroll
    for(int ks = 0; ks < 2; ks++){
      int r = rowbase + mi * 16 + lr;
      if(MODE == 0){
        afh[mi][ks] = *(const u16x8*)(Aex + ((size_t)bh * 8192 + r) * 64 + ks * 32 + lg * 8);
      } else {
        size_t idx = ((size_t)bh * 256 + r) * 64 + ks * 32 + lg * 8;
        afh[mi][ks] = *(const u16x8*)(Ah_ + idx);
        afl[mi][ks] = *(const u16x8*)(Al_ + idx);
      }
    }

  f32x4 pv[2][4] = {};
  float m[2][4], l[2][4];
  #pragma unroll
  for(int mi = 0; mi < 2; mi++)
    #pragma unroll
    for(int e = 0; e < 4; e++){ m[mi][e] = -1e30f; l[mi][e] = 0.f; }

  for(int t = 0; t < NT; t++){
    u16x8 bfh[4][2], bfl[4][2];
    #pragma unroll
    for(int ni = 0; ni < 4; ni++)
      #pragma unroll
      for(int ks = 0; ks < 2; ks++){
        if(MODE == 0){
          int j = t * 64 + ni * 16 + lr;
          size_t bi = ((size_t)bh * 256 + j) * 64 + ks * 32 + lg * 8;
          bfh[ni][ks] = *(const u16x8*)(Bh_ + bi);
          bfl[ni][ks] = *(const u16x8*)(Bl_ + bi);
        } else {
          int key = kbase + t * 64 + ni * 16 + lr;
          bfh[ni][ks] = *(const u16x8*)(Bh_ + ((size_t)bh * 8192 + key) * 64 + ks * 32 + lg * 8);
        }
      }
    f32x4 sv[2][4];
    #pragma unroll
    for(int mi = 0; mi < 2; mi++)
      #pragma unroll
      for(int ni = 0; ni < 4; ni++) sv[mi][ni] = (f32x4){0.f, 0.f, 0.f, 0.f};
    #pragma unroll
    for(int ks = 0; ks < 2; ks++)
      #pragma unroll
      for(int mi = 0; mi < 2; mi++)
        #pragma unroll
        for(int ni = 0; ni < 4; ni++){
          sv[mi][ni] = mfma16(afh[mi][ks], bfh[ni][ks], sv[mi][ni]);
          if(MODE == 0) sv[mi][ni] = mfma16(afh[mi][ks], bfl[ni][ks], sv[mi][ni]);
          else          sv[mi][ni] = mfma16(afl[mi][ks], bfh[ni][ks], sv[mi][ni]);
        }
    // online softmax: cross-lane max reduce; l kept as PER-LANE partial
    #pragma unroll
    for(int mi = 0; mi < 2; mi++)
      #pragma unroll
      for(int e = 0; e < 4; e++){
        float mx = fmaxf(fmaxf(sv[mi][0][e], sv[mi][1][e]), fmaxf(sv[mi][2][e], sv[mi][3][e]));
        #pragma unroll
        for(int off = 1; off < 16; off <<= 1) mx = fmaxf(mx, __shfl_xor(mx, off, 64));
        float mo = m[mi][e];
        float mn = fmaxf(mo, mx);
        float fs = __expf(mo - mn);
        m[mi][e] = mn;
        float rs = 0.f;
        #pragma unroll
        for(int ni = 0; ni < 4; ni++){
          float p = __expf(sv[mi][ni][e] - mn);
          sv[mi][ni][e] = p;
          rs += p;
        }
        l[mi][e] = l[mi][e] * fs + rs;
        #pragma unroll
        for(int ni2 = 0; ni2 < 4; ni2++) pv[mi][ni2][e] *= fs;
      }
    // P hi/lo pack (RNE hi via magic add, perm pack) -> LDS transpose
    #pragma unroll
    for(int mi = 0; mi < 2; mi++)
      #pragma unroll
      for(int ni = 0; ni < 4; ni++)
        #pragma unroll
        for(int e = 0; e < 4; e++){
          float p = sv[mi][ni][e];
          u32 pb = __float_as_uint(p);
          u32 rb = pb + 0x7fffu + ((pb >> 16) & 1u);
          float hif = __uint_as_float(rb & 0xffff0000u);
          u32 lob = __float_as_uint(p - hif);
          pbuf[w][mi * 16 + lg * 4 + e][ni * 16 + lr] = __builtin_amdgcn_perm(lob, rb, 0x07060302u);
        }
    #pragma unroll
    for(int ks2 = 0; ks2 < 2; ks2++){
      u16x8 pah[2], pal[2];
      #pragma unroll
      for(int mi = 0; mi < 2; mi++){
        u32 tv[8];
        #pragma unroll
        for(int e2 = 0; e2 < 8; e2++) tv[e2] = pbuf[w][mi * 16 + lr][ks2 * 32 + lg * 8 + e2];
        u32* ph = (u32*)&pah[mi];
        u32* pl = (u32*)&pal[mi];
        #pragma unroll
        for(int q = 0; q < 4; q++){
          ph[q] = __builtin_amdgcn_perm(tv[2 * q + 1], tv[2 * q], 0x05040100u);
          pl[q] = __builtin_amdgcn_perm(tv[2 * q + 1], tv[2 * q], 0x07060302u);
        }
      }
      #pragma unroll
      for(int ni2 = 0; ni2 < 4; ni2++){
        int d = ni2 * 16 + lr;
        u16x8 vh, vl;
        if(MODE == 0){
          size_t vi = ((size_t)bh * 64 + d) * 256 + t * 64 + ks2 * 32 + lg * 8;
          vh = *(const u16x8*)(Vh_ + vi);
          vl = *(const u16x8*)(Vl_ + vi);
        } else {
          size_t vi = ((size_t)bh * 64 + d) * 8192 + kbase + t * 64 + ks2 * 32 + lg * 8;
          vh = *(const u16x8*)(Vh_ + vi);
        }
        #pragma unroll
        for(int mi = 0; mi < 2; mi++){
          pv[mi][ni2] = mfma16(pah[mi], vh, pv[mi][ni2]);
          if(MODE == 0){
            pv[mi][ni2] = mfma16(pah[mi], vl, pv[mi][ni2]);
            pv[mi][ni2] = mfma16(pal[mi], vh, pv[mi][ni2]);
          } else {
            pv[mi][ni2] = mfma16(pal[mi], vh, pv[mi][ni2]);
          }
        }
      }
    }
  }
  // reduce per-lane l across the 16-lane row group
  #pragma unroll
  for(int mi = 0; mi < 2; mi++)
    #pragma unroll
    for(int e = 0; e < 4; e++){
      float lv = l[mi][e];
      #pragma unroll
      for(int off = 1; off < 16; off <<= 1) lv += __shfl_xor(lv, off, 64);
      l[mi][e] = lv;
    }
  #pragma unroll
  for(int mi = 0; mi < 2; mi++){
    #pragma unroll
    for(int e = 0; e < 4; e++){
      if(MODE == 0){
        float invl = 1.f / l[mi][e];
        int row = rowbase + mi * 16 + lg * 4 + e;
        int b = bh >> 3, h = bh & 7;
        #pragma unroll
        for(int ni2 = 0; ni2 < 4; ni2++){
          int col = ni2 * 16 + lr;
          size_t oi = ((size_t)b * 8192 + row) * 512 + h * 64 + col;
          o[oi] = f2b(pv[mi][ni2][e] * invl + b2f(o[oi]));
        }
      } else {
        int row = rowbase + mi * 16 + lg * 4 + e;
        #pragma unroll
        for(int ni2 = 0; ni2 < 4; ni2++){
          int col = ni2 * 16 + lr;
          pacc[(((size_t)blockIdx.z * 8192) + (size_t)bh * 256 + row) * 64 + col] = pv[mi][ni2][e];
        }
      }
    }
  }
  if(MODE == 1 && lr == 0){
    #pragma unroll
    for(int mi = 0; mi < 2; mi++)
      #pragma unroll
      for(int e = 0; e < 4; e++){
        int row = rowbase + mi * 16 + lg * 4 + e;
        pml[(size_t)blockIdx.z * 8192 + (size_t)bh * 256 + row] = make_float2(m[mi][e], l[mi][e]);
      }
  }
}

// ------------- merge a3v split-K partials (16) -> av fp32 -------------
__global__ __launch_bounds__(64) void a3v_merge(const float* __restrict__ pacc,
                                                const float2* __restrict__ pml,
                                                float* __restrict__ av){
  int row = blockIdx.x, d = threadIdx.x;
  float2 s[16];
  float M = -1e30f;
  #pragma unroll
  for(int p = 0; p < 16; p++){ s[p] = pml[(size_t)p * 8192 + row]; M = fmaxf(M, s[p].x); }
  float L = 0.f, acc = 0.f;
  #pragma unroll
  for(int p = 0; p < 16; p++){
    float f = __expf(s[p].x - M);
    L += s[p].y * f;
    acc += f * pacc[((size_t)p * 8192 + row) * 64 + d];
  }
  av[(size_t)row * 64 + d] = acc / L;
}

// ------------- W^T = (Z @ av)^T as bf16 hi/lo -------------
__global__ __launch_bounds__(64) void zw_kernel(const float* __restrict__ z,
                                                const float* __restrict__ av,
                                                u16* __restrict__ wth, u16* __restrict__ wtl){
  int i = blockIdx.x & 255, bh = blockIdx.x >> 8, d = threadIdx.x;
  const float* zr = z + ((size_t)bh * 256 + i) * 256;
  const float* ab = av + (size_t)bh * 256 * 64;
  float s = 0.f;
  for(int j = 0; j < 256; j++) s += zr[j] * ab[j * 64 + d];
  size_t oi = ((size_t)bh * 64 + d) * 256 + i;
  u16 hi = f2b(s);
  wth[oi] = hi;
  wtl[oi] = f2b(s - b2f(hi));
}

// ------------- depthwise conv residual -> o (bf16 token layout) -------------
__global__ __launch_bounds__(256) void conv_kernel(const u16* __restrict__ v,
                                                   const float* __restrict__ cw,
                                                   u16* __restrict__ o){
  __shared__ float wl[33];
  __shared__ u16 vl[96][64];
  int bh = blockIdx.y, b = bh >> 3, h = bh & 7;
  int r0 = blockIdx.x * 64;
  if(threadIdx.x < 33) wl[threadIdx.x] = cw[h * 33 + threadIdx.x];
  const u16* vb = v + (size_t)bh * 8192 * 64;
  for(int idx = threadIdx.x; idx < 768; idx += 256){
    int row = idx >> 3, col = (idx & 7) * 8;
    int gr = r0 - 16 + row;
    u16x8 u = {};
    if(gr >= 0 && gr < 8192) u = *(const u16x8*)(vb + (size_t)gr * 64 + col);
    *(u16x8*)&vl[row][col] = u;
  }
  __syncthreads();
  int d = threadIdx.x & 63, rbase = (threadIdx.x >> 6) * 16;
  for(int r = 0; r < 16; r++){
    int lr = rbase + r;
    float s = 0.f;
    #pragma unroll
    for(int t = 0; t < 33; t++) s += wl[t] * b2f(vl[lr + t][d]);
    size_t oi = ((size_t)b * 8192 + (r0 + rbase + r)) * 512 + h * 64 + d;
    o[oi] = f2b(s);
  }
}

extern "C" void kernel_launch(void* const* d_in, const int* in_sizes, int n_in,
                              void* d_out, int out_size, void* d_ws, size_t ws_size,
                              hipStream_t stream){
  (void)in_sizes; (void)n_in; (void)out_size; (void)ws_size;
  const float* x     = (const float*)d_in[0];
  const float* ln_w  = (const float*)d_in[1];
  const float* ln_b  = (const float*)d_in[2];
  const float* w_qkv = (const float*)d_in[3];
  const float* w_out = (const float*)d_in[4];
  const float* b_out = (const float*)d_in[5];
  const float* cw    = (const float*)d_in[6];
  float* out = (float*)d_out;

  char* base = (char*)d_ws;
  size_t off = 0;
  auto alloc = [&](size_t bytes)->void*{
    void* r = base + off; off += (bytes + 255) & ~(size_t)255; return r;
  };
  u16* xn      = (u16*)alloc(32768ull * 512 * 2);    // reused as o after QKV GEMM
  float2* stat = (float2*)alloc(32768ull * 8);
  u16* qb      = (u16*)alloc(32ull * 8192 * 64 * 2);
  u16* kb      = (u16*)alloc(32ull * 8192 * 64 * 2);
  u16* vb      = (u16*)alloc(32ull * 8192 * 64 * 2);
  u16* vtb     = (u16*)alloc(32ull * 8192 * 64 * 2);
  u16* wqkvT   = (u16*)alloc(1536ull * 512 * 2);
  u16* woutT   = (u16*)alloc(512ull * 512 * 2);
  float* wqkT  = (float*)alloc(1024ull * 512 * 4);
  float* xl    = (float*)alloc(1024ull * 512 * 4);
  float* qlf   = (float*)alloc(32ull * 256 * 64 * 4);
  float* klf   = (float*)alloc(32ull * 256 * 64 * 4);
  u16* qlh     = (u16*)alloc(32ull * 256 * 64 * 2);
  u16* qll     = (u16*)alloc(32ull * 256 * 64 * 2);
  u16* klh     = (u16*)alloc(32ull * 256 * 64 * 2);
  u16* kll     = (u16*)alloc(32ull * 256 * 64 * 2);
  float* a2b   = (float*)alloc(32ull * 65536 * 4);
  float* zA    = (float*)alloc(32ull * 65536 * 4);
  float* zAT   = (float*)alloc(32ull * 65536 * 4);
  float* zB    = (float*)alloc(32ull * 65536 * 4);
  float* zBT   = (float*)alloc(32ull * 65536 * 4);
  float* az    = (float*)alloc(32ull * 65536 * 4);
  float* azT   = (float*)alloc(32ull * 65536 * 4);   // reused as x3t
  float* x2t   = (float*)alloc(32ull * 65536 * 4);
  float* av    = (float*)alloc(32ull * 256 * 64 * 4);
  u16* wth     = (u16*)alloc(32ull * 64 * 256 * 2);
  u16* wtl     = (u16*)alloc(32ull * 64 * 256 * 2);
  u32* scal    = (u32*)alloc(256);
  u16* ob = xn;
  float* x3t = azT;
  // split-K partials: alias the contiguous dead region zB..x2t (5 x 8.4 MB)
  float* pacc = zB;            // needs 16*8192*64*4 = 33.5 MB < 42 MB
  float2* pml = (float2*)a2b;  // needs 1 MB; a2b dead after pinv loop

  hipMemsetAsync(scal, 0, 8, stream);
  ln_kernel<<<32768, 256, 0, stream>>>(x, ln_w, ln_b, xn, stat);
  trans_kernel<<<3072, 256, 0, stream>>>(w_qkv, wqkvT, 512, 1536);
  trans_kernel<<<1024, 256, 0, stream>>>(w_out, woutT, 512, 512);
  transf32_kernel<<<2048, 256, 0, stream>>>(w_qkv, wqkT);
  gemm128<0><<<dim3(256, 12), 256, 0, stream>>>(xn, wqkvT, qb, kb, vb, nullptr, nullptr, nullptr);
  vtrans_kernel<<<dim3(128, 32), 256, 0, stream>>>(vb, vtb);
  xl_kernel<<<1024, 256, 0, stream>>>(x, stat, ln_w, ln_b, xl);
  gemm_qlkl<<<dim3(16, 16), 256, 0, stream>>>(xl, wqkT, qlf, klf, qlh, qll, klh, kll);
  a2_kernel<<<dim3(256, 32), 256, 0, stream>>>(qlf, klf, a2b);
  scale_kernel<<<32, 256, 0, stream>>>(a2b, scal);
  z0_kernel<<<dim3(256, 32), 256, 0, stream>>>(a2b, zA, zAT, scal);

  float* zP = zA; float* zPT = zAT; float* zQ = zB; float* zQT = zBT;
  for(int it = 0; it < 6; it++){
    gemm_pinv_f32<<<dim3(16, 32), 256, 0, stream>>>(a2b, zPT, az, azT, 0.f, 1.f, 1.f);
    gemm_pinv_f32<<<dim3(16, 32), 256, 0, stream>>>(az, azT, nullptr, x2t, 7.f, -1.f, 1.f);
    gemm_pinv_f32<<<dim3(16, 32), 256, 0, stream>>>(az, x2t, nullptr, x3t, 11.f, -1.f, 1.f);
    gemm_pinv_f32<<<dim3(16, 32), 256, 0, stream>>>(zP, x3t, zQ, zQT, 13.f, -1.f, 0.25f);
    float* t1 = zP; zP = zQ; zQ = t1;
    float* t2 = zPT; zPT = zQT; zQT = t2;
  }

  flash_kernel<1><<<dim3(2, 32, 16), 256, 0, stream>>>(nullptr, qlh, qll, kb, nullptr, vtb, nullptr,
                                                       nullptr, pacc, pml);
  a3v_merge<<<8192, 64, 0, stream>>>(pacc, pml, av);
  zw_kernel<<<8192, 64, 0, stream>>>(zP, av, wth, wtl);
  conv_kernel<<<dim3(128, 32), 256, 0, stream>>>(vb, cw, ob);
  flash_kernel<0><<<dim3(64, 32), 256, 0, stream>>>(qb, nullptr, nullptr, klh, kll, wth, wtl,
                                                    ob, nullptr, nullptr);
  gemm128<1><<<dim3(256, 4), 256, 0, stream>>>(ob, woutT, nullptr, nullptr, nullptr, b_out, x, out);
}

// Round 6
// 1153.641 us; speedup vs baseline: 5.9726x; 1.0240x over previous
//
#include <hip/hip_runtime.h>

#define DEV __device__ __forceinline__

typedef unsigned short u16;
typedef unsigned int   u32;
typedef u16   u16x8 __attribute__((ext_vector_type(8)));
typedef __bf16 bf16x8 __attribute__((ext_vector_type(8)));
typedef float f32x4 __attribute__((ext_vector_type(4)));

DEV float b2f(u16 u){ return __uint_as_float(((u32)u) << 16); }
DEV u16 f2b(float f){ u32 u = __float_as_uint(f); u32 r = (u + 0x7fffu + ((u >> 16) & 1u)) >> 16; return (u16)r; }

DEV f32x4 mfma16(u16x8 a, u16x8 b, f32x4 c){
  return __builtin_amdgcn_mfma_f32_16x16x32_bf16(
      __builtin_bit_cast(bf16x8, a), __builtin_bit_cast(bf16x8, b), c, 0, 0, 0);
}

// ---------------- LayerNorm: x(f32) -> xn(bf16) + per-row stats ----------------
__global__ __launch_bounds__(256) void ln_kernel(const float* __restrict__ x,
                                                 const float* __restrict__ w,
                                                 const float* __restrict__ bb,
                                                 u16* __restrict__ xn,
                                                 float2* __restrict__ stats){
  int row = blockIdx.x;
  const float* xr = x + (size_t)row * 512;
  int t = threadIdx.x;
  float2 v = *(const float2*)(xr + t * 2);
  float s = v.x + v.y;
  float sq = v.x * v.x + v.y * v.y;
  #pragma unroll
  for(int off = 32; off; off >>= 1){ s += __shfl_xor(s, off, 64); sq += __shfl_xor(sq, off, 64); }
  __shared__ float rs[4], rq[4];
  int wv = t >> 6, ln = t & 63;
  if(ln == 0){ rs[wv] = s; rq[wv] = sq; }
  __syncthreads();
  s = rs[0] + rs[1] + rs[2] + rs[3];
  sq = rq[0] + rq[1] + rq[2] + rq[3];
  float mu = s * (1.f / 512.f);
  float var = sq * (1.f / 512.f) - mu * mu;
  float rstd = rsqrtf(var + 1e-5f);
  if(t == 0) stats[row] = make_float2(mu, rstd);
  float w0 = w[t * 2], w1 = w[t * 2 + 1], b0 = bb[t * 2], b1 = bb[t * 2 + 1];
  u16 u0 = f2b((v.x - mu) * rstd * w0 + b0);
  u16 u1 = f2b((v.y - mu) * rstd * w1 + b1);
  ((u32*)(xn + (size_t)row * 512))[t] = (u32)u0 | ((u32)u1 << 16);
}

// ------------- landmark means of LN(x) in fp32: xl[b*256+j][512] -------------
__global__ __launch_bounds__(256) void xl_kernel(const float* __restrict__ x,
                                                 const float2* __restrict__ stats,
                                                 const float* __restrict__ w,
                                                 const float* __restrict__ bb,
                                                 float* __restrict__ xl){
  int blk = blockIdx.x;          // b*256 + j
  int b = blk >> 8, j = blk & 255;
  int t = threadIdx.x;
  int d0 = t * 2;
  float acc0 = 0.f, acc1 = 0.f;
  size_t row0 = (size_t)b * 8192 + (size_t)j * 32;
  for(int tt = 0; tt < 32; tt++){
    size_t row = row0 + tt;
    float2 st = stats[row];
    const float* xr = x + row * 512;
    float2 v = *(const float2*)(xr + d0);
    acc0 += (v.x - st.x) * st.y;
    acc1 += (v.y - st.x) * st.y;
  }
  float* dst = xl + (size_t)blk * 512;
  dst[d0]     = acc0 * (1.f / 32.f) * w[d0]     + bb[d0];
  dst[d0 + 1] = acc1 * (1.f / 32.f) * w[d0 + 1] + bb[d0 + 1];
}

// ------------- transpose fp32 [K][N] -> bf16 [N][K] -------------
__global__ __launch_bounds__(256) void trans_kernel(const float* __restrict__ src,
                                                    u16* __restrict__ dst, int K, int N){
  int idx = blockIdx.x * 256 + threadIdx.x;
  if(idx >= K * N) return;
  int k = idx / N, n = idx - k * N;
  dst[(size_t)n * K + k] = f2b(src[idx]);
}

// ------------- transpose fp32: first 1024 cols of w_qkv -> wqkT[1024][512] -------------
__global__ __launch_bounds__(256) void transf32_kernel(const float* __restrict__ src,
                                                       float* __restrict__ dst){
  int idx = blockIdx.x * 256 + threadIdx.x;
  int n = idx >> 9, k = idx & 511;
  dst[idx] = src[(size_t)k * 1536 + n];
}

// ------------- v [key][d] -> vt [d][key] (bf16, per bh) -------------
__global__ __launch_bounds__(256) void vtrans_kernel(const u16* __restrict__ v,
                                                     u16* __restrict__ vt){
  __shared__ u16 tile[64][72];
  int bh = blockIdx.y, n0 = blockIdx.x * 64;
  int t = threadIdx.x;
  for(int s = t; s < 512; s += 256){
    int row = s >> 3, col = (s & 7) * 8;
    *(u16x8*)&tile[row][col] = *(const u16x8*)(v + ((size_t)bh * 8192 + n0 + row) * 64 + col);
  }
  __syncthreads();
  for(int s = t; s < 512; s += 256){
    int d = s >> 3, nc = (s & 7) * 8;
    u16x8 u;
    #pragma unroll
    for(int e = 0; e < 8; e++) u[e] = tile[nc + e][d];
    *(u16x8*)(vt + ((size_t)bh * 64 + d) * 8192 + n0 + nc) = u;
  }
}

// ------------- big bf16 GEMM: A[M x 512] @ BT[N x 512]^T, 128x128 tile -------------
template<int EPI>
__global__ __launch_bounds__(256) void gemm128(const u16* __restrict__ A,
                                               const u16* __restrict__ BT,
                                               u16* __restrict__ qo, u16* __restrict__ ko, u16* __restrict__ vo,
                                               const float* __restrict__ bout,
                                               const float* __restrict__ xres,
                                               float* __restrict__ dout){
  __shared__ u16 As[128][40];
  __shared__ u16 Bs[128][40];
  const int K = 512;
  int tb_m = blockIdx.x * 128, tb_n = blockIdx.y * 128;
  int tid = threadIdx.x, lane = tid & 63, w = tid >> 6;
  int wm = (w >> 1) * 64, wn = (w & 1) * 64;
  f32x4 acc[4][4] = {};
  int srow = tid >> 1, sseg = (tid & 1) * 16;
  const u16* Ag = A + (size_t)(tb_m + srow) * K + sseg;
  const u16* Bg = BT + (size_t)(tb_n + srow) * K + sseg;
  for(int kk = 0; kk < K; kk += 32){
    __syncthreads();
    u16x8 a0 = *(const u16x8*)(Ag + kk);
    u16x8 a1 = *(const u16x8*)(Ag + kk + 8);
    u16x8 b0 = *(const u16x8*)(Bg + kk);
    u16x8 b1 = *(const u16x8*)(Bg + kk + 8);
    *(u16x8*)&As[srow][sseg]     = a0;
    *(u16x8*)&As[srow][sseg + 8] = a1;
    *(u16x8*)&Bs[srow][sseg]     = b0;
    *(u16x8*)&Bs[srow][sseg + 8] = b1;
    __syncthreads();
    int r = lane & 15, ko2 = (lane >> 4) * 8;
    u16x8 af[4], bf[4];
    #pragma unroll
    for(int mi = 0; mi < 4; mi++) af[mi] = *(const u16x8*)&As[wm + mi * 16 + r][ko2];
    #pragma unroll
    for(int ni = 0; ni < 4; ni++) bf[ni] = *(const u16x8*)&Bs[wn + ni * 16 + r][ko2];
    #pragma unroll
    for(int mi = 0; mi < 4; mi++)
      #pragma unroll
      for(int ni = 0; ni < 4; ni++)
        acc[mi][ni] = mfma16(af[mi], bf[ni], acc[mi][ni]);
  }
  int r = lane & 15, rr = (lane >> 4) * 4;
  #pragma unroll
  for(int mi = 0; mi < 4; mi++)
    #pragma unroll
    for(int ni = 0; ni < 4; ni++){
      int col = tb_n + wn + ni * 16 + r;
      #pragma unroll
      for(int e = 0; e < 4; e++){
        int row = tb_m + wm + mi * 16 + rr + e;
        float val = acc[mi][ni][e];
        if(EPI == 0){
          int t3 = col >> 9, h = (col >> 6) & 7, dh = col & 63;
          int b = row >> 13, n = row & 8191;
          if(t3 == 0) val *= 0.125f;
          u16* dst = (t3 == 0 ? qo : (t3 == 1 ? ko : vo));
          dst[(((size_t)(b * 8 + h) * 8192) + n) * 64 + dh] = f2b(val);
        } else {
          val += bout[col] + xres[(size_t)row * 512 + col];
          dout[(size_t)row * 512 + col] = val;
        }
      }
    }
}

// ------------- fp32 GEMM: ql/kl = xl @ wqkT^T, scatter epi + hi/lo split -------------
__global__ __launch_bounds__(256) void gemm_qlkl(const float* __restrict__ A,
                                                 const float* __restrict__ BT,
                                                 float* __restrict__ qlf,
                                                 float* __restrict__ klf,
                                                 u16* __restrict__ qlh, u16* __restrict__ qll,
                                                 u16* __restrict__ klh, u16* __restrict__ kll){
  __shared__ float As[64][17];
  __shared__ float Bs[64][17];
  int tb_m = blockIdx.x * 64, tb_n = blockIdx.y * 64;
  int tid = threadIdx.x;
  int ty = tid >> 4, tx = tid & 15;
  float acc[4][4] = {};
  int srow = tid >> 2, sseg = (tid & 3) * 4;
  const float* Ag = A + (size_t)(tb_m + srow) * 512 + sseg;
  const float* Bg = BT + (size_t)(tb_n + srow) * 512 + sseg;
  for(int kk = 0; kk < 512; kk += 16){
    __syncthreads();
    f32x4 a4 = *(const f32x4*)(Ag + kk);
    f32x4 b4 = *(const f32x4*)(Bg + kk);
    #pragma unroll
    for(int e = 0; e < 4; e++){ As[srow][sseg + e] = a4[e]; Bs[srow][sseg + e] = b4[e]; }
    __syncthreads();
    #pragma unroll
    for(int k2 = 0; k2 < 16; k2++){
      float a[4], b[4];
      #pragma unroll
      for(int i = 0; i < 4; i++) a[i] = As[ty * 4 + i][k2];
      #pragma unroll
      for(int jv = 0; jv < 4; jv++) b[jv] = Bs[tx * 4 + jv][k2];
      #pragma unroll
      for(int i = 0; i < 4; i++)
        #pragma unroll
        for(int jv = 0; jv < 4; jv++) acc[i][jv] += a[i] * b[jv];
    }
  }
  #pragma unroll
  for(int i = 0; i < 4; i++)
    #pragma unroll
    for(int jv = 0; jv < 4; jv++){
      int r = tb_m + ty * 4 + i;
      int c = tb_n + tx * 4 + jv;
      int b = r >> 8, jl = r & 255;
      float val = acc[i][jv];
      if(c < 512){
        float q = val * 0.125f;
        size_t qi = (((size_t)(b * 8 + (c >> 6)) * 256) + jl) * 64 + (c & 63);
        qlf[qi] = q;
        u16 hi = f2b(q);
        qlh[qi] = hi; qll[qi] = f2b(q - b2f(hi));
      } else {
        int c2 = c - 512;
        size_t ki = (((size_t)(b * 8 + (c2 >> 6)) * 256) + jl) * 64 + (c2 & 63);
        klf[ki] = val;
        u16 hi = f2b(val);
        klh[ki] = hi; kll[ki] = f2b(val - b2f(hi));
      }
    }
}

// ------------- batched fp32 pinv GEMM: C = osc*(A @ (dB*I + sB*B)), all row-major -------------
__global__ __launch_bounds__(256) void gemm_pinv_f32(const float* __restrict__ A,
                                                     const float* __restrict__ B,
                                                     float* __restrict__ C,
                                                     float dB, float sB, float osc){
  __shared__ float As[32][68];   // [k][m]
  __shared__ float Bs[32][68];   // [k][n]
  int bh = blockIdx.y;
  size_t base = (size_t)bh * 65536;
  int tb_m = (blockIdx.x >> 2) * 64, tb_n = (blockIdx.x & 3) * 64;
  int tid = threadIdx.x;
  int ty = tid >> 4, tx = tid & 15;
  float acc[4][4] = {};
  int arow = tid >> 2, aseg = (tid & 3) * 8;
  int brow = tid >> 3, bcol = (tid & 7) * 8;
  const float* Ag = A + base + (size_t)(tb_m + arow) * 256 + aseg;
  const float* Bg = B + base + (size_t)brow * 256 + tb_n + bcol;
  for(int kk = 0; kk < 256; kk += 32){
    __syncthreads();
    f32x4 a0 = *(const f32x4*)(Ag + kk);
    f32x4 a1 = *(const f32x4*)(Ag + kk + 4);
    const float* bp = Bg + (size_t)kk * 256;
    f32x4 b0 = *(const f32x4*)bp;
    f32x4 b1 = *(const f32x4*)(bp + 4);
    int krow = kk + brow;
    #pragma unroll
    for(int e = 0; e < 4; e++){
      As[aseg + e][arow]     = a0[e];
      As[aseg + 4 + e][arow] = a1[e];
    }
    f32x4 v0, v1;
    #pragma unroll
    for(int e = 0; e < 4; e++){
      float t0 = sB * b0[e]; if(krow == tb_n + bcol + e)     t0 += dB;
      float t1 = sB * b1[e]; if(krow == tb_n + bcol + 4 + e) t1 += dB;
      v0[e] = t0; v1[e] = t1;
    }
    *(f32x4*)&Bs[brow][bcol]     = v0;
    *(f32x4*)&Bs[brow][bcol + 4] = v1;
    __syncthreads();
    #pragma unroll
    for(int k2 = 0; k2 < 32; k2++){
      f32x4 av4 = *(const f32x4*)&As[k2][ty * 4];
      f32x4 bv4 = *(const f32x4*)&Bs[k2][tx * 4];
      #pragma unroll
      for(int i = 0; i < 4; i++)
        #pragma unroll
        for(int jv = 0; jv < 4; jv++) acc[i][jv] += av4[i] * bv4[jv];
    }
  }
  #pragma unroll
  for(int i = 0; i < 4; i++){
    int r = tb_m + ty * 4 + i;
    f32x4 ov;
    #pragma unroll
    for(int jv = 0; jv < 4; jv++) ov[jv] = osc * acc[i][jv];
    *(f32x4*)(C + base + (size_t)r * 256 + tb_n + tx * 4) = ov;
  }
}

// ------------- a2 = softmax(q_l @ k_l^T) per row, fp32 -------------
__global__ __launch_bounds__(256) void a2_kernel(const float* __restrict__ qlf,
                                                 const float* __restrict__ klf,
                                                 float* __restrict__ a2){
  int i = blockIdx.x, bh = blockIdx.y, j = threadIdx.x;
  const float* qp = qlf + ((size_t)bh * 256 + i) * 64;
  const float* kp = klf + ((size_t)bh * 256 + j) * 64;
  float s = 0.f;
  #pragma unroll
  for(int d0 = 0; d0 < 16; d0++){
    f32x4 uq = *(const f32x4*)(qp + d0 * 4);
    f32x4 uk = *(const f32x4*)(kp + d0 * 4);
    #pragma unroll
    for(int e = 0; e < 4; e++) s += uq[e] * uk[e];
  }
  __shared__ float red[256];
  red[j] = s; __syncthreads();
  for(int off = 128; off; off >>= 1){ if(j < off) red[j] = fmaxf(red[j], red[j + off]); __syncthreads(); }
  float m = red[0]; __syncthreads();
  float p = expf(s - m);
  red[j] = p; __syncthreads();
  for(int off = 128; off; off >>= 1){ if(j < off) red[j] += red[j + off]; __syncthreads(); }
  float denom = red[0];
  a2[((size_t)bh * 256 + i) * 256 + j] = p / denom;
}

// ------------- scale maxes -------------
__global__ __launch_bounds__(256) void scale_kernel(const float* __restrict__ a2, u32* __restrict__ maxes){
  int bh = blockIdx.x, t = threadIdx.x;
  const float* p = a2 + (size_t)bh * 65536;
  float cs = 0.f, rs = 0.f;
  for(int i = 0; i < 256; i++) cs += p[i * 256 + t];
  for(int j = 0; j < 256; j++) rs += p[t * 256 + j];
  __shared__ float rc[256], rr[256];
  rc[t] = cs; rr[t] = rs; __syncthreads();
  for(int off = 128; off; off >>= 1){
    if(t < off){ rc[t] = fmaxf(rc[t], rc[t + off]); rr[t] = fmaxf(rr[t], rr[t + off]); }
    __syncthreads();
  }
  if(t == 0){
    atomicMax(&maxes[0], __float_as_uint(rc[0]));
    atomicMax(&maxes[1], __float_as_uint(rr[0]));
  }
}

// ------------- z0 = a2^T / scale (tiled transpose) -------------
__global__ __launch_bounds__(256) void z0_kernel(const float* __restrict__ a2,
                                                 float* __restrict__ z,
                                                 const u32* __restrict__ maxes){
  __shared__ float tile[64][65];
  float inv = 1.f / (__uint_as_float(maxes[0]) * __uint_as_float(maxes[1]));
  int bh = blockIdx.z;
  int i0 = blockIdx.x * 64, j0 = blockIdx.y * 64;
  const float* src = a2 + (size_t)bh * 65536;
  float* dst = z + (size_t)bh * 65536;
  for(int s = threadIdx.x; s < 1024; s += 256){
    int r = s >> 4, c4 = (s & 15) * 4;
    f32x4 v = *(const f32x4*)(src + (size_t)(i0 + r) * 256 + j0 + c4);
    #pragma unroll
    for(int e = 0; e < 4; e++) tile[r][c4 + e] = v[e];
  }
  __syncthreads();
  for(int s = threadIdx.x; s < 1024; s += 256){
    int jr = s >> 4, c4 = (s & 15) * 4;
    f32x4 v;
    #pragma unroll
    for(int e = 0; e < 4; e++) v[e] = tile[c4 + e][jr] * inv;
    *(f32x4*)(dst + (size_t)(j0 + jr) * 256 + i0 + c4) = v;
  }
}

// ------------- unified MFMA flash attention (no online max; scores are O(1)) -------------
// MODE 0 (a1): A=qb exact; B=kl hi/lo; V=W^T hi/lo; 256 keys; RMW into o.
// MODE 1 (a3v): A=ql hi/lo; B=kb exact; V=v^T exact; 512-key split; partial out.
template<int MODE>
__global__ __launch_bounds__(256) void flash_kernel(
    const u16* __restrict__ Aex,
    const u16* __restrict__ Ah_, const u16* __restrict__ Al_,
    const u16* __restrict__ Bh_, const u16* __restrict__ Bl_,
    const u16* __restrict__ Vh_, const u16* __restrict__ Vl_,
    u16* __restrict__ o,
    float* __restrict__ pacc, float* __restrict__ plo){
  __shared__ u32 pbuf[4][32][35];
  int w = threadIdx.x >> 6, lane = threadIdx.x & 63;
  int lr = lane & 15, lg = lane >> 4;
  int bh = blockIdx.y;
  int rowbase = blockIdx.x * 128 + w * 32;
  constexpr int NT = (MODE == 0) ? 4 : 8;
  int kbase = (MODE == 0) ? 0 : blockIdx.z * 512;

  u16x8 afh[2][2], afl[2][2];
  #pragma unroll
  for(int mi = 0; mi < 2; mi++)
    #pragma unroll
    for(int ks = 0; ks < 2; ks++){
      int r = rowbase + mi * 16 + lr;
      if(MODE == 0){
        afh[mi][ks] = *(const u16x8*)(Aex + ((size_t)bh * 8192 + r) * 64 + ks * 32 + lg * 8);
      } else {
        size_t idx = ((size_t)bh * 256 + r) * 64 + ks * 32 + lg * 8;
        afh[mi][ks] = *(const u16x8*)(Ah_ + idx);
        afl[mi][ks] = *(const u16x8*)(Al_ + idx);
      }
    }

  f32x4 pv[2][4] = {};
  float l[2][4] = {};

  for(int t = 0; t < NT; t++){
    u16x8 bfh[4][2], bfl[4][2];
    #pragma unroll
    for(int ni = 0; ni < 4; ni++)
      #pragma unroll
      for(int ks = 0; ks < 2; ks++){
        if(MODE == 0){
          int j = t * 64 + ni * 16 + lr;
          size_t bi = ((size_t)bh * 256 + j) * 64 + ks * 32 + lg * 8;
          bfh[ni][ks] = *(const u16x8*)(Bh_ + bi);
          bfl[ni][ks] = *(const u16x8*)(Bl_ + bi);
        } else {
          int key = kbase + t * 64 + ni * 16 + lr;
          bfh[ni][ks] = *(const u16x8*)(Bh_ + ((size_t)bh * 8192 + key) * 64 + ks * 32 + lg * 8);
        }
      }
    f32x4 sv[2][4];
    #pragma unroll
    for(int mi = 0; mi < 2; mi++)
      #pragma unroll
      for(int ni = 0; ni < 4; ni++) sv[mi][ni] = (f32x4){0.f, 0.f, 0.f, 0.f};
    #pragma unroll
    for(int ks = 0; ks < 2; ks++)
      #pragma unroll
      for(int mi = 0; mi < 2; mi++)
        #pragma unroll
        for(int ni = 0; ni < 4; ni++){
          sv[mi][ni] = mfma16(afh[mi][ks], bfh[ni][ks], sv[mi][ni]);
          if(MODE == 0) sv[mi][ni] = mfma16(afh[mi][ks], bfl[ni][ks], sv[mi][ni]);
          else          sv[mi][ni] = mfma16(afl[mi][ks], bfh[ni][ks], sv[mi][ni]);
        }
    // exp + per-lane l accumulation (no max, no shuffles)
    #pragma unroll
    for(int mi = 0; mi < 2; mi++)
      #pragma unroll
      for(int ni = 0; ni < 4; ni++)
        #pragma unroll
        for(int e = 0; e < 4; e++){
          float p = __expf(sv[mi][ni][e]);
          sv[mi][ni][e] = p;
          l[mi][e] += p;
        }
    // per 32-key half: pack P hi/lo -> LDS transpose -> PV
    #pragma unroll
    for(int half = 0; half < 2; half++){
      #pragma unroll
      for(int mi = 0; mi < 2; mi++)
        #pragma unroll
        for(int nh = 0; nh < 2; nh++)
          #pragma unroll
          for(int e = 0; e < 4; e++){
            float p = sv[mi][2 * half + nh][e];
            u32 pb = __float_as_uint(p);
            u32 rb = pb + 0x7fffu + ((pb >> 16) & 1u);
            float hif = __uint_as_float(rb & 0xffff0000u);
            u32 lob = __float_as_uint(p - hif);
            pbuf[w][mi * 16 + lg * 4 + e][nh * 16 + lr] = __builtin_amdgcn_perm(lob, rb, 0x07060302u);
          }
      u16x8 pah[2], pal[2];
      #pragma unroll
      for(int mi = 0; mi < 2; mi++){
        u32 tv[8];
        #pragma unroll
        for(int e2 = 0; e2 < 8; e2++) tv[e2] = pbuf[w][mi * 16 + lr][lg * 8 + e2];
        u32* ph = (u32*)&pah[mi];
        u32* pl = (u32*)&pal[mi];
        #pragma unroll
        for(int q = 0; q < 4; q++){
          ph[q] = __builtin_amdgcn_perm(tv[2 * q + 1], tv[2 * q], 0x05040100u);
          pl[q] = __builtin_amdgcn_perm(tv[2 * q + 1], tv[2 * q], 0x07060302u);
        }
      }
      #pragma unroll
      for(int ni2 = 0; ni2 < 4; ni2++){
        int d = ni2 * 16 + lr;
        u16x8 vh, vl;
        if(MODE == 0){
          size_t vi = ((size_t)bh * 64 + d) * 256 + t * 64 + half * 32 + lg * 8;
          vh = *(const u16x8*)(Vh_ + vi);
          vl = *(const u16x8*)(Vl_ + vi);
        } else {
          size_t vi = ((size_t)bh * 64 + d) * 8192 + kbase + t * 64 + half * 32 + lg * 8;
          vh = *(const u16x8*)(Vh_ + vi);
        }
        #pragma unroll
        for(int mi = 0; mi < 2; mi++){
          pv[mi][ni2] = mfma16(pah[mi], vh, pv[mi][ni2]);
          if(MODE == 0){
            pv[mi][ni2] = mfma16(pah[mi], vl, pv[mi][ni2]);
            pv[mi][ni2] = mfma16(pal[mi], vh, pv[mi][ni2]);
          } else {
            pv[mi][ni2] = mfma16(pal[mi], vh, pv[mi][ni2]);
          }
        }
      }
    }
  }
  // reduce per-lane l across the 16-lane row group
  #pragma unroll
  for(int mi = 0; mi < 2; mi++)
    #pragma unroll
    for(int e = 0; e < 4; e++){
      float lv = l[mi][e];
      #pragma unroll
      for(int off = 1; off < 16; off <<= 1) lv += __shfl_xor(lv, off, 64);
      l[mi][e] = lv;
    }
  #pragma unroll
  for(int mi = 0; mi < 2; mi++){
    #pragma unroll
    for(int e = 0; e < 4; e++){
      int row = rowbase + mi * 16 + lg * 4 + e;
      if(MODE == 0){
        float invl = 1.f / l[mi][e];
        int b = bh >> 3, h = bh & 7;
        #pragma unroll
        for(int ni2 = 0; ni2 < 4; ni2++){
          int col = ni2 * 16 + lr;
          size_t oi = ((size_t)b * 8192 + row) * 512 + h * 64 + col;
          o[oi] = f2b(pv[mi][ni2][e] * invl + b2f(o[oi]));
        }
      } else {
        #pragma unroll
        for(int ni2 = 0; ni2 < 4; ni2++){
          int col = ni2 * 16 + lr;
          pacc[(((size_t)blockIdx.z * 8192) + (size_t)bh * 256 + row) * 64 + col] = pv[mi][ni2][e];
        }
      }
    }
  }
  if(MODE == 1 && lr == 0){
    #pragma unroll
    for(int mi = 0; mi < 2; mi++)
      #pragma unroll
      for(int e = 0; e < 4; e++){
        int row = rowbase + mi * 16 + lg * 4 + e;
        plo[(size_t)blockIdx.z * 8192 + (size_t)bh * 256 + row] = l[mi][e];
      }
  }
}

// ------------- merge a3v split-K partials (16) -> av fp32 -------------
__global__ __launch_bounds__(64) void a3v_merge(const float* __restrict__ pacc,
                                                const float* __restrict__ plo,
                                                float* __restrict__ av){
  int row = blockIdx.x, d = threadIdx.x;
  float L = 0.f, acc = 0.f;
  #pragma unroll
  for(int p = 0; p < 16; p++){
    L += plo[(size_t)p * 8192 + row];
    acc += pacc[((size_t)p * 8192 + row) * 64 + d];
  }
  av[(size_t)row * 64 + d] = acc / L;
}

// ------------- W^T = (Z @ av)^T as bf16 hi/lo -------------
__global__ __launch_bounds__(64) void zw_kernel(const float* __restrict__ z,
                                                const float* __restrict__ av,
                                                u16* __restrict__ wth, u16* __restrict__ wtl){
  int i = blockIdx.x & 255, bh = blockIdx.x >> 8, d = threadIdx.x;
  const float* zr = z + ((size_t)bh * 256 + i) * 256;
  const float* ab = av + (size_t)bh * 256 * 64;
  float s = 0.f;
  for(int j = 0; j < 256; j++) s += zr[j] * ab[j * 64 + d];
  size_t oi = ((size_t)bh * 64 + d) * 256 + i;
  u16 hi = f2b(s);
  wth[oi] = hi;
  wtl[oi] = f2b(s - b2f(hi));
}

// ------------- depthwise conv residual -> o (bf16 token layout), register-blocked -------------
__global__ __launch_bounds__(256) void conv_kernel(const u16* __restrict__ v,
                                                   const float* __restrict__ cw,
                                                   u16* __restrict__ o){
  __shared__ float wl[33];
  __shared__ float vt[64][104];   // [d][local row]; stride 104 floats = 416 B (16B-aligned rows)
  int bh = blockIdx.y, b = bh >> 3, h = bh & 7;
  int r0 = blockIdx.x * 64;
  if(threadIdx.x < 33) wl[threadIdx.x] = cw[h * 33 + threadIdx.x];
  const u16* vb = v + (size_t)bh * 8192 * 64;
  for(int idx = threadIdx.x; idx < 768; idx += 256){
    int row = idx >> 3, c8 = (idx & 7) * 8;
    int gr = r0 - 16 + row;
    u16x8 u = {};
    if(gr >= 0 && gr < 8192) u = *(const u16x8*)(vb + (size_t)gr * 64 + c8);
    #pragma unroll
    for(int e = 0; e < 8; e++) vt[c8 + e][row] = b2f(u[e]);
  }
  __syncthreads();
  int d = threadIdx.x & 63, g = threadIdx.x >> 6;
  float vin[48];
  #pragma unroll
  for(int i = 0; i < 12; i++){
    f32x4 q4 = *(const f32x4*)&vt[d][g * 16 + i * 4];
    #pragma unroll
    for(int e = 0; e < 4; e++) vin[i * 4 + e] = q4[e];
  }
  float acc[16] = {};
  #pragma unroll
  for(int t = 0; t < 33; t++){
    float wt = wl[t];
    #pragma unroll
    for(int r = 0; r < 16; r++) acc[r] += wt * vin[r + t];
  }
  #pragma unroll
  for(int r = 0; r < 16; r++){
    size_t oi = ((size_t)b * 8192 + (r0 + g * 16 + r)) * 512 + h * 64 + d;
    o[oi] = f2b(acc[r]);
  }
}

extern "C" void kernel_launch(void* const* d_in, const int* in_sizes, int n_in,
                              void* d_out, int out_size, void* d_ws, size_t ws_size,
                              hipStream_t stream){
  (void)in_sizes; (void)n_in; (void)out_size; (void)ws_size;
  const float* x     = (const float*)d_in[0];
  const float* ln_w  = (const float*)d_in[1];
  const float* ln_b  = (const float*)d_in[2];
  const float* w_qkv = (const float*)d_in[3];
  const float* w_out = (const float*)d_in[4];
  const float* b_out = (const float*)d_in[5];
  const float* cw    = (const float*)d_in[6];
  float* out = (float*)d_out;

  char* base = (char*)d_ws;
  size_t off = 0;
  auto alloc = [&](size_t bytes)->void*{
    void* r = base + off; off += (bytes + 255) & ~(size_t)255; return r;
  };
  u16* xn      = (u16*)alloc(32768ull * 512 * 2);    // reused as o after QKV GEMM
  float2* stat = (float2*)alloc(32768ull * 8);
  u16* qb      = (u16*)alloc(32ull * 8192 * 64 * 2);
  u16* kb      = (u16*)alloc(32ull * 8192 * 64 * 2);
  u16* vb      = (u16*)alloc(32ull * 8192 * 64 * 2);
  u16* vtb     = (u16*)alloc(32ull * 8192 * 64 * 2);
  u16* wqkvT   = (u16*)alloc(1536ull * 512 * 2);
  u16* woutT   = (u16*)alloc(512ull * 512 * 2);
  float* wqkT  = (float*)alloc(1024ull * 512 * 4);
  float* xl    = (float*)alloc(1024ull * 512 * 4);
  float* qlf   = (float*)alloc(32ull * 256 * 64 * 4);
  float* klf   = (float*)alloc(32ull * 256 * 64 * 4);
  u16* qlh     = (u16*)alloc(32ull * 256 * 64 * 2);
  u16* qll     = (u16*)alloc(32ull * 256 * 64 * 2);
  u16* klh     = (u16*)alloc(32ull * 256 * 64 * 2);
  u16* kll     = (u16*)alloc(32ull * 256 * 64 * 2);
  float* a2b   = (float*)alloc(32ull * 65536 * 4);
  float* zA    = (float*)alloc(32ull * 65536 * 4);
  float* zB    = (float*)alloc(32ull * 65536 * 4);   // pacc aliases zB..x3 (33.55 MB) after pinv
  float* az    = (float*)alloc(32ull * 65536 * 4);
  float* x2    = (float*)alloc(32ull * 65536 * 4);
  float* x3    = (float*)alloc(32ull * 65536 * 4);
  float* av    = (float*)alloc(32ull * 256 * 64 * 4);
  u16* wth     = (u16*)alloc(32ull * 64 * 256 * 2);
  u16* wtl     = (u16*)alloc(32ull * 64 * 256 * 2);
  u32* scal    = (u32*)alloc(256);
  u16* ob = xn;
  // after the pinv loop zP ends at zA; zB, az, x2, x3 are dead and contiguous:
  // 4 x 8,388,608 B = 33,554,432 B = exactly 16 split-K slabs of 8192*64*4.
  float* pacc = zB;
  float* plo  = a2b;   // dead after pinv loop; needs 16*8192*4 = 512 KB

  hipMemsetAsync(scal, 0, 8, stream);
  ln_kernel<<<32768, 256, 0, stream>>>(x, ln_w, ln_b, xn, stat);
  trans_kernel<<<3072, 256, 0, stream>>>(w_qkv, wqkvT, 512, 1536);
  trans_kernel<<<1024, 256, 0, stream>>>(w_out, woutT, 512, 512);
  transf32_kernel<<<2048, 256, 0, stream>>>(w_qkv, wqkT);
  gemm128<0><<<dim3(256, 12), 256, 0, stream>>>(xn, wqkvT, qb, kb, vb, nullptr, nullptr, nullptr);
  vtrans_kernel<<<dim3(128, 32), 256, 0, stream>>>(vb, vtb);
  xl_kernel<<<1024, 256, 0, stream>>>(x, stat, ln_w, ln_b, xl);
  gemm_qlkl<<<dim3(16, 16), 256, 0, stream>>>(xl, wqkT, qlf, klf, qlh, qll, klh, kll);
  a2_kernel<<<dim3(256, 32), 256, 0, stream>>>(qlf, klf, a2b);
  scale_kernel<<<32, 256, 0, stream>>>(a2b, scal);
  z0_kernel<<<dim3(4, 4, 32), 256, 0, stream>>>(a2b, zA, scal);

  float* zP = zA; float* zQ = zB;
  for(int it = 0; it < 6; it++){
    gemm_pinv_f32<<<dim3(16, 32), 256, 0, stream>>>(a2b, zP, az, 0.f, 1.f, 1.f);
    gemm_pinv_f32<<<dim3(16, 32), 256, 0, stream>>>(az, az, x2, 7.f, -1.f, 1.f);
    gemm_pinv_f32<<<dim3(16, 32), 256, 0, stream>>>(az, x2, x3, 11.f, -1.f, 1.f);
    gemm_pinv_f32<<<dim3(16, 32), 256, 0, stream>>>(zP, x3, zQ, 13.f, -1.f, 0.25f);
    float* t1 = zP; zP = zQ; zQ = t1;
  }

  flash_kernel<1><<<dim3(2, 32, 16), 256, 0, stream>>>(nullptr, qlh, qll, kb, nullptr, vtb, nullptr,
                                                       nullptr, pacc, plo);
  a3v_merge<<<8192, 64, 0, stream>>>(pacc, plo, av);
  zw_kernel<<<8192, 64, 0, stream>>>(zP, av, wth, wtl);
  conv_kernel<<<dim3(128, 32), 256, 0, stream>>>(vb, cw, ob);
  flash_kernel<0><<<dim3(64, 32), 256, 0, stream>>>(qb, nullptr, nullptr, klh, kll, wth, wtl,
                                                    ob, nullptr, nullptr);
  gemm128<1><<<dim3(256, 4), 256, 0, stream>>>(ob, woutT, nullptr, nullptr, nullptr, b_out, x, out);
}

// Round 7
// 1077.919 us; speedup vs baseline: 6.3921x; 1.0702x over previous
//
#include <hip/hip_runtime.h>

#define DEV __device__ __forceinline__

typedef unsigned short u16;
typedef unsigned int   u32;
typedef u16   u16x8 __attribute__((ext_vector_type(8)));
typedef __bf16 bf16x8 __attribute__((ext_vector_type(8)));
typedef float f32x4 __attribute__((ext_vector_type(4)));

DEV float b2f(u16 u){ return __uint_as_float(((u32)u) << 16); }
DEV u16 f2b(float f){ u32 u = __float_as_uint(f); u32 r = (u + 0x7fffu + ((u >> 16) & 1u)) >> 16; return (u16)r; }

DEV f32x4 mfma16(u16x8 a, u16x8 b, f32x4 c){
  return __builtin_amdgcn_mfma_f32_16x16x32_bf16(
      __builtin_bit_cast(bf16x8, a), __builtin_bit_cast(bf16x8, b), c, 0, 0, 0);
}

// ---------------- LayerNorm: x(f32) -> xn(bf16) + per-row stats ----------------
__global__ __launch_bounds__(256) void ln_kernel(const float* __restrict__ x,
                                                 const float* __restrict__ w,
                                                 const float* __restrict__ bb,
                                                 u16* __restrict__ xn,
                                                 float2* __restrict__ stats){
  int row = blockIdx.x;
  const float* xr = x + (size_t)row * 512;
  int t = threadIdx.x;
  float2 v = *(const float2*)(xr + t * 2);
  float s = v.x + v.y;
  float sq = v.x * v.x + v.y * v.y;
  #pragma unroll
  for(int off = 32; off; off >>= 1){ s += __shfl_xor(s, off, 64); sq += __shfl_xor(sq, off, 64); }
  __shared__ float rs[4], rq[4];
  int wv = t >> 6, ln = t & 63;
  if(ln == 0){ rs[wv] = s; rq[wv] = sq; }
  __syncthreads();
  s = rs[0] + rs[1] + rs[2] + rs[3];
  sq = rq[0] + rq[1] + rq[2] + rq[3];
  float mu = s * (1.f / 512.f);
  float var = sq * (1.f / 512.f) - mu * mu;
  float rstd = rsqrtf(var + 1e-5f);
  if(t == 0) stats[row] = make_float2(mu, rstd);
  float w0 = w[t * 2], w1 = w[t * 2 + 1], b0 = bb[t * 2], b1 = bb[t * 2 + 1];
  u16 u0 = f2b((v.x - mu) * rstd * w0 + b0);
  u16 u1 = f2b((v.y - mu) * rstd * w1 + b1);
  ((u32*)(xn + (size_t)row * 512))[t] = (u32)u0 | ((u32)u1 << 16);
}

// ------------- landmark means of LN(x) in fp32: xl[b*256+j][512] -------------
__global__ __launch_bounds__(256) void xl_kernel(const float* __restrict__ x,
                                                 const float2* __restrict__ stats,
                                                 const float* __restrict__ w,
                                                 const float* __restrict__ bb,
                                                 float* __restrict__ xl){
  int blk = blockIdx.x;          // b*256 + j
  int b = blk >> 8, j = blk & 255;
  int t = threadIdx.x;
  int d0 = t * 2;
  float acc0 = 0.f, acc1 = 0.f;
  size_t row0 = (size_t)b * 8192 + (size_t)j * 32;
  for(int tt = 0; tt < 32; tt++){
    size_t row = row0 + tt;
    float2 st = stats[row];
    const float* xr = x + row * 512;
    float2 v = *(const float2*)(xr + d0);
    acc0 += (v.x - st.x) * st.y;
    acc1 += (v.y - st.x) * st.y;
  }
  float* dst = xl + (size_t)blk * 512;
  dst[d0]     = acc0 * (1.f / 32.f) * w[d0]     + bb[d0];
  dst[d0 + 1] = acc1 * (1.f / 32.f) * w[d0 + 1] + bb[d0 + 1];
}

// ------------- transpose fp32 [K][N] -> bf16 [N][K] -------------
__global__ __launch_bounds__(256) void trans_kernel(const float* __restrict__ src,
                                                    u16* __restrict__ dst, int K, int N){
  int idx = blockIdx.x * 256 + threadIdx.x;
  if(idx >= K * N) return;
  int k = idx / N, n = idx - k * N;
  dst[(size_t)n * K + k] = f2b(src[idx]);
}

// ------------- transpose fp32: first 1024 cols of w_qkv -> wqkT[1024][512] -------------
__global__ __launch_bounds__(256) void transf32_kernel(const float* __restrict__ src,
                                                       float* __restrict__ dst){
  int idx = blockIdx.x * 256 + threadIdx.x;
  int n = idx >> 9, k = idx & 511;
  dst[idx] = src[(size_t)k * 1536 + n];
}

// ------------- v [key][d] -> vt [d][key] (bf16, per bh) -------------
__global__ __launch_bounds__(256) void vtrans_kernel(const u16* __restrict__ v,
                                                     u16* __restrict__ vt){
  __shared__ u16 tile[64][72];
  int bh = blockIdx.y, n0 = blockIdx.x * 64;
  int t = threadIdx.x;
  for(int s = t; s < 512; s += 256){
    int row = s >> 3, col = (s & 7) * 8;
    *(u16x8*)&tile[row][col] = *(const u16x8*)(v + ((size_t)bh * 8192 + n0 + row) * 64 + col);
  }
  __syncthreads();
  for(int s = t; s < 512; s += 256){
    int d = s >> 3, nc = (s & 7) * 8;
    u16x8 u;
    #pragma unroll
    for(int e = 0; e < 8; e++) u[e] = tile[nc + e][d];
    *(u16x8*)(vt + ((size_t)bh * 64 + d) * 8192 + n0 + nc) = u;
  }
}

// ------------- big bf16 GEMM: A[M x 512] @ BT[N x 512]^T, 128x128 tile -------------
template<int EPI>
__global__ __launch_bounds__(256) void gemm128(const u16* __restrict__ A,
                                               const u16* __restrict__ BT,
                                               u16* __restrict__ qo, u16* __restrict__ ko, u16* __restrict__ vo,
                                               const float* __restrict__ bout,
                                               const float* __restrict__ xres,
                                               float* __restrict__ dout){
  __shared__ u16 As[128][40];
  __shared__ u16 Bs[128][40];
  const int K = 512;
  int tb_m = blockIdx.x * 128, tb_n = blockIdx.y * 128;
  int tid = threadIdx.x, lane = tid & 63, w = tid >> 6;
  int wm = (w >> 1) * 64, wn = (w & 1) * 64;
  f32x4 acc[4][4] = {};
  int srow = tid >> 1, sseg = (tid & 1) * 16;
  const u16* Ag = A + (size_t)(tb_m + srow) * K + sseg;
  const u16* Bg = BT + (size_t)(tb_n + srow) * K + sseg;
  for(int kk = 0; kk < K; kk += 32){
    __syncthreads();
    u16x8 a0 = *(const u16x8*)(Ag + kk);
    u16x8 a1 = *(const u16x8*)(Ag + kk + 8);
    u16x8 b0 = *(const u16x8*)(Bg + kk);
    u16x8 b1 = *(const u16x8*)(Bg + kk + 8);
    *(u16x8*)&As[srow][sseg]     = a0;
    *(u16x8*)&As[srow][sseg + 8] = a1;
    *(u16x8*)&Bs[srow][sseg]     = b0;
    *(u16x8*)&Bs[srow][sseg + 8] = b1;
    __syncthreads();
    int r = lane & 15, ko2 = (lane >> 4) * 8;
    u16x8 af[4], bf[4];
    #pragma unroll
    for(int mi = 0; mi < 4; mi++) af[mi] = *(const u16x8*)&As[wm + mi * 16 + r][ko2];
    #pragma unroll
    for(int ni = 0; ni < 4; ni++) bf[ni] = *(const u16x8*)&Bs[wn + ni * 16 + r][ko2];
    #pragma unroll
    for(int mi = 0; mi < 4; mi++)
      #pragma unroll
      for(int ni = 0; ni < 4; ni++)
        acc[mi][ni] = mfma16(af[mi], bf[ni], acc[mi][ni]);
  }
  int r = lane & 15, rr = (lane >> 4) * 4;
  #pragma unroll
  for(int mi = 0; mi < 4; mi++)
    #pragma unroll
    for(int ni = 0; ni < 4; ni++){
      int col = tb_n + wn + ni * 16 + r;
      #pragma unroll
      for(int e = 0; e < 4; e++){
        int row = tb_m + wm + mi * 16 + rr + e;
        float val = acc[mi][ni][e];
        if(EPI == 0){
          int t3 = col >> 9, h = (col >> 6) & 7, dh = col & 63;
          int b = row >> 13, n = row & 8191;
          if(t3 == 0) val *= 0.125f;
          u16* dst = (t3 == 0 ? qo : (t3 == 1 ? ko : vo));
          dst[(((size_t)(b * 8 + h) * 8192) + n) * 64 + dh] = f2b(val);
        } else {
          val += bout[col] + xres[(size_t)row * 512 + col];
          dout[(size_t)row * 512 + col] = val;
        }
      }
    }
}

// ------------- fp32 GEMM: ql/kl = xl @ wqkT^T, scatter epi + hi/lo split -------------
__global__ __launch_bounds__(256) void gemm_qlkl(const float* __restrict__ A,
                                                 const float* __restrict__ BT,
                                                 float* __restrict__ qlf,
                                                 float* __restrict__ klf,
                                                 u16* __restrict__ qlh, u16* __restrict__ qll,
                                                 u16* __restrict__ klh, u16* __restrict__ kll){
  __shared__ float As[64][17];
  __shared__ float Bs[64][17];
  int tb_m = blockIdx.x * 64, tb_n = blockIdx.y * 64;
  int tid = threadIdx.x;
  int ty = tid >> 4, tx = tid & 15;
  float acc[4][4] = {};
  int srow = tid >> 2, sseg = (tid & 3) * 4;
  const float* Ag = A + (size_t)(tb_m + srow) * 512 + sseg;
  const float* Bg = BT + (size_t)(tb_n + srow) * 512 + sseg;
  for(int kk = 0; kk < 512; kk += 16){
    __syncthreads();
    f32x4 a4 = *(const f32x4*)(Ag + kk);
    f32x4 b4 = *(const f32x4*)(Bg + kk);
    #pragma unroll
    for(int e = 0; e < 4; e++){ As[srow][sseg + e] = a4[e]; Bs[srow][sseg + e] = b4[e]; }
    __syncthreads();
    #pragma unroll
    for(int k2 = 0; k2 < 16; k2++){
      float a[4], b[4];
      #pragma unroll
      for(int i = 0; i < 4; i++) a[i] = As[ty * 4 + i][k2];
      #pragma unroll
      for(int jv = 0; jv < 4; jv++) b[jv] = Bs[tx * 4 + jv][k2];
      #pragma unroll
      for(int i = 0; i < 4; i++)
        #pragma unroll
        for(int jv = 0; jv < 4; jv++) acc[i][jv] += a[i] * b[jv];
    }
  }
  #pragma unroll
  for(int i = 0; i < 4; i++)
    #pragma unroll
    for(int jv = 0; jv < 4; jv++){
      int r = tb_m + ty * 4 + i;
      int c = tb_n + tx * 4 + jv;
      int b = r >> 8, jl = r & 255;
      float val = acc[i][jv];
      if(c < 512){
        float q = val * 0.125f;
        size_t qi = (((size_t)(b * 8 + (c >> 6)) * 256) + jl) * 64 + (c & 63);
        qlf[qi] = q;
        u16 hi = f2b(q);
        qlh[qi] = hi; qll[qi] = f2b(q - b2f(hi));
      } else {
        int c2 = c - 512;
        size_t ki = (((size_t)(b * 8 + (c2 >> 6)) * 256) + jl) * 64 + (c2 & 63);
        klf[ki] = val;
        u16 hi = f2b(val);
        klh[ki] = hi; kll[ki] = f2b(val - b2f(hi));
      }
    }
}

// ------------- batched fp32 pinv GEMM: C = osc*(A @ (dB*I + sB*B)), KCHUNK=64 -------------
__global__ __launch_bounds__(256) void gemm_pinv_f32(const float* __restrict__ A,
                                                     const float* __restrict__ B,
                                                     float* __restrict__ C,
                                                     float dB, float sB, float osc){
  __shared__ float As[64][68];   // [k][m]
  __shared__ float Bs[64][68];   // [k][n]
  int bh = blockIdx.y;
  size_t base = (size_t)bh * 65536;
  int tb_m = (blockIdx.x >> 2) * 64, tb_n = (blockIdx.x & 3) * 64;
  int tid = threadIdx.x;
  int ty = tid >> 4, tx = tid & 15;
  float acc[4][4] = {};
  int arow = tid >> 2, acol = (tid & 3) * 16;
  int brow = tid >> 3, bcol = (tid & 7) * 8;
  const float* Ag = A + base + (size_t)(tb_m + arow) * 256 + acol;
  const float* Bg = B + base + (size_t)brow * 256 + tb_n + bcol;
  for(int kk = 0; kk < 256; kk += 64){
    f32x4 a[4];
    #pragma unroll
    for(int q = 0; q < 4; q++) a[q] = *(const f32x4*)(Ag + kk + q * 4);
    f32x4 b[2][2];
    #pragma unroll
    for(int rr = 0; rr < 2; rr++){
      const float* bp = Bg + (size_t)(kk + rr * 32) * 256;
      b[rr][0] = *(const f32x4*)bp;
      b[rr][1] = *(const f32x4*)(bp + 4);
    }
    __syncthreads();
    #pragma unroll
    for(int q = 0; q < 4; q++)
      #pragma unroll
      for(int e = 0; e < 4; e++)
        As[acol + q * 4 + e][arow] = a[q][e];
    #pragma unroll
    for(int rr = 0; rr < 2; rr++){
      int krow = kk + rr * 32 + brow;
      f32x4 v0, v1;
      #pragma unroll
      for(int e = 0; e < 4; e++){
        float t0 = sB * b[rr][0][e]; if(krow == tb_n + bcol + e)     t0 += dB;
        float t1 = sB * b[rr][1][e]; if(krow == tb_n + bcol + 4 + e) t1 += dB;
        v0[e] = t0; v1[e] = t1;
      }
      *(f32x4*)&Bs[rr * 32 + brow][bcol]     = v0;
      *(f32x4*)&Bs[rr * 32 + brow][bcol + 4] = v1;
    }
    __syncthreads();
    #pragma unroll
    for(int k2 = 0; k2 < 64; k2++){
      f32x4 av4 = *(const f32x4*)&As[k2][ty * 4];
      f32x4 bv4 = *(const f32x4*)&Bs[k2][tx * 4];
      #pragma unroll
      for(int i = 0; i < 4; i++)
        #pragma unroll
        for(int jv = 0; jv < 4; jv++) acc[i][jv] += av4[i] * bv4[jv];
    }
  }
  #pragma unroll
  for(int i = 0; i < 4; i++){
    int r = tb_m + ty * 4 + i;
    f32x4 ov;
    #pragma unroll
    for(int jv = 0; jv < 4; jv++) ov[jv] = osc * acc[i][jv];
    *(f32x4*)(C + base + (size_t)r * 256 + tb_n + tx * 4) = ov;
  }
}

// ------------- a2 = softmax(q_l @ k_l^T) per row, fp32 -------------
__global__ __launch_bounds__(256) void a2_kernel(const float* __restrict__ qlf,
                                                 const float* __restrict__ klf,
                                                 float* __restrict__ a2){
  int i = blockIdx.x, bh = blockIdx.y, j = threadIdx.x;
  const float* qp = qlf + ((size_t)bh * 256 + i) * 64;
  const float* kp = klf + ((size_t)bh * 256 + j) * 64;
  float s = 0.f;
  #pragma unroll
  for(int d0 = 0; d0 < 16; d0++){
    f32x4 uq = *(const f32x4*)(qp + d0 * 4);
    f32x4 uk = *(const f32x4*)(kp + d0 * 4);
    #pragma unroll
    for(int e = 0; e < 4; e++) s += uq[e] * uk[e];
  }
  __shared__ float red[256];
  red[j] = s; __syncthreads();
  for(int off = 128; off; off >>= 1){ if(j < off) red[j] = fmaxf(red[j], red[j + off]); __syncthreads(); }
  float m = red[0]; __syncthreads();
  float p = expf(s - m);
  red[j] = p; __syncthreads();
  for(int off = 128; off; off >>= 1){ if(j < off) red[j] += red[j + off]; __syncthreads(); }
  float denom = red[0];
  a2[((size_t)bh * 256 + i) * 256 + j] = p / denom;
}

// ------------- scale maxes -------------
__global__ __launch_bounds__(256) void scale_kernel(const float* __restrict__ a2, u32* __restrict__ maxes){
  int bh = blockIdx.x, t = threadIdx.x;
  const float* p = a2 + (size_t)bh * 65536;
  float cs = 0.f, rs = 0.f;
  for(int i = 0; i < 256; i++) cs += p[i * 256 + t];
  for(int j = 0; j < 256; j++) rs += p[t * 256 + j];
  __shared__ float rc[256], rr[256];
  rc[t] = cs; rr[t] = rs; __syncthreads();
  for(int off = 128; off; off >>= 1){
    if(t < off){ rc[t] = fmaxf(rc[t], rc[t + off]); rr[t] = fmaxf(rr[t], rr[t + off]); }
    __syncthreads();
  }
  if(t == 0){
    atomicMax(&maxes[0], __float_as_uint(rc[0]));
    atomicMax(&maxes[1], __float_as_uint(rr[0]));
  }
}

// ------------- z0 = a2^T / scale (tiled transpose) -------------
__global__ __launch_bounds__(256) void z0_kernel(const float* __restrict__ a2,
                                                 float* __restrict__ z,
                                                 const u32* __restrict__ maxes){
  __shared__ float tile[64][65];
  float inv = 1.f / (__uint_as_float(maxes[0]) * __uint_as_float(maxes[1]));
  int bh = blockIdx.z;
  int i0 = blockIdx.x * 64, j0 = blockIdx.y * 64;
  const float* src = a2 + (size_t)bh * 65536;
  float* dst = z + (size_t)bh * 65536;
  for(int s = threadIdx.x; s < 1024; s += 256){
    int r = s >> 4, c4 = (s & 15) * 4;
    f32x4 v = *(const f32x4*)(src + (size_t)(i0 + r) * 256 + j0 + c4);
    #pragma unroll
    for(int e = 0; e < 4; e++) tile[r][c4 + e] = v[e];
  }
  __syncthreads();
  for(int s = threadIdx.x; s < 1024; s += 256){
    int jr = s >> 4, c4 = (s & 15) * 4;
    f32x4 v;
    #pragma unroll
    for(int e = 0; e < 4; e++) v[e] = tile[c4 + e][jr] * inv;
    *(f32x4*)(dst + (size_t)(j0 + jr) * 256 + i0 + c4) = v;
  }
}

// ------------- unified MFMA flash attention (no online max; per-half processing) -------------
// MODE 0 (a1): A=qb exact; B=kl hi/lo; V=W^T hi/lo; 256 keys; RMW into o.
// MODE 1 (a3v): A=ql hi/lo; B=kb exact; V=v^T exact; 512-key split; partial out.
template<int MODE>
__global__ __launch_bounds__(256, 3) void flash_kernel(
    const u16* __restrict__ Aex,
    const u16* __restrict__ Ah_, const u16* __restrict__ Al_,
    const u16* __restrict__ Bh_, const u16* __restrict__ Bl_,
    const u16* __restrict__ Vh_, const u16* __restrict__ Vl_,
    u16* __restrict__ o,
    float* __restrict__ pacc, float* __restrict__ plo){
  __shared__ u32 pbuf[4][32][35];
  int w = threadIdx.x >> 6, lane = threadIdx.x & 63;
  int lr = lane & 15, lg = lane >> 4;
  int bh = blockIdx.y;
  int rowbase = blockIdx.x * 128 + w * 32;
  constexpr int NT = (MODE == 0) ? 4 : 8;
  int kbase = (MODE == 0) ? 0 : blockIdx.z * 512;

  u16x8 afh[2][2], afl[2][2];
  #pragma unroll
  for(int mi = 0; mi < 2; mi++)
    #pragma unroll
    for(int ks = 0; ks < 2; ks++){
      int r = rowbase + mi * 16 + lr;
      if(MODE == 0){
        afh[mi][ks] = *(const u16x8*)(Aex + ((size_t)bh * 8192 + r) * 64 + ks * 32 + lg * 8);
      } else {
        size_t idx = ((size_t)bh * 256 + r) * 64 + ks * 32 + lg * 8;
        afh[mi][ks] = *(const u16x8*)(Ah_ + idx);
        afl[mi][ks] = *(const u16x8*)(Al_ + idx);
      }
    }

  f32x4 pv[2][4] = {};
  float l[2][4] = {};

  for(int t = 0; t < NT; t++){
    #pragma unroll
    for(int half = 0; half < 2; half++){
      int koff = t * 64 + half * 32;
      // B frags for these 32 keys (2 ni groups)
      u16x8 bfh[2][2], bfl[2][2];
      #pragma unroll
      for(int ni = 0; ni < 2; ni++)
        #pragma unroll
        for(int ks = 0; ks < 2; ks++){
          if(MODE == 0){
            int j = koff + ni * 16 + lr;
            size_t bi = ((size_t)bh * 256 + j) * 64 + ks * 32 + lg * 8;
            bfh[ni][ks] = *(const u16x8*)(Bh_ + bi);
            bfl[ni][ks] = *(const u16x8*)(Bl_ + bi);
          } else {
            int key = kbase + koff + ni * 16 + lr;
            bfh[ni][ks] = *(const u16x8*)(Bh_ + ((size_t)bh * 8192 + key) * 64 + ks * 32 + lg * 8);
          }
        }
      // S = Q @ K^T for 32 keys
      f32x4 sv[2][2];
      #pragma unroll
      for(int mi = 0; mi < 2; mi++)
        #pragma unroll
        for(int ni = 0; ni < 2; ni++) sv[mi][ni] = (f32x4){0.f, 0.f, 0.f, 0.f};
      #pragma unroll
      for(int ks = 0; ks < 2; ks++)
        #pragma unroll
        for(int mi = 0; mi < 2; mi++)
          #pragma unroll
          for(int ni = 0; ni < 2; ni++){
            sv[mi][ni] = mfma16(afh[mi][ks], bfh[ni][ks], sv[mi][ni]);
            if(MODE == 0) sv[mi][ni] = mfma16(afh[mi][ks], bfl[ni][ks], sv[mi][ni]);
            else          sv[mi][ni] = mfma16(afl[mi][ks], bfh[ni][ks], sv[mi][ni]);
          }
      // exp + per-lane l accumulation; pack hi/lo -> LDS transpose
      #pragma unroll
      for(int mi = 0; mi < 2; mi++)
        #pragma unroll
        for(int ni = 0; ni < 2; ni++)
          #pragma unroll
          for(int e = 0; e < 4; e++){
            float p = __expf(sv[mi][ni][e]);
            l[mi][e] += p;
            u32 pb = __float_as_uint(p);
            u32 rb = pb + 0x7fffu + ((pb >> 16) & 1u);
            float hif = __uint_as_float(rb & 0xffff0000u);
            u32 lob = __float_as_uint(p - hif);
            pbuf[w][mi * 16 + lg * 4 + e][ni * 16 + lr] = __builtin_amdgcn_perm(lob, rb, 0x07060302u);
          }
      // read P^T fragments
      u16x8 pah[2], pal[2];
      #pragma unroll
      for(int mi = 0; mi < 2; mi++){
        u32 tv[8];
        #pragma unroll
        for(int e2 = 0; e2 < 8; e2++) tv[e2] = pbuf[w][mi * 16 + lr][lg * 8 + e2];
        u32* ph = (u32*)&pah[mi];
        u32* pl = (u32*)&pal[mi];
        #pragma unroll
        for(int q = 0; q < 4; q++){
          ph[q] = __builtin_amdgcn_perm(tv[2 * q + 1], tv[2 * q], 0x05040100u);
          pl[q] = __builtin_amdgcn_perm(tv[2 * q + 1], tv[2 * q], 0x07060302u);
        }
      }
      // PV over 32 keys
      #pragma unroll
      for(int ni2 = 0; ni2 < 4; ni2++){
        int d = ni2 * 16 + lr;
        u16x8 vh, vl;
        if(MODE == 0){
          size_t vi = ((size_t)bh * 64 + d) * 256 + koff + lg * 8;
          vh = *(const u16x8*)(Vh_ + vi);
          vl = *(const u16x8*)(Vl_ + vi);
        } else {
          size_t vi = ((size_t)bh * 64 + d) * 8192 + kbase + koff + lg * 8;
          vh = *(const u16x8*)(Vh_ + vi);
        }
        #pragma unroll
        for(int mi = 0; mi < 2; mi++){
          pv[mi][ni2] = mfma16(pah[mi], vh, pv[mi][ni2]);
          if(MODE == 0){
            pv[mi][ni2] = mfma16(pah[mi], vl, pv[mi][ni2]);
            pv[mi][ni2] = mfma16(pal[mi], vh, pv[mi][ni2]);
          } else {
            pv[mi][ni2] = mfma16(pal[mi], vh, pv[mi][ni2]);
          }
        }
      }
    }
  }
  // reduce per-lane l across the 16-lane row group
  #pragma unroll
  for(int mi = 0; mi < 2; mi++)
    #pragma unroll
    for(int e = 0; e < 4; e++){
      float lv = l[mi][e];
      #pragma unroll
      for(int off = 1; off < 16; off <<= 1) lv += __shfl_xor(lv, off, 64);
      l[mi][e] = lv;
    }
  #pragma unroll
  for(int mi = 0; mi < 2; mi++){
    #pragma unroll
    for(int e = 0; e < 4; e++){
      int row = rowbase + mi * 16 + lg * 4 + e;
      if(MODE == 0){
        float invl = 1.f / l[mi][e];
        int b = bh >> 3, h = bh & 7;
        #pragma unroll
        for(int ni2 = 0; ni2 < 4; ni2++){
          int col = ni2 * 16 + lr;
          size_t oi = ((size_t)b * 8192 + row) * 512 + h * 64 + col;
          o[oi] = f2b(pv[mi][ni2][e] * invl + b2f(o[oi]));
        }
      } else {
        #pragma unroll
        for(int ni2 = 0; ni2 < 4; ni2++){
          int col = ni2 * 16 + lr;
          pacc[(((size_t)blockIdx.z * 8192) + (size_t)bh * 256 + row) * 64 + col] = pv[mi][ni2][e];
        }
      }
    }
  }
  if(MODE == 1 && lr == 0){
    #pragma unroll
    for(int mi = 0; mi < 2; mi++)
      #pragma unroll
      for(int e = 0; e < 4; e++){
        int row = rowbase + mi * 16 + lg * 4 + e;
        plo[(size_t)blockIdx.z * 8192 + (size_t)bh * 256 + row] = l[mi][e];
      }
  }
}

// ------------- merge a3v split-K partials (16) -> av fp32 -------------
__global__ __launch_bounds__(64) void a3v_merge(const float* __restrict__ pacc,
                                                const float* __restrict__ plo,
                                                float* __restrict__ av){
  int row = blockIdx.x, d = threadIdx.x;
  float L = 0.f, acc = 0.f;
  #pragma unroll
  for(int p = 0; p < 16; p++){
    L += plo[(size_t)p * 8192 + row];
    acc += pacc[((size_t)p * 8192 + row) * 64 + d];
  }
  av[(size_t)row * 64 + d] = acc / L;
}

// ------------- W^T = (Z @ av)^T as bf16 hi/lo -------------
__global__ __launch_bounds__(64) void zw_kernel(const float* __restrict__ z,
                                                const float* __restrict__ av,
                                                u16* __restrict__ wth, u16* __restrict__ wtl){
  int i = blockIdx.x & 255, bh = blockIdx.x >> 8, d = threadIdx.x;
  const float* zr = z + ((size_t)bh * 256 + i) * 256;
  const float* ab = av + (size_t)bh * 256 * 64;
  float s = 0.f;
  for(int j = 0; j < 256; j++) s += zr[j] * ab[j * 64 + d];
  size_t oi = ((size_t)bh * 64 + d) * 256 + i;
  u16 hi = f2b(s);
  wth[oi] = hi;
  wtl[oi] = f2b(s - b2f(hi));
}

// ------------- depthwise conv residual -> o (bf16 token layout), register-blocked -------------
__global__ __launch_bounds__(256) void conv_kernel(const u16* __restrict__ v,
                                                   const float* __restrict__ cw,
                                                   u16* __restrict__ o){
  __shared__ float wl[33];
  __shared__ float vt[64][104];   // [d][local row]; stride 104 floats = 416 B (16B-aligned rows)
  int bh = blockIdx.y, b = bh >> 3, h = bh & 7;
  int r0 = blockIdx.x * 64;
  if(threadIdx.x < 33) wl[threadIdx.x] = cw[h * 33 + threadIdx.x];
  const u16* vb = v + (size_t)bh * 8192 * 64;
  for(int idx = threadIdx.x; idx < 768; idx += 256){
    int row = idx >> 3, c8 = (idx & 7) * 8;
    int gr = r0 - 16 + row;
    u16x8 u = {};
    if(gr >= 0 && gr < 8192) u = *(const u16x8*)(vb + (size_t)gr * 64 + c8);
    #pragma unroll
    for(int e = 0; e < 8; e++) vt[c8 + e][row] = b2f(u[e]);
  }
  __syncthreads();
  int d = threadIdx.x & 63, g = threadIdx.x >> 6;
  float vin[48];
  #pragma unroll
  for(int i = 0; i < 12; i++){
    f32x4 q4 = *(const f32x4*)&vt[d][g * 16 + i * 4];
    #pragma unroll
    for(int e = 0; e < 4; e++) vin[i * 4 + e] = q4[e];
  }
  float acc[16] = {};
  #pragma unroll
  for(int t = 0; t < 33; t++){
    float wt = wl[t];
    #pragma unroll
    for(int r = 0; r < 16; r++) acc[r] += wt * vin[r + t];
  }
  #pragma unroll
  for(int r = 0; r < 16; r++){
    size_t oi = ((size_t)b * 8192 + (r0 + g * 16 + r)) * 512 + h * 64 + d;
    o[oi] = f2b(acc[r]);
  }
}

extern "C" void kernel_launch(void* const* d_in, const int* in_sizes, int n_in,
                              void* d_out, int out_size, void* d_ws, size_t ws_size,
                              hipStream_t stream){
  (void)in_sizes; (void)n_in; (void)out_size; (void)ws_size;
  const float* x     = (const float*)d_in[0];
  const float* ln_w  = (const float*)d_in[1];
  const float* ln_b  = (const float*)d_in[2];
  const float* w_qkv = (const float*)d_in[3];
  const float* w_out = (const float*)d_in[4];
  const float* b_out = (const float*)d_in[5];
  const float* cw    = (const float*)d_in[6];
  float* out = (float*)d_out;

  char* base = (char*)d_ws;
  size_t off = 0;
  auto alloc = [&](size_t bytes)->void*{
    void* r = base + off; off += (bytes + 255) & ~(size_t)255; return r;
  };
  u16* xn      = (u16*)alloc(32768ull * 512 * 2);    // reused as o after QKV GEMM
  float2* stat = (float2*)alloc(32768ull * 8);
  u16* qb      = (u16*)alloc(32ull * 8192 * 64 * 2);
  u16* kb      = (u16*)alloc(32ull * 8192 * 64 * 2);
  u16* vb      = (u16*)alloc(32ull * 8192 * 64 * 2);
  u16* vtb     = (u16*)alloc(32ull * 8192 * 64 * 2);
  u16* wqkvT   = (u16*)alloc(1536ull * 512 * 2);
  u16* woutT   = (u16*)alloc(512ull * 512 * 2);
  float* wqkT  = (float*)alloc(1024ull * 512 * 4);
  float* xl    = (float*)alloc(1024ull * 512 * 4);
  float* qlf   = (float*)alloc(32ull * 256 * 64 * 4);
  float* klf   = (float*)alloc(32ull * 256 * 64 * 4);
  u16* qlh     = (u16*)alloc(32ull * 256 * 64 * 2);
  u16* qll     = (u16*)alloc(32ull * 256 * 64 * 2);
  u16* klh     = (u16*)alloc(32ull * 256 * 64 * 2);
  u16* kll     = (u16*)alloc(32ull * 256 * 64 * 2);
  float* a2b   = (float*)alloc(32ull * 65536 * 4);
  float* zA    = (float*)alloc(32ull * 65536 * 4);
  float* zB    = (float*)alloc(32ull * 65536 * 4);   // pacc aliases zB..x3 (33.55 MB) after pinv
  float* az    = (float*)alloc(32ull * 65536 * 4);
  float* x2    = (float*)alloc(32ull * 65536 * 4);
  float* x3    = (float*)alloc(32ull * 65536 * 4);
  float* av    = (float*)alloc(32ull * 256 * 64 * 4);
  u16* wth     = (u16*)alloc(32ull * 64 * 256 * 2);
  u16* wtl     = (u16*)alloc(32ull * 64 * 256 * 2);
  u32* scal    = (u32*)alloc(256);
  u16* ob = xn;
  // after the pinv loop zP ends at zA; zB, az, x2, x3 are dead and contiguous:
  // 4 x 8,388,608 B = 33,554,432 B = exactly 16 split-K slabs of 8192*64*4.
  float* pacc = zB;
  float* plo  = a2b;   // dead after pinv loop; needs 16*8192*4 = 512 KB

  hipMemsetAsync(scal, 0, 8, stream);
  ln_kernel<<<32768, 256, 0, stream>>>(x, ln_w, ln_b, xn, stat);
  trans_kernel<<<3072, 256, 0, stream>>>(w_qkv, wqkvT, 512, 1536);
  trans_kernel<<<1024, 256, 0, stream>>>(w_out, woutT, 512, 512);
  transf32_kernel<<<2048, 256, 0, stream>>>(w_qkv, wqkT);
  gemm128<0><<<dim3(256, 12), 256, 0, stream>>>(xn, wqkvT, qb, kb, vb, nullptr, nullptr, nullptr);
  vtrans_kernel<<<dim3(128, 32), 256, 0, stream>>>(vb, vtb);
  xl_kernel<<<1024, 256, 0, stream>>>(x, stat, ln_w, ln_b, xl);
  gemm_qlkl<<<dim3(16, 16), 256, 0, stream>>>(xl, wqkT, qlf, klf, qlh, qll, klh, kll);
  a2_kernel<<<dim3(256, 32), 256, 0, stream>>>(qlf, klf, a2b);
  scale_kernel<<<32, 256, 0, stream>>>(a2b, scal);
  z0_kernel<<<dim3(4, 4, 32), 256, 0, stream>>>(a2b, zA, scal);

  float* zP = zA; float* zQ = zB;
  for(int it = 0; it < 6; it++){
    gemm_pinv_f32<<<dim3(16, 32), 256, 0, stream>>>(a2b, zP, az, 0.f, 1.f, 1.f);
    gemm_pinv_f32<<<dim3(16, 32), 256, 0, stream>>>(az, az, x2, 7.f, -1.f, 1.f);
    gemm_pinv_f32<<<dim3(16, 32), 256, 0, stream>>>(az, x2, x3, 11.f, -1.f, 1.f);
    gemm_pinv_f32<<<dim3(16, 32), 256, 0, stream>>>(zP, x3, zQ, 13.f, -1.f, 0.25f);
    float* t1 = zP; zP = zQ; zQ = t1;
  }

  flash_kernel<1><<<dim3(2, 32, 16), 256, 0, stream>>>(nullptr, qlh, qll, kb, nullptr, vtb, nullptr,
                                                       nullptr, pacc, plo);
  a3v_merge<<<8192, 64, 0, stream>>>(pacc, plo, av);
  zw_kernel<<<8192, 64, 0, stream>>>(zP, av, wth, wtl);
  conv_kernel<<<dim3(128, 32), 256, 0, stream>>>(vb, cw, ob);
  flash_kernel<0><<<dim3(64, 32), 256, 0, stream>>>(qb, nullptr, nullptr, klh, kll, wth, wtl,
                                                    ob, nullptr, nullptr);
  gemm128<1><<<dim3(256, 4), 256, 0, stream>>>(ob, woutT, nullptr, nullptr, nullptr, b_out, x, out);
}

// Round 8
// 973.554 us; speedup vs baseline: 7.0774x; 1.1072x over previous
//
#include <hip/hip_runtime.h>

#define DEV __device__ __forceinline__

typedef unsigned short u16;
typedef unsigned int   u32;
typedef u16   u16x8 __attribute__((ext_vector_type(8)));
typedef __bf16 bf16x8 __attribute__((ext_vector_type(8)));
typedef float f32x4 __attribute__((ext_vector_type(4)));

DEV float b2f(u16 u){ return __uint_as_float(((u32)u) << 16); }
DEV u16 f2b(float f){ u32 u = __float_as_uint(f); u32 r = (u + 0x7fffu + ((u >> 16) & 1u)) >> 16; return (u16)r; }

DEV f32x4 mfma16(u16x8 a, u16x8 b, f32x4 c){
  return __builtin_amdgcn_mfma_f32_16x16x32_bf16(
      __builtin_bit_cast(bf16x8, a), __builtin_bit_cast(bf16x8, b), c, 0, 0, 0);
}

// ---------------- LayerNorm: x(f32) -> xn(bf16) + per-row stats ----------------
__global__ __launch_bounds__(256) void ln_kernel(const float* __restrict__ x,
                                                 const float* __restrict__ w,
                                                 const float* __restrict__ bb,
                                                 u16* __restrict__ xn,
                                                 float2* __restrict__ stats){
  int row = blockIdx.x;
  const float* xr = x + (size_t)row * 512;
  int t = threadIdx.x;
  float2 v = *(const float2*)(xr + t * 2);
  float s = v.x + v.y;
  float sq = v.x * v.x + v.y * v.y;
  #pragma unroll
  for(int off = 32; off; off >>= 1){ s += __shfl_xor(s, off, 64); sq += __shfl_xor(sq, off, 64); }
  __shared__ float rs[4], rq[4];
  int wv = t >> 6, ln = t & 63;
  if(ln == 0){ rs[wv] = s; rq[wv] = sq; }
  __syncthreads();
  s = rs[0] + rs[1] + rs[2] + rs[3];
  sq = rq[0] + rq[1] + rq[2] + rq[3];
  float mu = s * (1.f / 512.f);
  float var = sq * (1.f / 512.f) - mu * mu;
  float rstd = rsqrtf(var + 1e-5f);
  if(t == 0) stats[row] = make_float2(mu, rstd);
  float w0 = w[t * 2], w1 = w[t * 2 + 1], b0 = bb[t * 2], b1 = bb[t * 2 + 1];
  u16 u0 = f2b((v.x - mu) * rstd * w0 + b0);
  u16 u1 = f2b((v.y - mu) * rstd * w1 + b1);
  ((u32*)(xn + (size_t)row * 512))[t] = (u32)u0 | ((u32)u1 << 16);
}

// ------------- landmark means of LN(x) in fp32: xl[b*256+j][512] -------------
__global__ __launch_bounds__(256) void xl_kernel(const float* __restrict__ x,
                                                 const float2* __restrict__ stats,
                                                 const float* __restrict__ w,
                                                 const float* __restrict__ bb,
                                                 float* __restrict__ xl){
  int blk = blockIdx.x;          // b*256 + j
  int b = blk >> 8, j = blk & 255;
  int t = threadIdx.x;
  int d0 = t * 2;
  float acc0 = 0.f, acc1 = 0.f;
  size_t row0 = (size_t)b * 8192 + (size_t)j * 32;
  for(int tt = 0; tt < 32; tt++){
    size_t row = row0 + tt;
    float2 st = stats[row];
    const float* xr = x + row * 512;
    float2 v = *(const float2*)(xr + d0);
    acc0 += (v.x - st.x) * st.y;
    acc1 += (v.y - st.x) * st.y;
  }
  float* dst = xl + (size_t)blk * 512;
  dst[d0]     = acc0 * (1.f / 32.f) * w[d0]     + bb[d0];
  dst[d0 + 1] = acc1 * (1.f / 32.f) * w[d0 + 1] + bb[d0 + 1];
}

// ------------- transpose fp32 [K][N] -> bf16 [N][K] -------------
__global__ __launch_bounds__(256) void trans_kernel(const float* __restrict__ src,
                                                    u16* __restrict__ dst, int K, int N){
  int idx = blockIdx.x * 256 + threadIdx.x;
  if(idx >= K * N) return;
  int k = idx / N, n = idx - k * N;
  dst[(size_t)n * K + k] = f2b(src[idx]);
}

// ------------- transpose fp32: first 1024 cols of w_qkv -> wqkT[1024][512] -------------
__global__ __launch_bounds__(256) void transf32_kernel(const float* __restrict__ src,
                                                       float* __restrict__ dst){
  int idx = blockIdx.x * 256 + threadIdx.x;
  int n = idx >> 9, k = idx & 511;
  dst[idx] = src[(size_t)k * 1536 + n];
}

// ------------- v [key][d] -> vt [d][key] (bf16, per bh) -------------
__global__ __launch_bounds__(256) void vtrans_kernel(const u16* __restrict__ v,
                                                     u16* __restrict__ vt){
  __shared__ u16 tile[64][72];
  int bh = blockIdx.y, n0 = blockIdx.x * 64;
  int t = threadIdx.x;
  for(int s = t; s < 512; s += 256){
    int row = s >> 3, col = (s & 7) * 8;
    *(u16x8*)&tile[row][col] = *(const u16x8*)(v + ((size_t)bh * 8192 + n0 + row) * 64 + col);
  }
  __syncthreads();
  for(int s = t; s < 512; s += 256){
    int d = s >> 3, nc = (s & 7) * 8;
    u16x8 u;
    #pragma unroll
    for(int e = 0; e < 8; e++) u[e] = tile[nc + e][d];
    *(u16x8*)(vt + ((size_t)bh * 64 + d) * 8192 + n0 + nc) = u;
  }
}

// ------------- big bf16 GEMM: A[M x 512] @ BT[N x 512]^T, 128x128 tile -------------
template<int EPI>
__global__ __launch_bounds__(256) void gemm128(const u16* __restrict__ A,
                                               const u16* __restrict__ BT,
                                               u16* __restrict__ qo, u16* __restrict__ ko, u16* __restrict__ vo,
                                               const float* __restrict__ bout,
                                               const float* __restrict__ xres,
                                               float* __restrict__ dout){
  __shared__ u16 As[128][40];
  __shared__ u16 Bs[128][40];
  const int K = 512;
  int tb_m = blockIdx.x * 128, tb_n = blockIdx.y * 128;
  int tid = threadIdx.x, lane = tid & 63, w = tid >> 6;
  int wm = (w >> 1) * 64, wn = (w & 1) * 64;
  f32x4 acc[4][4] = {};
  int srow = tid >> 1, sseg = (tid & 1) * 16;
  const u16* Ag = A + (size_t)(tb_m + srow) * K + sseg;
  const u16* Bg = BT + (size_t)(tb_n + srow) * K + sseg;
  for(int kk = 0; kk < K; kk += 32){
    __syncthreads();
    u16x8 a0 = *(const u16x8*)(Ag + kk);
    u16x8 a1 = *(const u16x8*)(Ag + kk + 8);
    u16x8 b0 = *(const u16x8*)(Bg + kk);
    u16x8 b1 = *(const u16x8*)(Bg + kk + 8);
    *(u16x8*)&As[srow][sseg]     = a0;
    *(u16x8*)&As[srow][sseg + 8] = a1;
    *(u16x8*)&Bs[srow][sseg]     = b0;
    *(u16x8*)&Bs[srow][sseg + 8] = b1;
    __syncthreads();
    int r = lane & 15, ko2 = (lane >> 4) * 8;
    u16x8 af[4], bf[4];
    #pragma unroll
    for(int mi = 0; mi < 4; mi++) af[mi] = *(const u16x8*)&As[wm + mi * 16 + r][ko2];
    #pragma unroll
    for(int ni = 0; ni < 4; ni++) bf[ni] = *(const u16x8*)&Bs[wn + ni * 16 + r][ko2];
    #pragma unroll
    for(int mi = 0; mi < 4; mi++)
      #pragma unroll
      for(int ni = 0; ni < 4; ni++)
        acc[mi][ni] = mfma16(af[mi], bf[ni], acc[mi][ni]);
  }
  int r = lane & 15, rr = (lane >> 4) * 4;
  #pragma unroll
  for(int mi = 0; mi < 4; mi++)
    #pragma unroll
    for(int ni = 0; ni < 4; ni++){
      int col = tb_n + wn + ni * 16 + r;
      #pragma unroll
      for(int e = 0; e < 4; e++){
        int row = tb_m + wm + mi * 16 + rr + e;
        float val = acc[mi][ni][e];
        if(EPI == 0){
          int t3 = col >> 9, h = (col >> 6) & 7, dh = col & 63;
          int b = row >> 13, n = row & 8191;
          if(t3 == 0) val *= 0.125f;
          u16* dst = (t3 == 0 ? qo : (t3 == 1 ? ko : vo));
          dst[(((size_t)(b * 8 + h) * 8192) + n) * 64 + dh] = f2b(val);
        } else {
          val += bout[col] + xres[(size_t)row * 512 + col];
          dout[(size_t)row * 512 + col] = val;
        }
      }
    }
}

// ------------- fp32 GEMM: ql/kl = xl @ wqkT^T, scatter epi + hi/lo split -------------
__global__ __launch_bounds__(256) void gemm_qlkl(const float* __restrict__ A,
                                                 const float* __restrict__ BT,
                                                 float* __restrict__ qlf,
                                                 float* __restrict__ klf,
                                                 u16* __restrict__ qlh, u16* __restrict__ qll,
                                                 u16* __restrict__ klh, u16* __restrict__ kll){
  __shared__ float As[64][17];
  __shared__ float Bs[64][17];
  int tb_m = blockIdx.x * 64, tb_n = blockIdx.y * 64;
  int tid = threadIdx.x;
  int ty = tid >> 4, tx = tid & 15;
  float acc[4][4] = {};
  int srow = tid >> 2, sseg = (tid & 3) * 4;
  const float* Ag = A + (size_t)(tb_m + srow) * 512 + sseg;
  const float* Bg = BT + (size_t)(tb_n + srow) * 512 + sseg;
  for(int kk = 0; kk < 512; kk += 16){
    __syncthreads();
    f32x4 a4 = *(const f32x4*)(Ag + kk);
    f32x4 b4 = *(const f32x4*)(Bg + kk);
    #pragma unroll
    for(int e = 0; e < 4; e++){ As[srow][sseg + e] = a4[e]; Bs[srow][sseg + e] = b4[e]; }
    __syncthreads();
    #pragma unroll
    for(int k2 = 0; k2 < 16; k2++){
      float a[4], b[4];
      #pragma unroll
      for(int i = 0; i < 4; i++) a[i] = As[ty * 4 + i][k2];
      #pragma unroll
      for(int jv = 0; jv < 4; jv++) b[jv] = Bs[tx * 4 + jv][k2];
      #pragma unroll
      for(int i = 0; i < 4; i++)
        #pragma unroll
        for(int jv = 0; jv < 4; jv++) acc[i][jv] += a[i] * b[jv];
    }
  }
  #pragma unroll
  for(int i = 0; i < 4; i++)
    #pragma unroll
    for(int jv = 0; jv < 4; jv++){
      int r = tb_m + ty * 4 + i;
      int c = tb_n + tx * 4 + jv;
      int b = r >> 8, jl = r & 255;
      float val = acc[i][jv];
      if(c < 512){
        float q = val * 0.125f;
        size_t qi = (((size_t)(b * 8 + (c >> 6)) * 256) + jl) * 64 + (c & 63);
        qlf[qi] = q;
        u16 hi = f2b(q);
        qlh[qi] = hi; qll[qi] = f2b(q - b2f(hi));
      } else {
        int c2 = c - 512;
        size_t ki = (((size_t)(b * 8 + (c2 >> 6)) * 256) + jl) * 64 + (c2 & 63);
        klf[ki] = val;
        u16 hi = f2b(val);
        klh[ki] = hi; kll[ki] = f2b(val - b2f(hi));
      }
    }
}

// ------------- batched fp32 pinv GEMM: C = osc*(A @ (dB*I + sB*B)), KCHUNK=64 -------------
__global__ __launch_bounds__(256) void gemm_pinv_f32(const float* __restrict__ A,
                                                     const float* __restrict__ B,
                                                     float* __restrict__ C,
                                                     float dB, float sB, float osc){
  __shared__ float As[64][68];   // [k][m]
  __shared__ float Bs[64][68];   // [k][n]
  int bh = blockIdx.y;
  size_t base = (size_t)bh * 65536;
  int tb_m = (blockIdx.x >> 2) * 64, tb_n = (blockIdx.x & 3) * 64;
  int tid = threadIdx.x;
  int ty = tid >> 4, tx = tid & 15;
  float acc[4][4] = {};
  int arow = tid >> 2, acol = (tid & 3) * 16;
  int brow = tid >> 3, bcol = (tid & 7) * 8;
  const float* Ag = A + base + (size_t)(tb_m + arow) * 256 + acol;
  const float* Bg = B + base + (size_t)brow * 256 + tb_n + bcol;
  for(int kk = 0; kk < 256; kk += 64){
    f32x4 a[4];
    #pragma unroll
    for(int q = 0; q < 4; q++) a[q] = *(const f32x4*)(Ag + kk + q * 4);
    f32x4 b[2][2];
    #pragma unroll
    for(int rr = 0; rr < 2; rr++){
      const float* bp = Bg + (size_t)(kk + rr * 32) * 256;
      b[rr][0] = *(const f32x4*)bp;
      b[rr][1] = *(const f32x4*)(bp + 4);
    }
    __syncthreads();
    #pragma unroll
    for(int q = 0; q < 4; q++)
      #pragma unroll
      for(int e = 0; e < 4; e++)
        As[acol + q * 4 + e][arow] = a[q][e];
    #pragma unroll
    for(int rr = 0; rr < 2; rr++){
      int krow = kk + rr * 32 + brow;
      f32x4 v0, v1;
      #pragma unroll
      for(int e = 0; e < 4; e++){
        float t0 = sB * b[rr][0][e]; if(krow == tb_n + bcol + e)     t0 += dB;
        float t1 = sB * b[rr][1][e]; if(krow == tb_n + bcol + 4 + e) t1 += dB;
        v0[e] = t0; v1[e] = t1;
      }
      *(f32x4*)&Bs[rr * 32 + brow][bcol]     = v0;
      *(f32x4*)&Bs[rr * 32 + brow][bcol + 4] = v1;
    }
    __syncthreads();
    #pragma unroll
    for(int k2 = 0; k2 < 64; k2++){
      f32x4 av4 = *(const f32x4*)&As[k2][ty * 4];
      f32x4 bv4 = *(const f32x4*)&Bs[k2][tx * 4];
      #pragma unroll
      for(int i = 0; i < 4; i++)
        #pragma unroll
        for(int jv = 0; jv < 4; jv++) acc[i][jv] += av4[i] * bv4[jv];
    }
  }
  #pragma unroll
  for(int i = 0; i < 4; i++){
    int r = tb_m + ty * 4 + i;
    f32x4 ov;
    #pragma unroll
    for(int jv = 0; jv < 4; jv++) ov[jv] = osc * acc[i][jv];
    *(f32x4*)(C + base + (size_t)r * 256 + tb_n + tx * 4) = ov;
  }
}

// ------------- a2 = softmax(q_l @ k_l^T) per row, fp32 -------------
__global__ __launch_bounds__(256) void a2_kernel(const float* __restrict__ qlf,
                                                 const float* __restrict__ klf,
                                                 float* __restrict__ a2){
  int i = blockIdx.x, bh = blockIdx.y, j = threadIdx.x;
  const float* qp = qlf + ((size_t)bh * 256 + i) * 64;
  const float* kp = klf + ((size_t)bh * 256 + j) * 64;
  float s = 0.f;
  #pragma unroll
  for(int d0 = 0; d0 < 16; d0++){
    f32x4 uq = *(const f32x4*)(qp + d0 * 4);
    f32x4 uk = *(const f32x4*)(kp + d0 * 4);
    #pragma unroll
    for(int e = 0; e < 4; e++) s += uq[e] * uk[e];
  }
  __shared__ float red[256];
  red[j] = s; __syncthreads();
  for(int off = 128; off; off >>= 1){ if(j < off) red[j] = fmaxf(red[j], red[j + off]); __syncthreads(); }
  float m = red[0]; __syncthreads();
  float p = expf(s - m);
  red[j] = p; __syncthreads();
  for(int off = 128; off; off >>= 1){ if(j < off) red[j] += red[j + off]; __syncthreads(); }
  float denom = red[0];
  a2[((size_t)bh * 256 + i) * 256 + j] = p / denom;
}

// ------------- scale maxes -------------
__global__ __launch_bounds__(256) void scale_kernel(const float* __restrict__ a2, u32* __restrict__ maxes){
  int bh = blockIdx.x, t = threadIdx.x;
  const float* p = a2 + (size_t)bh * 65536;
  float cs = 0.f, rs = 0.f;
  for(int i = 0; i < 256; i++) cs += p[i * 256 + t];
  for(int j = 0; j < 256; j++) rs += p[t * 256 + j];
  __shared__ float rc[256], rr[256];
  rc[t] = cs; rr[t] = rs; __syncthreads();
  for(int off = 128; off; off >>= 1){
    if(t < off){ rc[t] = fmaxf(rc[t], rc[t + off]); rr[t] = fmaxf(rr[t], rr[t + off]); }
    __syncthreads();
  }
  if(t == 0){
    atomicMax(&maxes[0], __float_as_uint(rc[0]));
    atomicMax(&maxes[1], __float_as_uint(rr[0]));
  }
}

// ------------- z0 = a2^T / scale (tiled transpose) -------------
__global__ __launch_bounds__(256) void z0_kernel(const float* __restrict__ a2,
                                                 float* __restrict__ z,
                                                 const u32* __restrict__ maxes){
  __shared__ float tile[64][65];
  float inv = 1.f / (__uint_as_float(maxes[0]) * __uint_as_float(maxes[1]));
  int bh = blockIdx.z;
  int i0 = blockIdx.x * 64, j0 = blockIdx.y * 64;
  const float* src = a2 + (size_t)bh * 65536;
  float* dst = z + (size_t)bh * 65536;
  for(int s = threadIdx.x; s < 1024; s += 256){
    int r = s >> 4, c4 = (s & 15) * 4;
    f32x4 v = *(const f32x4*)(src + (size_t)(i0 + r) * 256 + j0 + c4);
    #pragma unroll
    for(int e = 0; e < 4; e++) tile[r][c4 + e] = v[e];
  }
  __syncthreads();
  for(int s = threadIdx.x; s < 1024; s += 256){
    int jr = s >> 4, c4 = (s & 15) * 4;
    f32x4 v;
    #pragma unroll
    for(int e = 0; e < 4; e++) v[e] = tile[c4 + e][jr] * inv;
    *(f32x4*)(dst + (size_t)(j0 + jr) * 256 + i0 + c4) = v;
  }
}

// ------------- unified MFMA flash attention, LDS-staged K/V (shared by 4 waves) -------------
// MODE 0 (a1): A=qb exact; B=kl hi/lo; V=W^T hi/lo; 256 keys; RMW into o.  smem 54784 B
// MODE 1 (a3v): A=ql hi/lo; B=kb exact; V=v^T exact; 512-key split.        smem 36352 B
template<int MODE>
__global__ __launch_bounds__(256) void flash_kernel(
    const u16* __restrict__ Aex,
    const u16* __restrict__ Ah_, const u16* __restrict__ Al_,
    const u16* __restrict__ Bh_, const u16* __restrict__ Bl_,
    const u16* __restrict__ Vh_, const u16* __restrict__ Vl_,
    u16* __restrict__ o,
    float* __restrict__ pacc, float* __restrict__ plo){
  extern __shared__ char smem[];
  u32 (*pbuf)[32][35] = (u32(*)[32][35])smem;                  // [4][32][35] = 17920 B
  u16 (*ksh)[72] = (u16(*)[72])(smem + 17920);                 // [64][72] key-major
  u16 (*vsh)[72] = (u16(*)[72])(smem + 17920 + 9216);          // [64][72] d-major
  u16 (*ksl)[72] = (u16(*)[72])(smem + 17920 + 2 * 9216);      // MODE0 only
  u16 (*vsl)[72] = (u16(*)[72])(smem + 17920 + 3 * 9216);      // MODE0 only

  int tid = threadIdx.x;
  int w = tid >> 6, lane = tid & 63;
  int lr = lane & 15, lg = lane >> 4;
  int bh = blockIdx.y;
  int rowbase = blockIdx.x * 128 + w * 32;
  constexpr int NT = (MODE == 0) ? 4 : 8;
  int kbase = (MODE == 0) ? 0 : blockIdx.z * 512;
  int srow = tid >> 2, sseg = (tid & 3) * 16;

  u16x8 afh[2][2], afl[2][2];
  #pragma unroll
  for(int mi = 0; mi < 2; mi++)
    #pragma unroll
    for(int ks = 0; ks < 2; ks++){
      int r = rowbase + mi * 16 + lr;
      if(MODE == 0){
        afh[mi][ks] = *(const u16x8*)(Aex + ((size_t)bh * 8192 + r) * 64 + ks * 32 + lg * 8);
      } else {
        size_t idx = ((size_t)bh * 256 + r) * 64 + ks * 32 + lg * 8;
        afh[mi][ks] = *(const u16x8*)(Ah_ + idx);
        afl[mi][ks] = *(const u16x8*)(Al_ + idx);
      }
    }

  f32x4 pv[2][4] = {};
  float l[2][4] = {};

  for(int t = 0; t < NT; t++){
    int koff = t * 64;
    __syncthreads();
    // ---- cooperative stage: 64-key K tile (key-major) + V tile (d-major) ----
    if(MODE == 0){
      size_t kix = ((size_t)bh * 256 + koff + srow) * 64 + sseg;
      *(u16x8*)&ksh[srow][sseg]     = *(const u16x8*)(Bh_ + kix);
      *(u16x8*)&ksh[srow][sseg + 8] = *(const u16x8*)(Bh_ + kix + 8);
      *(u16x8*)&ksl[srow][sseg]     = *(const u16x8*)(Bl_ + kix);
      *(u16x8*)&ksl[srow][sseg + 8] = *(const u16x8*)(Bl_ + kix + 8);
      size_t vix = ((size_t)bh * 64 + srow) * 256 + koff + sseg;
      *(u16x8*)&vsh[srow][sseg]     = *(const u16x8*)(Vh_ + vix);
      *(u16x8*)&vsh[srow][sseg + 8] = *(const u16x8*)(Vh_ + vix + 8);
      *(u16x8*)&vsl[srow][sseg]     = *(const u16x8*)(Vl_ + vix);
      *(u16x8*)&vsl[srow][sseg + 8] = *(const u16x8*)(Vl_ + vix + 8);
    } else {
      size_t kix = ((size_t)bh * 8192 + kbase + koff + srow) * 64 + sseg;
      *(u16x8*)&ksh[srow][sseg]     = *(const u16x8*)(Bh_ + kix);
      *(u16x8*)&ksh[srow][sseg + 8] = *(const u16x8*)(Bh_ + kix + 8);
      size_t vix = ((size_t)bh * 64 + srow) * 8192 + kbase + koff + sseg;
      *(u16x8*)&vsh[srow][sseg]     = *(const u16x8*)(Vh_ + vix);
      *(u16x8*)&vsh[srow][sseg + 8] = *(const u16x8*)(Vh_ + vix + 8);
    }
    __syncthreads();
    // ---- compute both 32-key halves ----
    #pragma unroll
    for(int half = 0; half < 2; half++){
      u16x8 bfh[2][2], bfl[2][2];
      #pragma unroll
      for(int ni = 0; ni < 2; ni++){
        int krow = half * 32 + ni * 16 + lr;
        #pragma unroll
        for(int ks = 0; ks < 2; ks++){
          bfh[ni][ks] = *(const u16x8*)&ksh[krow][ks * 32 + lg * 8];
          if(MODE == 0) bfl[ni][ks] = *(const u16x8*)&ksl[krow][ks * 32 + lg * 8];
        }
      }
      f32x4 sv[2][2];
      #pragma unroll
      for(int mi = 0; mi < 2; mi++)
        #pragma unroll
        for(int ni = 0; ni < 2; ni++) sv[mi][ni] = (f32x4){0.f, 0.f, 0.f, 0.f};
      #pragma unroll
      for(int ks = 0; ks < 2; ks++)
        #pragma unroll
        for(int mi = 0; mi < 2; mi++)
          #pragma unroll
          for(int ni = 0; ni < 2; ni++){
            sv[mi][ni] = mfma16(afh[mi][ks], bfh[ni][ks], sv[mi][ni]);
            if(MODE == 0) sv[mi][ni] = mfma16(afh[mi][ks], bfl[ni][ks], sv[mi][ni]);
            else          sv[mi][ni] = mfma16(afl[mi][ks], bfh[ni][ks], sv[mi][ni]);
          }
      // exp + per-lane l; pack hi/lo -> pbuf transpose
      #pragma unroll
      for(int mi = 0; mi < 2; mi++)
        #pragma unroll
        for(int ni = 0; ni < 2; ni++)
          #pragma unroll
          for(int e = 0; e < 4; e++){
            float p = __expf(sv[mi][ni][e]);
            l[mi][e] += p;
            u32 pb = __float_as_uint(p);
            u32 rb = pb + 0x7fffu + ((pb >> 16) & 1u);
            float hif = __uint_as_float(rb & 0xffff0000u);
            u32 lob = __float_as_uint(p - hif);
            pbuf[w][mi * 16 + lg * 4 + e][ni * 16 + lr] = __builtin_amdgcn_perm(lob, rb, 0x07060302u);
          }
      u16x8 pah[2], pal[2];
      #pragma unroll
      for(int mi = 0; mi < 2; mi++){
        u32 tv[8];
        #pragma unroll
        for(int e2 = 0; e2 < 8; e2++) tv[e2] = pbuf[w][mi * 16 + lr][lg * 8 + e2];
        u32* ph = (u32*)&pah[mi];
        u32* pl = (u32*)&pal[mi];
        #pragma unroll
        for(int q = 0; q < 4; q++){
          ph[q] = __builtin_amdgcn_perm(tv[2 * q + 1], tv[2 * q], 0x05040100u);
          pl[q] = __builtin_amdgcn_perm(tv[2 * q + 1], tv[2 * q], 0x07060302u);
        }
      }
      // PV over 32 keys from LDS V tile
      #pragma unroll
      for(int ni2 = 0; ni2 < 4; ni2++){
        int d = ni2 * 16 + lr;
        u16x8 vh = *(const u16x8*)&vsh[d][half * 32 + lg * 8];
        u16x8 vl;
        if(MODE == 0) vl = *(const u16x8*)&vsl[d][half * 32 + lg * 8];
        #pragma unroll
        for(int mi = 0; mi < 2; mi++){
          pv[mi][ni2] = mfma16(pah[mi], vh, pv[mi][ni2]);
          if(MODE == 0){
            pv[mi][ni2] = mfma16(pah[mi], vl, pv[mi][ni2]);
            pv[mi][ni2] = mfma16(pal[mi], vh, pv[mi][ni2]);
          } else {
            pv[mi][ni2] = mfma16(pal[mi], vh, pv[mi][ni2]);
          }
        }
      }
    }
  }
  // reduce per-lane l across the 16-lane row group
  #pragma unroll
  for(int mi = 0; mi < 2; mi++)
    #pragma unroll
    for(int e = 0; e < 4; e++){
      float lv = l[mi][e];
      #pragma unroll
      for(int off = 1; off < 16; off <<= 1) lv += __shfl_xor(lv, off, 64);
      l[mi][e] = lv;
    }
  #pragma unroll
  for(int mi = 0; mi < 2; mi++){
    #pragma unroll
    for(int e = 0; e < 4; e++){
      int row = rowbase + mi * 16 + lg * 4 + e;
      if(MODE == 0){
        float invl = 1.f / l[mi][e];
        int b = bh >> 3, h = bh & 7;
        #pragma unroll
        for(int ni2 = 0; ni2 < 4; ni2++){
          int col = ni2 * 16 + lr;
          size_t oi = ((size_t)b * 8192 + row) * 512 + h * 64 + col;
          o[oi] = f2b(pv[mi][ni2][e] * invl + b2f(o[oi]));
        }
      } else {
        #pragma unroll
        for(int ni2 = 0; ni2 < 4; ni2++){
          int col = ni2 * 16 + lr;
          pacc[(((size_t)blockIdx.z * 8192) + (size_t)bh * 256 + row) * 64 + col] = pv[mi][ni2][e];
        }
      }
    }
  }
  if(MODE == 1 && lr == 0){
    #pragma unroll
    for(int mi = 0; mi < 2; mi++)
      #pragma unroll
      for(int e = 0; e < 4; e++){
        int row = rowbase + mi * 16 + lg * 4 + e;
        plo[(size_t)blockIdx.z * 8192 + (size_t)bh * 256 + row] = l[mi][e];
      }
  }
}

// ------------- merge a3v split-K partials (16) -> av fp32 -------------
__global__ __launch_bounds__(64) void a3v_merge(const float* __restrict__ pacc,
                                                const float* __restrict__ plo,
                                                float* __restrict__ av){
  int row = blockIdx.x, d = threadIdx.x;
  float L = 0.f, acc = 0.f;
  #pragma unroll
  for(int p = 0; p < 16; p++){
    L += plo[(size_t)p * 8192 + row];
    acc += pacc[((size_t)p * 8192 + row) * 64 + d];
  }
  av[(size_t)row * 64 + d] = acc / L;
}

// ------------- W^T = (Z @ av)^T as bf16 hi/lo -------------
__global__ __launch_bounds__(64) void zw_kernel(const float* __restrict__ z,
                                                const float* __restrict__ av,
                                                u16* __restrict__ wth, u16* __restrict__ wtl){
  int i = blockIdx.x & 255, bh = blockIdx.x >> 8, d = threadIdx.x;
  const float* zr = z + ((size_t)bh * 256 + i) * 256;
  const float* ab = av + (size_t)bh * 256 * 64;
  float s = 0.f;
  for(int j = 0; j < 256; j++) s += zr[j] * ab[j * 64 + d];
  size_t oi = ((size_t)bh * 64 + d) * 256 + i;
  u16 hi = f2b(s);
  wth[oi] = hi;
  wtl[oi] = f2b(s - b2f(hi));
}

// ------------- depthwise conv residual -> o (bf16 token layout), register-blocked -------------
__global__ __launch_bounds__(256) void conv_kernel(const u16* __restrict__ v,
                                                   const float* __restrict__ cw,
                                                   u16* __restrict__ o){
  __shared__ float wl[33];
  __shared__ float vt[64][104];   // [d][local row]; stride 104 floats = 416 B (16B-aligned rows)
  int bh = blockIdx.y, b = bh >> 3, h = bh & 7;
  int r0 = blockIdx.x * 64;
  if(threadIdx.x < 33) wl[threadIdx.x] = cw[h * 33 + threadIdx.x];
  const u16* vb = v + (size_t)bh * 8192 * 64;
  for(int idx = threadIdx.x; idx < 768; idx += 256){
    int row = idx >> 3, c8 = (idx & 7) * 8;
    int gr = r0 - 16 + row;
    u16x8 u = {};
    if(gr >= 0 && gr < 8192) u = *(const u16x8*)(vb + (size_t)gr * 64 + c8);
    #pragma unroll
    for(int e = 0; e < 8; e++) vt[c8 + e][row] = b2f(u[e]);
  }
  __syncthreads();
  int d = threadIdx.x & 63, g = threadIdx.x >> 6;
  float vin[48];
  #pragma unroll
  for(int i = 0; i < 12; i++){
    f32x4 q4 = *(const f32x4*)&vt[d][g * 16 + i * 4];
    #pragma unroll
    for(int e = 0; e < 4; e++) vin[i * 4 + e] = q4[e];
  }
  float acc[16] = {};
  #pragma unroll
  for(int t = 0; t < 33; t++){
    float wt = wl[t];
    #pragma unroll
    for(int r = 0; r < 16; r++) acc[r] += wt * vin[r + t];
  }
  #pragma unroll
  for(int r = 0; r < 16; r++){
    size_t oi = ((size_t)b * 8192 + (r0 + g * 16 + r)) * 512 + h * 64 + d;
    o[oi] = f2b(acc[r]);
  }
}

extern "C" void kernel_launch(void* const* d_in, const int* in_sizes, int n_in,
                              void* d_out, int out_size, void* d_ws, size_t ws_size,
                              hipStream_t stream){
  (void)in_sizes; (void)n_in; (void)out_size; (void)ws_size;
  const float* x     = (const float*)d_in[0];
  const float* ln_w  = (const float*)d_in[1];
  const float* ln_b  = (const float*)d_in[2];
  const float* w_qkv = (const float*)d_in[3];
  const float* w_out = (const float*)d_in[4];
  const float* b_out = (const float*)d_in[5];
  const float* cw    = (const float*)d_in[6];
  float* out = (float*)d_out;

  char* base = (char*)d_ws;
  size_t off = 0;
  auto alloc = [&](size_t bytes)->void*{
    void* r = base + off; off += (bytes + 255) & ~(size_t)255; return r;
  };
  u16* xn      = (u16*)alloc(32768ull * 512 * 2);    // reused as o after QKV GEMM
  float2* stat = (float2*)alloc(32768ull * 8);
  u16* qb      = (u16*)alloc(32ull * 8192 * 64 * 2);
  u16* kb      = (u16*)alloc(32ull * 8192 * 64 * 2);
  u16* vb      = (u16*)alloc(32ull * 8192 * 64 * 2);
  u16* vtb     = (u16*)alloc(32ull * 8192 * 64 * 2);
  u16* wqkvT   = (u16*)alloc(1536ull * 512 * 2);
  u16* woutT   = (u16*)alloc(512ull * 512 * 2);
  float* wqkT  = (float*)alloc(1024ull * 512 * 4);
  float* xl    = (float*)alloc(1024ull * 512 * 4);
  float* qlf   = (float*)alloc(32ull * 256 * 64 * 4);
  float* klf   = (float*)alloc(32ull * 256 * 64 * 4);
  u16* qlh     = (u16*)alloc(32ull * 256 * 64 * 2);
  u16* qll     = (u16*)alloc(32ull * 256 * 64 * 2);
  u16* klh     = (u16*)alloc(32ull * 256 * 64 * 2);
  u16* kll     = (u16*)alloc(32ull * 256 * 64 * 2);
  float* a2b   = (float*)alloc(32ull * 65536 * 4);
  float* zA    = (float*)alloc(32ull * 65536 * 4);
  float* zB    = (float*)alloc(32ull * 65536 * 4);   // pacc aliases zB..x3 (33.55 MB) after pinv
  float* az    = (float*)alloc(32ull * 65536 * 4);
  float* x2    = (float*)alloc(32ull * 65536 * 4);
  float* x3    = (float*)alloc(32ull * 65536 * 4);
  float* av    = (float*)alloc(32ull * 256 * 64 * 4);
  u16* wth     = (u16*)alloc(32ull * 64 * 256 * 2);
  u16* wtl     = (u16*)alloc(32ull * 64 * 256 * 2);
  u32* scal    = (u32*)alloc(256);
  u16* ob = xn;
  // after the pinv loop zP ends at zA; zB, az, x2, x3 are dead and contiguous:
  // 4 x 8,388,608 B = 33,554,432 B = exactly 16 split-K slabs of 8192*64*4.
  float* pacc = zB;
  float* plo  = a2b;   // dead after pinv loop; needs 16*8192*4 = 512 KB

  hipMemsetAsync(scal, 0, 8, stream);
  ln_kernel<<<32768, 256, 0, stream>>>(x, ln_w, ln_b, xn, stat);
  trans_kernel<<<3072, 256, 0, stream>>>(w_qkv, wqkvT, 512, 1536);
  trans_kernel<<<1024, 256, 0, stream>>>(w_out, woutT, 512, 512);
  transf32_kernel<<<2048, 256, 0, stream>>>(w_qkv, wqkT);
  gemm128<0><<<dim3(256, 12), 256, 0, stream>>>(xn, wqkvT, qb, kb, vb, nullptr, nullptr, nullptr);
  vtrans_kernel<<<dim3(128, 32), 256, 0, stream>>>(vb, vtb);
  xl_kernel<<<1024, 256, 0, stream>>>(x, stat, ln_w, ln_b, xl);
  gemm_qlkl<<<dim3(16, 16), 256, 0, stream>>>(xl, wqkT, qlf, klf, qlh, qll, klh, kll);
  a2_kernel<<<dim3(256, 32), 256, 0, stream>>>(qlf, klf, a2b);
  scale_kernel<<<32, 256, 0, stream>>>(a2b, scal);
  z0_kernel<<<dim3(4, 4, 32), 256, 0, stream>>>(a2b, zA, scal);

  float* zP = zA; float* zQ = zB;
  for(int it = 0; it < 6; it++){
    gemm_pinv_f32<<<dim3(16, 32), 256, 0, stream>>>(a2b, zP, az, 0.f, 1.f, 1.f);
    gemm_pinv_f32<<<dim3(16, 32), 256, 0, stream>>>(az, az, x2, 7.f, -1.f, 1.f);
    gemm_pinv_f32<<<dim3(16, 32), 256, 0, stream>>>(az, x2, x3, 11.f, -1.f, 1.f);
    gemm_pinv_f32<<<dim3(16, 32), 256, 0, stream>>>(zP, x3, zQ, 13.f, -1.f, 0.25f);
    float* t1 = zP; zP = zQ; zQ = t1;
  }

  flash_kernel<1><<<dim3(2, 32, 16), 256, 36352, stream>>>(nullptr, qlh, qll, kb, nullptr, vtb, nullptr,
                                                           nullptr, pacc, plo);
  a3v_merge<<<8192, 64, 0, stream>>>(pacc, plo, av);
  zw_kernel<<<8192, 64, 0, stream>>>(zP, av, wth, wtl);
  conv_kernel<<<dim3(128, 32), 256, 0, stream>>>(vb, cw, ob);
  flash_kernel<0><<<dim3(64, 32), 256, 54784, stream>>>(qb, nullptr, nullptr, klh, kll, wth, wtl,
                                                        ob, nullptr, nullptr);
  gemm128<1><<<dim3(256, 4), 256, 0, stream>>>(ob, woutT, nullptr, nullptr, nullptr, b_out, x, out);
}

// Round 9
// 961.283 us; speedup vs baseline: 7.1677x; 1.0128x over previous
//
#include <hip/hip_runtime.h>

#define DEV __device__ __forceinline__

typedef unsigned short u16;
typedef unsigned int   u32;
typedef u16   u16x8 __attribute__((ext_vector_type(8)));
typedef __bf16 bf16x8 __attribute__((ext_vector_type(8)));
typedef float f32x4 __attribute__((ext_vector_type(4)));

DEV float b2f(u16 u){ return __uint_as_float(((u32)u) << 16); }
DEV u16 f2b(float f){ u32 u = __float_as_uint(f); u32 r = (u + 0x7fffu + ((u >> 16) & 1u)) >> 16; return (u16)r; }

DEV f32x4 mfma16(u16x8 a, u16x8 b, f32x4 c){
  return __builtin_amdgcn_mfma_f32_16x16x32_bf16(
      __builtin_bit_cast(bf16x8, a), __builtin_bit_cast(bf16x8, b), c, 0, 0, 0);
}

// async global->LDS 16B (wave-uniform LDS base + lane*16; LDS must be linear)
DEV void gload16(const void* g, void* l){
  __builtin_amdgcn_global_load_lds(
      (const __attribute__((address_space(1))) u32*)g,
      (__attribute__((address_space(3))) u32*)l,
      16, 0, 0);
}

// ---------------- LayerNorm: x(f32) -> xn(bf16) + per-row stats ----------------
__global__ __launch_bounds__(256) void ln_kernel(const float* __restrict__ x,
                                                 const float* __restrict__ w,
                                                 const float* __restrict__ bb,
                                                 u16* __restrict__ xn,
                                                 float2* __restrict__ stats){
  int row = blockIdx.x;
  const float* xr = x + (size_t)row * 512;
  int t = threadIdx.x;
  float2 v = *(const float2*)(xr + t * 2);
  float s = v.x + v.y;
  float sq = v.x * v.x + v.y * v.y;
  #pragma unroll
  for(int off = 32; off; off >>= 1){ s += __shfl_xor(s, off, 64); sq += __shfl_xor(sq, off, 64); }
  __shared__ float rs[4], rq[4];
  int wv = t >> 6, ln = t & 63;
  if(ln == 0){ rs[wv] = s; rq[wv] = sq; }
  __syncthreads();
  s = rs[0] + rs[1] + rs[2] + rs[3];
  sq = rq[0] + rq[1] + rq[2] + rq[3];
  float mu = s * (1.f / 512.f);
  float var = sq * (1.f / 512.f) - mu * mu;
  float rstd = rsqrtf(var + 1e-5f);
  if(t == 0) stats[row] = make_float2(mu, rstd);
  float w0 = w[t * 2], w1 = w[t * 2 + 1], b0 = bb[t * 2], b1 = bb[t * 2 + 1];
  u16 u0 = f2b((v.x - mu) * rstd * w0 + b0);
  u16 u1 = f2b((v.y - mu) * rstd * w1 + b1);
  ((u32*)(xn + (size_t)row * 512))[t] = (u32)u0 | ((u32)u1 << 16);
}

// ------------- landmark means of LN(x) in fp32: xl[b*256+j][512] -------------
__global__ __launch_bounds__(256) void xl_kernel(const float* __restrict__ x,
                                                 const float2* __restrict__ stats,
                                                 const float* __restrict__ w,
                                                 const float* __restrict__ bb,
                                                 float* __restrict__ xl){
  int blk = blockIdx.x;          // b*256 + j
  int b = blk >> 8, j = blk & 255;
  int t = threadIdx.x;
  int d0 = t * 2;
  float acc0 = 0.f, acc1 = 0.f;
  size_t row0 = (size_t)b * 8192 + (size_t)j * 32;
  for(int tt = 0; tt < 32; tt++){
    size_t row = row0 + tt;
    float2 st = stats[row];
    const float* xr = x + row * 512;
    float2 v = *(const float2*)(xr + d0);
    acc0 += (v.x - st.x) * st.y;
    acc1 += (v.y - st.x) * st.y;
  }
  float* dst = xl + (size_t)blk * 512;
  dst[d0]     = acc0 * (1.f / 32.f) * w[d0]     + bb[d0];
  dst[d0 + 1] = acc1 * (1.f / 32.f) * w[d0 + 1] + bb[d0 + 1];
}

// ------------- transpose fp32 [K][N] -> bf16 [N][K] -------------
__global__ __launch_bounds__(256) void trans_kernel(const float* __restrict__ src,
                                                    u16* __restrict__ dst, int K, int N){
  int idx = blockIdx.x * 256 + threadIdx.x;
  if(idx >= K * N) return;
  int k = idx / N, n = idx - k * N;
  dst[(size_t)n * K + k] = f2b(src[idx]);
}

// ------------- transpose fp32: first 1024 cols of w_qkv -> wqkT[1024][512] -------------
__global__ __launch_bounds__(256) void transf32_kernel(const float* __restrict__ src,
                                                       float* __restrict__ dst){
  int idx = blockIdx.x * 256 + threadIdx.x;
  int n = idx >> 9, k = idx & 511;
  dst[idx] = src[(size_t)k * 1536 + n];
}

// ------------- v [key][d] -> vt [d][key] (bf16, per bh) -------------
__global__ __launch_bounds__(256) void vtrans_kernel(const u16* __restrict__ v,
                                                     u16* __restrict__ vt){
  __shared__ u16 tile[64][72];
  int bh = blockIdx.y, n0 = blockIdx.x * 64;
  int t = threadIdx.x;
  for(int s = t; s < 512; s += 256){
    int row = s >> 3, col = (s & 7) * 8;
    *(u16x8*)&tile[row][col] = *(const u16x8*)(v + ((size_t)bh * 8192 + n0 + row) * 64 + col);
  }
  __syncthreads();
  for(int s = t; s < 512; s += 256){
    int d = s >> 3, nc = (s & 7) * 8;
    u16x8 u;
    #pragma unroll
    for(int e = 0; e < 8; e++) u[e] = tile[nc + e][d];
    *(u16x8*)(vt + ((size_t)bh * 64 + d) * 8192 + n0 + nc) = u;
  }
}

// ------------- big bf16 GEMM: A[M x 512] @ BT[N x 512]^T, 128x128 tile -------------
// global_load_lds staging (linear LDS [128][32] u16 per operand)
template<int EPI>
__global__ __launch_bounds__(256) void gemm128(const u16* __restrict__ A,
                                               const u16* __restrict__ BT,
                                               u16* __restrict__ qo, u16* __restrict__ ko, u16* __restrict__ vo,
                                               const float* __restrict__ bout,
                                               const float* __restrict__ xres,
                                               float* __restrict__ dout){
  __shared__ u16 As[128 * 32];
  __shared__ u16 Bs[128 * 32];
  const int K = 512;
  int tb_m = blockIdx.x * 128, tb_n = blockIdx.y * 128;
  int tid = threadIdx.x, lane = tid & 63, w = tid >> 6;
  int wm = (w >> 1) * 64, wn = (w & 1) * 64;
  f32x4 acc[4][4] = {};
  int srow = tid >> 2, sk = (tid & 3) * 8;
  const u16* Ag = A + (size_t)(tb_m + srow) * K + sk;
  const u16* Bg = BT + (size_t)(tb_n + srow) * K + sk;
  u16* Al = As + tid * 8;     // byte offset tid*16 (lane-linear)
  u16* Bl = Bs + tid * 8;
  for(int kk = 0; kk < K; kk += 32){
    __syncthreads();
    gload16(Ag + kk, Al);
    gload16(Ag + kk + (size_t)64 * K, Al + 2048);
    gload16(Bg + kk, Bl);
    gload16(Bg + kk + (size_t)64 * K, Bl + 2048);
    __syncthreads();
    int r = lane & 15, ko2 = (lane >> 4) * 8;
    u16x8 af[4], bf[4];
    #pragma unroll
    for(int mi = 0; mi < 4; mi++) af[mi] = *(const u16x8*)&As[(wm + mi * 16 + r) * 32 + ko2];
    #pragma unroll
    for(int ni = 0; ni < 4; ni++) bf[ni] = *(const u16x8*)&Bs[(wn + ni * 16 + r) * 32 + ko2];
    #pragma unroll
    for(int mi = 0; mi < 4; mi++)
      #pragma unroll
      for(int ni = 0; ni < 4; ni++)
        acc[mi][ni] = mfma16(af[mi], bf[ni], acc[mi][ni]);
  }
  int r = lane & 15, rr = (lane >> 4) * 4;
  #pragma unroll
  for(int mi = 0; mi < 4; mi++)
    #pragma unroll
    for(int ni = 0; ni < 4; ni++){
      int col = tb_n + wn + ni * 16 + r;
      #pragma unroll
      for(int e = 0; e < 4; e++){
        int row = tb_m + wm + mi * 16 + rr + e;
        float val = acc[mi][ni][e];
        if(EPI == 0){
          int t3 = col >> 9, h = (col >> 6) & 7, dh = col & 63;
          int b = row >> 13, n = row & 8191;
          if(t3 == 0) val *= 0.125f;
          u16* dst = (t3 == 0 ? qo : (t3 == 1 ? ko : vo));
          dst[(((size_t)(b * 8 + h) * 8192) + n) * 64 + dh] = f2b(val);
        } else {
          val += bout[col] + xres[(size_t)row * 512 + col];
          dout[(size_t)row * 512 + col] = val;
        }
      }
    }
}

// ------------- fp32 GEMM: ql/kl = xl @ wqkT^T, scatter epi + hi/lo split -------------
__global__ __launch_bounds__(256) void gemm_qlkl(const float* __restrict__ A,
                                                 const float* __restrict__ BT,
                                                 float* __restrict__ qlf,
                                                 float* __restrict__ klf,
                                                 u16* __restrict__ qlh, u16* __restrict__ qll,
                                                 u16* __restrict__ klh, u16* __restrict__ kll){
  __shared__ float As[64][17];
  __shared__ float Bs[64][17];
  int tb_m = blockIdx.x * 64, tb_n = blockIdx.y * 64;
  int tid = threadIdx.x;
  int ty = tid >> 4, tx = tid & 15;
  float acc[4][4] = {};
  int srow = tid >> 2, sseg = (tid & 3) * 4;
  const float* Ag = A + (size_t)(tb_m + srow) * 512 + sseg;
  const float* Bg = BT + (size_t)(tb_n + srow) * 512 + sseg;
  for(int kk = 0; kk < 512; kk += 16){
    __syncthreads();
    f32x4 a4 = *(const f32x4*)(Ag + kk);
    f32x4 b4 = *(const f32x4*)(Bg + kk);
    #pragma unroll
    for(int e = 0; e < 4; e++){ As[srow][sseg + e] = a4[e]; Bs[srow][sseg + e] = b4[e]; }
    __syncthreads();
    #pragma unroll
    for(int k2 = 0; k2 < 16; k2++){
      float a[4], b[4];
      #pragma unroll
      for(int i = 0; i < 4; i++) a[i] = As[ty * 4 + i][k2];
      #pragma unroll
      for(int jv = 0; jv < 4; jv++) b[jv] = Bs[tx * 4 + jv][k2];
      #pragma unroll
      for(int i = 0; i < 4; i++)
        #pragma unroll
        for(int jv = 0; jv < 4; jv++) acc[i][jv] += a[i] * b[jv];
    }
  }
  #pragma unroll
  for(int i = 0; i < 4; i++)
    #pragma unroll
    for(int jv = 0; jv < 4; jv++){
      int r = tb_m + ty * 4 + i;
      int c = tb_n + tx * 4 + jv;
      int b = r >> 8, jl = r & 255;
      float val = acc[i][jv];
      if(c < 512){
        float q = val * 0.125f;
        size_t qi = (((size_t)(b * 8 + (c >> 6)) * 256) + jl) * 64 + (c & 63);
        qlf[qi] = q;
        u16 hi = f2b(q);
        qlh[qi] = hi; qll[qi] = f2b(q - b2f(hi));
      } else {
        int c2 = c - 512;
        size_t ki = (((size_t)(b * 8 + (c2 >> 6)) * 256) + jl) * 64 + (c2 & 63);
        klf[ki] = val;
        u16 hi = f2b(val);
        klh[ki] = hi; kll[ki] = f2b(val - b2f(hi));
      }
    }
}

// ------------- batched fp32 pinv GEMM: C = osc*(A @ (dB*I + sB*B)), KCHUNK=64 -------------
__global__ __launch_bounds__(256) void gemm_pinv_f32(const float* __restrict__ A,
                                                     const float* __restrict__ B,
                                                     float* __restrict__ C,
                                                     float dB, float sB, float osc){
  __shared__ float As[64][68];   // [k][m]
  __shared__ float Bs[64][68];   // [k][n]
  int bh = blockIdx.y;
  size_t base = (size_t)bh * 65536;
  int tb_m = (blockIdx.x >> 2) * 64, tb_n = (blockIdx.x & 3) * 64;
  int tid = threadIdx.x;
  int ty = tid >> 4, tx = tid & 15;
  float acc[4][4] = {};
  int arow = tid >> 2, acol = (tid & 3) * 16;
  int brow = tid >> 3, bcol = (tid & 7) * 8;
  const float* Ag = A + base + (size_t)(tb_m + arow) * 256 + acol;
  const float* Bg = B + base + (size_t)brow * 256 + tb_n + bcol;
  for(int kk = 0; kk < 256; kk += 64){
    f32x4 a[4];
    #pragma unroll
    for(int q = 0; q < 4; q++) a[q] = *(const f32x4*)(Ag + kk + q * 4);
    f32x4 b[2][2];
    #pragma unroll
    for(int rr = 0; rr < 2; rr++){
      const float* bp = Bg + (size_t)(kk + rr * 32) * 256;
      b[rr][0] = *(const f32x4*)bp;
      b[rr][1] = *(const f32x4*)(bp + 4);
    }
    __syncthreads();
    #pragma unroll
    for(int q = 0; q < 4; q++)
      #pragma unroll
      for(int e = 0; e < 4; e++)
        As[acol + q * 4 + e][arow] = a[q][e];
    #pragma unroll
    for(int rr = 0; rr < 2; rr++){
      int krow = kk + rr * 32 + brow;
      f32x4 v0, v1;
      #pragma unroll
      for(int e = 0; e < 4; e++){
        float t0 = sB * b[rr][0][e]; if(krow == tb_n + bcol + e)     t0 += dB;
        float t1 = sB * b[rr][1][e]; if(krow == tb_n + bcol + 4 + e) t1 += dB;
        v0[e] = t0; v1[e] = t1;
      }
      *(f32x4*)&Bs[rr * 32 + brow][bcol]     = v0;
      *(f32x4*)&Bs[rr * 32 + brow][bcol + 4] = v1;
    }
    __syncthreads();
    #pragma unroll
    for(int k2 = 0; k2 < 64; k2++){
      f32x4 av4 = *(const f32x4*)&As[k2][ty * 4];
      f32x4 bv4 = *(const f32x4*)&Bs[k2][tx * 4];
      #pragma unroll
      for(int i = 0; i < 4; i++)
        #pragma unroll
        for(int jv = 0; jv < 4; jv++) acc[i][jv] += av4[i] * bv4[jv];
    }
  }
  #pragma unroll
  for(int i = 0; i < 4; i++){
    int r = tb_m + ty * 4 + i;
    f32x4 ov;
    #pragma unroll
    for(int jv = 0; jv < 4; jv++) ov[jv] = osc * acc[i][jv];
    *(f32x4*)(C + base + (size_t)r * 256 + tb_n + tx * 4) = ov;
  }
}

// ------------- a2 = softmax(q_l @ k_l^T) per row, fp32 -------------
__global__ __launch_bounds__(256) void a2_kernel(const float* __restrict__ qlf,
                                                 const float* __restrict__ klf,
                                                 float* __restrict__ a2){
  int i = blockIdx.x, bh = blockIdx.y, j = threadIdx.x;
  const float* qp = qlf + ((size_t)bh * 256 + i) * 64;
  const float* kp = klf + ((size_t)bh * 256 + j) * 64;
  float s = 0.f;
  #pragma unroll
  for(int d0 = 0; d0 < 16; d0++){
    f32x4 uq = *(const f32x4*)(qp + d0 * 4);
    f32x4 uk = *(const f32x4*)(kp + d0 * 4);
    #pragma unroll
    for(int e = 0; e < 4; e++) s += uq[e] * uk[e];
  }
  __shared__ float red[256];
  red[j] = s; __syncthreads();
  for(int off = 128; off; off >>= 1){ if(j < off) red[j] = fmaxf(red[j], red[j + off]); __syncthreads(); }
  float m = red[0]; __syncthreads();
  float p = expf(s - m);
  red[j] = p; __syncthreads();
  for(int off = 128; off; off >>= 1){ if(j < off) red[j] += red[j + off]; __syncthreads(); }
  float denom = red[0];
  a2[((size_t)bh * 256 + i) * 256 + j] = p / denom;
}

// ------------- scale maxes -------------
__global__ __launch_bounds__(256) void scale_kernel(const float* __restrict__ a2, u32* __restrict__ maxes){
  int bh = blockIdx.x, t = threadIdx.x;
  const float* p = a2 + (size_t)bh * 65536;
  float cs = 0.f, rs = 0.f;
  for(int i = 0; i < 256; i++) cs += p[i * 256 + t];
  for(int j = 0; j < 256; j++) rs += p[t * 256 + j];
  __shared__ float rc[256], rr[256];
  rc[t] = cs; rr[t] = rs; __syncthreads();
  for(int off = 128; off; off >>= 1){
    if(t < off){ rc[t] = fmaxf(rc[t], rc[t + off]); rr[t] = fmaxf(rr[t], rr[t + off]); }
    __syncthreads();
  }
  if(t == 0){
    atomicMax(&maxes[0], __float_as_uint(rc[0]));
    atomicMax(&maxes[1], __float_as_uint(rr[0]));
  }
}

// ------------- z0 = a2^T / scale (tiled transpose) -------------
__global__ __launch_bounds__(256) void z0_kernel(const float* __restrict__ a2,
                                                 float* __restrict__ z,
                                                 const u32* __restrict__ maxes){
  __shared__ float tile[64][65];
  float inv = 1.f / (__uint_as_float(maxes[0]) * __uint_as_float(maxes[1]));
  int bh = blockIdx.z;
  int i0 = blockIdx.x * 64, j0 = blockIdx.y * 64;
  const float* src = a2 + (size_t)bh * 65536;
  float* dst = z + (size_t)bh * 65536;
  for(int s = threadIdx.x; s < 1024; s += 256){
    int r = s >> 4, c4 = (s & 15) * 4;
    f32x4 v = *(const f32x4*)(src + (size_t)(i0 + r) * 256 + j0 + c4);
    #pragma unroll
    for(int e = 0; e < 4; e++) tile[r][c4 + e] = v[e];
  }
  __syncthreads();
  for(int s = threadIdx.x; s < 1024; s += 256){
    int jr = s >> 4, c4 = (s & 15) * 4;
    f32x4 v;
    #pragma unroll
    for(int e = 0; e < 4; e++) v[e] = tile[c4 + e][jr] * inv;
    *(f32x4*)(dst + (size_t)(j0 + jr) * 256 + i0 + c4) = v;
  }
}

// ------------- unified MFMA flash attention, LDS-staged K/V (shared by 4 waves) -------------
// MODE 0 (a1): A=qb exact; B=kl hi/lo; V=W^T hi/lo; 256 keys; RMW into o.  smem 54784 B
// MODE 1 (a3v): A=ql hi/lo; B=kb exact; V=v^T exact; 512-key split.        smem 36352 B
template<int MODE>
__global__ __launch_bounds__(256) void flash_kernel(
    const u16* __restrict__ Aex,
    const u16* __restrict__ Ah_, const u16* __restrict__ Al_,
    const u16* __restrict__ Bh_, const u16* __restrict__ Bl_,
    const u16* __restrict__ Vh_, const u16* __restrict__ Vl_,
    u16* __restrict__ o,
    float* __restrict__ pacc, float* __restrict__ plo){
  extern __shared__ char smem[];
  u32 (*pbuf)[32][35] = (u32(*)[32][35])smem;                  // [4][32][35] = 17920 B
  u16 (*ksh)[72] = (u16(*)[72])(smem + 17920);                 // [64][72] key-major
  u16 (*vsh)[72] = (u16(*)[72])(smem + 17920 + 9216);          // [64][72] d-major
  u16 (*ksl)[72] = (u16(*)[72])(smem + 17920 + 2 * 9216);      // MODE0 only
  u16 (*vsl)[72] = (u16(*)[72])(smem + 17920 + 3 * 9216);      // MODE0 only

  int tid = threadIdx.x;
  int w = tid >> 6, lane = tid & 63;
  int lr = lane & 15, lg = lane >> 4;
  int bh = blockIdx.y;
  int rowbase = blockIdx.x * 128 + w * 32;
  constexpr int NT = (MODE == 0) ? 4 : 8;
  int kbase = (MODE == 0) ? 0 : blockIdx.z * 512;
  int srow = tid >> 2, sseg = (tid & 3) * 16;

  u16x8 afh[2][2], afl[2][2];
  #pragma unroll
  for(int mi = 0; mi < 2; mi++)
    #pragma unroll
    for(int ks = 0; ks < 2; ks++){
      int r = rowbase + mi * 16 + lr;
      if(MODE == 0){
        afh[mi][ks] = *(const u16x8*)(Aex + ((size_t)bh * 8192 + r) * 64 + ks * 32 + lg * 8);
      } else {
        size_t idx = ((size_t)bh * 256 + r) * 64 + ks * 32 + lg * 8;
        afh[mi][ks] = *(const u16x8*)(Ah_ + idx);
        afl[mi][ks] = *(const u16x8*)(Al_ + idx);
      }
    }

  f32x4 pv[2][4] = {};
  float l[2][4] = {};

  for(int t = 0; t < NT; t++){
    int koff = t * 64;
    __syncthreads();
    if(MODE == 0){
      size_t kix = ((size_t)bh * 256 + koff + srow) * 64 + sseg;
      *(u16x8*)&ksh[srow][sseg]     = *(const u16x8*)(Bh_ + kix);
      *(u16x8*)&ksh[srow][sseg + 8] = *(const u16x8*)(Bh_ + kix + 8);
      *(u16x8*)&ksl[srow][sseg]     = *(const u16x8*)(Bl_ + kix);
      *(u16x8*)&ksl[srow][sseg + 8] = *(const u16x8*)(Bl_ + kix + 8);
      size_t vix = ((size_t)bh * 64 + srow) * 256 + koff + sseg;
      *(u16x8*)&vsh[srow][sseg]     = *(const u16x8*)(Vh_ + vix);
      *(u16x8*)&vsh[srow][sseg + 8] = *(const u16x8*)(Vh_ + vix + 8);
      *(u16x8*)&vsl[srow][sseg]     = *(const u16x8*)(Vl_ + vix);
      *(u16x8*)&vsl[srow][sseg + 8] = *(const u16x8*)(Vl_ + vix + 8);
    } else {
      size_t kix = ((size_t)bh * 8192 + kbase + koff + srow) * 64 + sseg;
      *(u16x8*)&ksh[srow][sseg]     = *(const u16x8*)(Bh_ + kix);
      *(u16x8*)&ksh[srow][sseg + 8] = *(const u16x8*)(Bh_ + kix + 8);
      size_t vix = ((size_t)bh * 64 + srow) * 8192 + kbase + koff + sseg;
      *(u16x8*)&vsh[srow][sseg]     = *(const u16x8*)(Vh_ + vix);
      *(u16x8*)&vsh[srow][sseg + 8] = *(const u16x8*)(Vh_ + vix + 8);
    }
    __syncthreads();
    #pragma unroll
    for(int half = 0; half < 2; half++){
      u16x8 bfh[2][2], bfl[2][2];
      #pragma unroll
      for(int ni = 0; ni < 2; ni++){
        int krow = half * 32 + ni * 16 + lr;
        #pragma unroll
        for(int ks = 0; ks < 2; ks++){
          bfh[ni][ks] = *(const u16x8*)&ksh[krow][ks * 32 + lg * 8];
          if(MODE == 0) bfl[ni][ks] = *(const u16x8*)&ksl[krow][ks * 32 + lg * 8];
        }
      }
      f32x4 sv[2][2];
      #pragma unroll
      for(int mi = 0; mi < 2; mi++)
        #pragma unroll
        for(int ni = 0; ni < 2; ni++) sv[mi][ni] = (f32x4){0.f, 0.f, 0.f, 0.f};
      #pragma unroll
      for(int ks = 0; ks < 2; ks++)
        #pragma unroll
        for(int mi = 0; mi < 2; mi++)
          #pragma unroll
          for(int ni = 0; ni < 2; ni++){
            sv[mi][ni] = mfma16(afh[mi][ks], bfh[ni][ks], sv[mi][ni]);
            if(MODE == 0) sv[mi][ni] = mfma16(afh[mi][ks], bfl[ni][ks], sv[mi][ni]);
            else          sv[mi][ni] = mfma16(afl[mi][ks], bfh[ni][ks], sv[mi][ni]);
          }
      #pragma unroll
      for(int mi = 0; mi < 2; mi++)
        #pragma unroll
        for(int ni = 0; ni < 2; ni++)
          #pragma unroll
          for(int e = 0; e < 4; e++){
            float p = __expf(sv[mi][ni][e]);
            l[mi][e] += p;
            u32 pb = __float_as_uint(p);
            u32 rb = pb + 0x7fffu + ((pb >> 16) & 1u);
            float hif = __uint_as_float(rb & 0xffff0000u);
            u32 lob = __float_as_uint(p - hif);
            pbuf[w][mi * 16 + lg * 4 + e][ni * 16 + lr] = __builtin_amdgcn_perm(lob, rb, 0x07060302u);
          }
      u16x8 pah[2], pal[2];
      #pragma unroll
      for(int mi = 0; mi < 2; mi++){
        u32 tv[8];
        #pragma unroll
        for(int e2 = 0; e2 < 8; e2++) tv[e2] = pbuf[w][mi * 16 + lr][lg * 8 + e2];
        u32* ph = (u32*)&pah[mi];
        u32* pl = (u32*)&pal[mi];
        #pragma unroll
        for(int q = 0; q < 4; q++){
          ph[q] = __builtin_amdgcn_perm(tv[2 * q + 1], tv[2 * q], 0x05040100u);
          pl[q] = __builtin_amdgcn_perm(tv[2 * q + 1], tv[2 * q], 0x07060302u);
        }
      }
      #pragma unroll
      for(int ni2 = 0; ni2 < 4; ni2++){
        int d = ni2 * 16 + lr;
        u16x8 vh = *(const u16x8*)&vsh[d][half * 32 + lg * 8];
        u16x8 vl;
        if(MODE == 0) vl = *(const u16x8*)&vsl[d][half * 32 + lg * 8];
        #pragma unroll
        for(int mi = 0; mi < 2; mi++){
          pv[mi][ni2] = mfma16(pah[mi], vh, pv[mi][ni2]);
          if(MODE == 0){
            pv[mi][ni2] = mfma16(pah[mi], vl, pv[mi][ni2]);
            pv[mi][ni2] = mfma16(pal[mi], vh, pv[mi][ni2]);
          } else {
            pv[mi][ni2] = mfma16(pal[mi], vh, pv[mi][ni2]);
          }
        }
      }
    }
  }
  #pragma unroll
  for(int mi = 0; mi < 2; mi++)
    #pragma unroll
    for(int e = 0; e < 4; e++){
      float lv = l[mi][e];
      #pragma unroll
      for(int off = 1; off < 16; off <<= 1) lv += __shfl_xor(lv, off, 64);
      l[mi][e] = lv;
    }
  #pragma unroll
  for(int mi = 0; mi < 2; mi++){
    #pragma unroll
    for(int e = 0; e < 4; e++){
      int row = rowbase + mi * 16 + lg * 4 + e;
      if(MODE == 0){
        float invl = 1.f / l[mi][e];
        int b = bh >> 3, h = bh & 7;
        #pragma unroll
        for(int ni2 = 0; ni2 < 4; ni2++){
          int col = ni2 * 16 + lr;
          size_t oi = ((size_t)b * 8192 + row) * 512 + h * 64 + col;
          o[oi] = f2b(pv[mi][ni2][e] * invl + b2f(o[oi]));
        }
      } else {
        #pragma unroll
        for(int ni2 = 0; ni2 < 4; ni2++){
          int col = ni2 * 16 + lr;
          pacc[(((size_t)blockIdx.z * 8192) + (size_t)bh * 256 + row) * 64 + col] = pv[mi][ni2][e];
        }
      }
    }
  }
  if(MODE == 1 && lr == 0){
    #pragma unroll
    for(int mi = 0; mi < 2; mi++)
      #pragma unroll
      for(int e = 0; e < 4; e++){
        int row = rowbase + mi * 16 + lg * 4 + e;
        plo[(size_t)blockIdx.z * 8192 + (size_t)bh * 256 + row] = l[mi][e];
      }
  }
}

// ------------- merge a3v split-K partials (16) -> av fp32 -------------
__global__ __launch_bounds__(64) void a3v_merge(const float* __restrict__ pacc,
                                                const float* __restrict__ plo,
                                                float* __restrict__ av){
  int row = blockIdx.x, d = threadIdx.x;
  float L = 0.f, acc = 0.f;
  #pragma unroll
  for(int p = 0; p < 16; p++){
    L += plo[(size_t)p * 8192 + row];
    acc += pacc[((size_t)p * 8192 + row) * 64 + d];
  }
  av[(size_t)row * 64 + d] = acc / L;
}

// ------------- W^T = (Z @ av)^T as bf16 hi/lo -------------
__global__ __launch_bounds__(64) void zw_kernel(const float* __restrict__ z,
                                                const float* __restrict__ av,
                                                u16* __restrict__ wth, u16* __restrict__ wtl){
  int i = blockIdx.x & 255, bh = blockIdx.x >> 8, d = threadIdx.x;
  const float* zr = z + ((size_t)bh * 256 + i) * 256;
  const float* ab = av + (size_t)bh * 256 * 64;
  float s = 0.f;
  for(int j = 0; j < 256; j++) s += zr[j] * ab[j * 64 + d];
  size_t oi = ((size_t)bh * 64 + d) * 256 + i;
  u16 hi = f2b(s);
  wth[oi] = hi;
  wtl[oi] = f2b(s - b2f(hi));
}

// ------------- depthwise conv residual -> o (bf16 token layout), register-blocked -------------
__global__ __launch_bounds__(256) void conv_kernel(const u16* __restrict__ v,
                                                   const float* __restrict__ cw,
                                                   u16* __restrict__ o){
  __shared__ float wl[33];
  __shared__ float vt[64][104];
  int bh = blockIdx.y, b = bh >> 3, h = bh & 7;
  int r0 = blockIdx.x * 64;
  if(threadIdx.x < 33) wl[threadIdx.x] = cw[h * 33 + threadIdx.x];
  const u16* vb = v + (size_t)bh * 8192 * 64;
  for(int idx = threadIdx.x; idx < 768; idx += 256){
    int row = idx >> 3, c8 = (idx & 7) * 8;
    int gr = r0 - 16 + row;
    u16x8 u = {};
    if(gr >= 0 && gr < 8192) u = *(const u16x8*)(vb + (size_t)gr * 64 + c8);
    #pragma unroll
    for(int e = 0; e < 8; e++) vt[c8 + e][row] = b2f(u[e]);
  }
  __syncthreads();
  int d = threadIdx.x & 63, g = threadIdx.x >> 6;
  float vin[48];
  #pragma unroll
  for(int i = 0; i < 12; i++){
    f32x4 q4 = *(const f32x4*)&vt[d][g * 16 + i * 4];
    #pragma unroll
    for(int e = 0; e < 4; e++) vin[i * 4 + e] = q4[e];
  }
  float acc[16] = {};
  #pragma unroll
  for(int t = 0; t < 33; t++){
    float wt = wl[t];
    #pragma unroll
    for(int r = 0; r < 16; r++) acc[r] += wt * vin[r + t];
  }
  #pragma unroll
  for(int r = 0; r < 16; r++){
    size_t oi = ((size_t)b * 8192 + (r0 + g * 16 + r)) * 512 + h * 64 + d;
    o[oi] = f2b(acc[r]);
  }
}

extern "C" void kernel_launch(void* const* d_in, const int* in_sizes, int n_in,
                              void* d_out, int out_size, void* d_ws, size_t ws_size,
                              hipStream_t stream){
  (void)in_sizes; (void)n_in; (void)out_size; (void)ws_size;
  const float* x     = (const float*)d_in[0];
  const float* ln_w  = (const float*)d_in[1];
  const float* ln_b  = (const float*)d_in[2];
  const float* w_qkv = (const float*)d_in[3];
  const float* w_out = (const float*)d_in[4];
  const float* b_out = (const float*)d_in[5];
  const float* cw    = (const float*)d_in[6];
  float* out = (float*)d_out;

  char* base = (char*)d_ws;
  size_t off = 0;
  auto alloc = [&](size_t bytes)->void*{
    void* r = base + off; off += (bytes + 255) & ~(size_t)255; return r;
  };
  u16* xn      = (u16*)alloc(32768ull * 512 * 2);    // reused as o after QKV GEMM
  float2* stat = (float2*)alloc(32768ull * 8);
  u16* qb      = (u16*)alloc(32ull * 8192 * 64 * 2);
  u16* kb      = (u16*)alloc(32ull * 8192 * 64 * 2);
  u16* vb      = (u16*)alloc(32ull * 8192 * 64 * 2);
  u16* vtb     = (u16*)alloc(32ull * 8192 * 64 * 2);
  u16* wqkvT   = (u16*)alloc(1536ull * 512 * 2);
  u16* woutT   = (u16*)alloc(512ull * 512 * 2);
  float* wqkT  = (float*)alloc(1024ull * 512 * 4);
  float* xl    = (float*)alloc(1024ull * 512 * 4);
  float* qlf   = (float*)alloc(32ull * 256 * 64 * 4);
  float* klf   = (float*)alloc(32ull * 256 * 64 * 4);
  u16* qlh     = (u16*)alloc(32ull * 256 * 64 * 2);
  u16* qll     = (u16*)alloc(32ull * 256 * 64 * 2);
  u16* klh     = (u16*)alloc(32ull * 256 * 64 * 2);
  u16* kll     = (u16*)alloc(32ull * 256 * 64 * 2);
  float* a2b   = (float*)alloc(32ull * 65536 * 4);
  float* zA    = (float*)alloc(32ull * 65536 * 4);
  float* zB    = (float*)alloc(32ull * 65536 * 4);   // pacc aliases zB..x3 (33.55 MB) after pinv
  float* az    = (float*)alloc(32ull * 65536 * 4);
  float* x2    = (float*)alloc(32ull * 65536 * 4);
  float* x3    = (float*)alloc(32ull * 65536 * 4);
  float* av    = (float*)alloc(32ull * 256 * 64 * 4);
  u16* wth     = (u16*)alloc(32ull * 64 * 256 * 2);
  u16* wtl     = (u16*)alloc(32ull * 64 * 256 * 2);
  u32* scal    = (u32*)alloc(256);
  u16* ob = xn;
  float* pacc = zB;
  float* plo  = a2b;

  hipMemsetAsync(scal, 0, 8, stream);
  ln_kernel<<<32768, 256, 0, stream>>>(x, ln_w, ln_b, xn, stat);
  trans_kernel<<<3072, 256, 0, stream>>>(w_qkv, wqkvT, 512, 1536);
  trans_kernel<<<1024, 256, 0, stream>>>(w_out, woutT, 512, 512);
  transf32_kernel<<<2048, 256, 0, stream>>>(w_qkv, wqkT);
  gemm128<0><<<dim3(256, 12), 256, 0, stream>>>(xn, wqkvT, qb, kb, vb, nullptr, nullptr, nullptr);
  vtrans_kernel<<<dim3(128, 32), 256, 0, stream>>>(vb, vtb);
  xl_kernel<<<1024, 256, 0, stream>>>(x, stat, ln_w, ln_b, xl);
  gemm_qlkl<<<dim3(16, 16), 256, 0, stream>>>(xl, wqkT, qlf, klf, qlh, qll, klh, kll);
  a2_kernel<<<dim3(256, 32), 256, 0, stream>>>(qlf, klf, a2b);
  scale_kernel<<<32, 256, 0, stream>>>(a2b, scal);
  z0_kernel<<<dim3(4, 4, 32), 256, 0, stream>>>(a2b, zA, scal);

  float* zP = zA; float* zQ = zB;
  for(int it = 0; it < 6; it++){
    gemm_pinv_f32<<<dim3(16, 32), 256, 0, stream>>>(a2b, zP, az, 0.f, 1.f, 1.f);
    gemm_pinv_f32<<<dim3(16, 32), 256, 0, stream>>>(az, az, x2, 7.f, -1.f, 1.f);
    gemm_pinv_f32<<<dim3(16, 32), 256, 0, stream>>>(az, x2, x3, 11.f, -1.f, 1.f);
    gemm_pinv_f32<<<dim3(16, 32), 256, 0, stream>>>(zP, x3, zQ, 13.f, -1.f, 0.25f);
    float* t1 = zP; zP = zQ; zQ = t1;
  }

  flash_kernel<1><<<dim3(2, 32, 16), 256, 36352, stream>>>(nullptr, qlh, qll, kb, nullptr, vtb, nullptr,
                                                           nullptr, pacc, plo);
  a3v_merge<<<8192, 64, 0, stream>>>(pacc, plo, av);
  zw_kernel<<<8192, 64, 0, stream>>>(zP, av, wth, wtl);
  conv_kernel<<<dim3(128, 32), 256, 0, stream>>>(vb, cw, ob);
  flash_kernel<0><<<dim3(64, 32), 256, 54784, stream>>>(qb, nullptr, nullptr, klh, kll, wth, wtl,
                                                        ob, nullptr, nullptr);
  gemm128<1><<<dim3(256, 4), 256, 0, stream>>>(ob, woutT, nullptr, nullptr, nullptr, b_out, x, out);
}